// Round 4
// baseline (1008.308 us; speedup 1.0000x reference)
//
#include <hip/hip_runtime.h>
#include <cstdint>
#include <cstddef>

typedef _Float16 half8 __attribute__((ext_vector_type(8)));
typedef _Float16 half4 __attribute__((ext_vector_type(4)));
typedef float    floatx4 __attribute__((ext_vector_type(4)));

constexpr int N_ROWS = 32768;
constexpr int D_DIM  = 1024;
constexpr int K_CENT = 4096;
constexpr int CAP    = 4096;      // max uncertain rows (E[count]~620, 100+ sigma margin)
constexpr float EPS_GAP = 0.4f;   // 2 * (14-sigma hh-error bound)

__device__ __forceinline__ void gload_lds16(const void* g, void* l) {
    __builtin_amdgcn_global_load_lds(
        (const __attribute__((address_space(1))) uint32_t*)g,
        (__attribute__((address_space(3))) uint32_t*)l, 16, 0, 0);
}

// ============================================================================
// Pre-pass: C[d][k] f32 -> C_hiT[k][d], C_loT[k][d] fp16 (transposed hi/lo split)
// ============================================================================
__global__ __launch_bounds__(256) void convert_C_kernel(
    const float* __restrict__ C, _Float16* __restrict__ ChiT, _Float16* __restrict__ CloT)
{
    __shared__ float tile[32][33];
    const int bk = blockIdx.x, bd = blockIdx.y, t = threadIdx.x;
    const int r = t >> 3, c4 = (t & 7) * 4;
    const float4 v = *(const float4*)&C[(size_t)(bd * 32 + r) * K_CENT + bk * 32 + c4];
    tile[r][c4 + 0] = v.x; tile[r][c4 + 1] = v.y;
    tile[r][c4 + 2] = v.z; tile[r][c4 + 3] = v.w;
    __syncthreads();
    half4 h, l;
#pragma unroll
    for (int i = 0; i < 4; ++i) {
        const float f = tile[c4 + i][r];
        const _Float16 hi = (_Float16)f;
        h[i] = hi;
        l[i] = (_Float16)(f - (float)hi);
    }
    *(half4*)&ChiT[(size_t)(bk * 32 + r) * D_DIM + bd * 32 + c4] = h;
    *(half4*)&CloT[(size_t)(bk * 32 + r) * D_DIM + bd * 32 + c4] = l;
}

// ============================================================================
// Pass 1: hh-only GEMM + argmin with (min1, idx1, min2) certainty tracking.
// 128x256 tile, 8 waves, BK=32, double-buffered. LDS 48KB+red -> 2 blocks/CU.
// ============================================================================
constexpr int BM = 128, BN = 256, BK = 32;
constexpr int P1_XH = 0;        // x_hi [8 msub][16 r][4 kg][8]
constexpr int P1_CH = 4096;     // C_hi [16 nsub][16 c][4 kg][8]
constexpr int P1_HB = 12288;    // halves per buffer (24 KB)

__device__ __forceinline__ void write_x1(_Float16* buf, const float4 v, int r, int kb) {
    const _Float16 h0 = (_Float16)v.x, h1 = (_Float16)v.y;
    const _Float16 h2 = (_Float16)v.z, h3 = (_Float16)v.w;
    const int kg  = kb >> 3;
    const int hs  = (kb >> 2) & 1;
    const int kge = kg ^ ((r >> 1) & 3);
    const int base = (r >> 4) * 512 + (r & 15) * 32 + kge * 8 + hs * 4;
    *(half4*)(buf + P1_XH + base) = (half4){h0, h1, h2, h3};
}

__global__ __launch_bounds__(512) void kmeans_pass1(
    const float* __restrict__ x, const _Float16* __restrict__ ChiT,
    const float* __restrict__ Cnorm, int* __restrict__ out,
    int* __restrict__ urows, unsigned int* __restrict__ ucount)
{
    __shared__ _Float16 lds[2][P1_HB];
    __shared__ float red_d[2][64][4];
    __shared__ int   red_i[2][64][4];
    __shared__ float red_2[2][64][4];

    const int tid  = threadIdx.x;
    const int lane = tid & 63;
    const int wid  = tid >> 6;
    const int wm   = wid >> 2;
    const int wn   = wid & 3;
    const int row0 = blockIdx.x * BM;

    const int l15 = lane & 15;
    const int l4  = lane >> 4;
    const int kge = l4 ^ ((l15 >> 1) & 3);
    const int fragoff = l15 * 32 + kge * 8;

    const int sr = tid >> 2;                            // x-stage row 0..127
    const int sc = tid & 3;                             // x-stage k-chunk
    const int ccol = lane >> 2;                         // C-stage col-in-subtile
    const int ckg  = (lane & 3) ^ ((ccol >> 1) & 3);    // pre-swizzled source kg

    float b1[4][4], b2[4][4];
    int   bi[4][4];
#pragma unroll
    for (int i = 0; i < 4; ++i)
#pragma unroll
        for (int r = 0; r < 4; ++r) { b1[i][r] = 3.4e38f; b2[i][r] = 3.4e38f; bi[i][r] = 0; }

    for (int kc = 0; kc < K_CENT; kc += BN) {
        floatx4 acc[4][4];
#pragma unroll
        for (int i = 0; i < 4; ++i)
#pragma unroll
            for (int j = 0; j < 4; ++j) acc[i][j] = (floatx4)0.0f;

        {   // prologue: stage kd=0 into buf 0
            _Float16* buf = lds[0];
            const float4 xv0 = *(const float4*)&x[(size_t)(row0 + sr) * D_DIM + 0 + sc * 4];
            const float4 xv1 = *(const float4*)&x[(size_t)(row0 + sr) * D_DIM + 16 + sc * 4];
            gload_lds16(&ChiT[(size_t)(kc + wid * 16       + ccol) * D_DIM + 0 + ckg * 8], buf + P1_CH + wid * 512);
            gload_lds16(&ChiT[(size_t)(kc + (wid + 8) * 16 + ccol) * D_DIM + 0 + ckg * 8], buf + P1_CH + (wid + 8) * 512);
            write_x1(buf, xv0, sr, sc * 4);
            write_x1(buf, xv1, sr, sc * 4 + 16);
            __syncthreads();
        }

        for (int kdi = 0; kdi < D_DIM / BK; ++kdi) {
            const int cur = kdi & 1;
            _Float16* bufc = lds[cur];
            _Float16* bufn = lds[cur ^ 1];
            const int  kdn = (kdi + 1) * BK;
            const bool pf  = (kdi + 1 < D_DIM / BK);

            float4 xv0, xv1;
            if (pf) {
                xv0 = *(const float4*)&x[(size_t)(row0 + sr) * D_DIM + kdn + sc * 4];
                xv1 = *(const float4*)&x[(size_t)(row0 + sr) * D_DIM + kdn + 16 + sc * 4];
                gload_lds16(&ChiT[(size_t)(kc + wid * 16       + ccol) * D_DIM + kdn + ckg * 8], bufn + P1_CH + wid * 512);
                gload_lds16(&ChiT[(size_t)(kc + (wid + 8) * 16 + ccol) * D_DIM + kdn + ckg * 8], bufn + P1_CH + (wid + 8) * 512);
            }

            half8 ah[4], bh[4];
#pragma unroll
            for (int i = 0; i < 4; ++i)
                ah[i] = *(const half8*)(bufc + P1_XH + (wm * 4 + i) * 512 + fragoff);
#pragma unroll
            for (int j = 0; j < 4; ++j)
                bh[j] = *(const half8*)(bufc + P1_CH + (wn * 4 + j) * 512 + fragoff);

#pragma unroll
            for (int i = 0; i < 4; ++i)
#pragma unroll
                for (int j = 0; j < 4; ++j)
                    acc[i][j] = __builtin_amdgcn_mfma_f32_16x16x32_f16(ah[i], bh[j], acc[i][j], 0, 0, 0);

            if (pf) {
                write_x1(bufn, xv0, sr, sc * 4);
                write_x1(bufn, xv1, sr, sc * 4 + 16);
            }
            __syncthreads();
        }

        // argmin epilogue with second-min tracking (cols ascending -> strict <)
        const int colw = kc + wn * 64;
#pragma unroll
        for (int ns = 0; ns < 4; ++ns) {
            const float cn = Cnorm[colw + ns * 16 + l15];
            const int   ix = colw + ns * 16 + l15;
#pragma unroll
            for (int i = 0; i < 4; ++i)
#pragma unroll
                for (int r = 0; r < 4; ++r) {
                    const float d = fmaf(-2.0f, acc[i][ns][r], cn);
                    if (d < b1[i][r]) { b2[i][r] = b1[i][r]; b1[i][r] = d; bi[i][r] = ix; }
                    else if (d < b2[i][r]) { b2[i][r] = d; }
                }
        }
    }

    // per-wave reduce over 16 col-lanes, merging (m1,i1,m2)
#pragma unroll
    for (int i = 0; i < 4; ++i)
#pragma unroll
        for (int r = 0; r < 4; ++r) {
            float m1 = b1[i][r], m2 = b2[i][r];
            int   i1 = bi[i][r];
#pragma unroll
            for (int off = 1; off < 16; off <<= 1) {
                const float om1 = __shfl_xor(m1, off, 64);
                const int   oi  = __shfl_xor(i1, off, 64);
                const float om2 = __shfl_xor(m2, off, 64);
                const float nm2 = fminf(fminf(m2, om2), fmaxf(m1, om1));
                if (om1 < m1 || (om1 == m1 && oi < i1)) { m1 = om1; i1 = oi; }
                m2 = nm2;
            }
            if (l15 == 0) {
                const int rr = i * 16 + l4 * 4 + r;
                red_d[wm][rr][wn] = m1;
                red_i[wm][rr][wn] = i1;
                red_2[wm][rr][wn] = m2;
            }
        }
    __syncthreads();

    if (tid < BM) {
        const int h  = tid >> 6;
        const int rr = tid & 63;
        float m1 = red_d[h][rr][0], m2 = red_2[h][rr][0];
        int   i1 = red_i[h][rr][0];
#pragma unroll
        for (int w = 1; w < 4; ++w) {
            const float om1 = red_d[h][rr][w];
            const int   oi  = red_i[h][rr][w];
            const float om2 = red_2[h][rr][w];
            m2 = fminf(fminf(m2, om2), fmaxf(m1, om1));
            if (om1 < m1 || (om1 == m1 && oi < i1)) { m1 = om1; i1 = oi; }
        }
        const int row = row0 + tid;
        out[row] = i1;
        if (m2 - m1 <= EPS_GAP) {
            const unsigned slot = atomicAdd(ucount, 1u);
            if (slot < (unsigned)CAP) urows[slot] = row;
        }
    }
}

// ============================================================================
// Gather: uncertain rows' x -> compact fp16 hi/lo buffers [slot][1024]
// ============================================================================
__global__ __launch_bounds__(64) void kmeans_gather(
    const float* __restrict__ x, const int* __restrict__ urows,
    const unsigned int* __restrict__ ucount,
    _Float16* __restrict__ xch, _Float16* __restrict__ xcl)
{
    const unsigned cnt = *ucount;
    const unsigned slot = blockIdx.x;
    const int row = (slot < cnt && slot < (unsigned)CAP) ? urows[slot] : 0;
    const int t = threadIdx.x;
#pragma unroll
    for (int e = 0; e < 16; ++e) {
        const int idx = e * 64 + t;
        const float v = x[(size_t)row * D_DIM + idx];
        const _Float16 h = (_Float16)v;
        xch[(size_t)slot * D_DIM + idx] = h;
        xcl[(size_t)slot * D_DIM + idx] = (_Float16)(v - (float)h);
    }
}

// ============================================================================
// Rescore: exact (3-pass hi/lo) argmin over all K for 16 uncertain rows/block.
// 4 waves, each 16 rows x 64 cols. Early-exit blocks beyond count.
// ============================================================================
constexpr int R_XH = 0;      // 512 halves
constexpr int R_XL = 512;    // 512
constexpr int R_CH = 1024;   // 8192
constexpr int R_CL = 9216;   // 8192
constexpr int R_HB = 17408;  // per buffer (34 KB)

__global__ __launch_bounds__(256) void kmeans_rescore(
    const _Float16* __restrict__ xch, const _Float16* __restrict__ xcl,
    const _Float16* __restrict__ ChiT, const _Float16* __restrict__ CloT,
    const float* __restrict__ Cnorm, const int* __restrict__ urows,
    const unsigned int* __restrict__ ucount, int* __restrict__ out)
{
    const unsigned cnt = *ucount;
    const int base = blockIdx.x * 16;
    if ((unsigned)base >= cnt) return;

    __shared__ _Float16 lds[2][R_HB];
    __shared__ float r2d[16][4];
    __shared__ int   r2i[16][4];

    const int tid  = threadIdx.x;
    const int lane = tid & 63;
    const int wid  = tid >> 6;          // 0..3 = wn (col quarter)
    const int l15  = lane & 15;
    const int l4   = lane >> 4;
    const int kge  = l4 ^ ((l15 >> 1) & 3);
    const int fragoff = l15 * 32 + kge * 8;

    const int ccol = lane >> 2;
    const int ckg  = (lane & 3) ^ ((ccol >> 1) & 3);
    const int xr   = lane >> 2;                        // 0..15 (X stage row)
    const int xkg  = (lane & 3) ^ ((xr >> 1) & 3);

    float best1[4];
    int   bidx1[4];
#pragma unroll
    for (int r = 0; r < 4; ++r) { best1[r] = 3.4e38f; bidx1[r] = 0; }

    for (int kc = 0; kc < K_CENT; kc += 256) {
        floatx4 acc[4];
#pragma unroll
        for (int j = 0; j < 4; ++j) acc[j] = (floatx4)0.0f;

        {   // prologue
            _Float16* buf = lds[0];
#pragma unroll
            for (int q = 0; q < 4; ++q) {
                const int nsub = wid + q * 4;
                gload_lds16(&ChiT[(size_t)(kc + nsub * 16 + ccol) * D_DIM + 0 + ckg * 8], buf + R_CH + nsub * 512);
                gload_lds16(&CloT[(size_t)(kc + nsub * 16 + ccol) * D_DIM + 0 + ckg * 8], buf + R_CL + nsub * 512);
            }
            if (wid == 0) gload_lds16(&xch[(size_t)(base + xr) * D_DIM + 0 + xkg * 8], buf + R_XH);
            if (wid == 1) gload_lds16(&xcl[(size_t)(base + xr) * D_DIM + 0 + xkg * 8], buf + R_XL);
            __syncthreads();
        }

        for (int kdi = 0; kdi < D_DIM / 32; ++kdi) {
            const int cur = kdi & 1;
            _Float16* bufc = lds[cur];
            _Float16* bufn = lds[cur ^ 1];
            const int  kdn = (kdi + 1) * 32;
            const bool pf  = (kdi + 1 < D_DIM / 32);

            if (pf) {
#pragma unroll
                for (int q = 0; q < 4; ++q) {
                    const int nsub = wid + q * 4;
                    gload_lds16(&ChiT[(size_t)(kc + nsub * 16 + ccol) * D_DIM + kdn + ckg * 8], bufn + R_CH + nsub * 512);
                    gload_lds16(&CloT[(size_t)(kc + nsub * 16 + ccol) * D_DIM + kdn + ckg * 8], bufn + R_CL + nsub * 512);
                }
                if (wid == 0) gload_lds16(&xch[(size_t)(base + xr) * D_DIM + kdn + xkg * 8], bufn + R_XH);
                if (wid == 1) gload_lds16(&xcl[(size_t)(base + xr) * D_DIM + kdn + xkg * 8], bufn + R_XL);
            }

            const half8 ah = *(const half8*)(bufc + R_XH + fragoff);
            const half8 al = *(const half8*)(bufc + R_XL + fragoff);
            half8 bh[4], bl[4];
#pragma unroll
            for (int j = 0; j < 4; ++j) {
                bh[j] = *(const half8*)(bufc + R_CH + (wid * 4 + j) * 512 + fragoff);
                bl[j] = *(const half8*)(bufc + R_CL + (wid * 4 + j) * 512 + fragoff);
            }
#pragma unroll
            for (int j = 0; j < 4; ++j) {
                acc[j] = __builtin_amdgcn_mfma_f32_16x16x32_f16(ah, bh[j], acc[j], 0, 0, 0);
                acc[j] = __builtin_amdgcn_mfma_f32_16x16x32_f16(ah, bl[j], acc[j], 0, 0, 0);
                acc[j] = __builtin_amdgcn_mfma_f32_16x16x32_f16(al, bh[j], acc[j], 0, 0, 0);
            }
            __syncthreads();
        }

#pragma unroll
        for (int j = 0; j < 4; ++j) {
            const int col = kc + wid * 64 + j * 16 + l15;
            const float cn = Cnorm[col];
#pragma unroll
            for (int r = 0; r < 4; ++r) {
                const float d = fmaf(-2.0f, acc[j][r], cn);
                if (d < best1[r]) { best1[r] = d; bidx1[r] = col; }
            }
        }
    }

    // reduce over 16 col-lanes (rows = l4*4+r are distinct per l4)
#pragma unroll
    for (int r = 0; r < 4; ++r) {
        float m1 = best1[r];
        int   i1 = bidx1[r];
#pragma unroll
        for (int off = 1; off < 16; off <<= 1) {
            const float om1 = __shfl_xor(m1, off, 64);
            const int   oi  = __shfl_xor(i1, off, 64);
            if (om1 < m1 || (om1 == m1 && oi < i1)) { m1 = om1; i1 = oi; }
        }
        if (l15 == 0) { r2d[l4 * 4 + r][wid] = m1; r2i[l4 * 4 + r][wid] = i1; }
    }
    __syncthreads();

    if (tid < 16) {
        float m1 = r2d[tid][0];
        int   i1 = r2i[tid][0];
#pragma unroll
        for (int w = 1; w < 4; ++w) {
            const float om1 = r2d[tid][w];
            const int   oi  = r2i[tid][w];
            if (om1 < m1 || (om1 == m1 && oi < i1)) { m1 = om1; i1 = oi; }
        }
        const unsigned slot = base + tid;
        const int row = (slot < cnt) ? urows[slot] : 0;  // padding -> row 0 (exact anyway)
        out[row] = i1;
    }
}

// ============================================================================
// Fallback A: proven R3 3-pass MFMA kernel (hi/lo, no rescore machinery)
// ============================================================================
constexpr int F_XH = 0, F_XL = 4096, F_CH = 8192, F_CL = 16384, F_HB = 24576;

__device__ __forceinline__ void write_x2(_Float16* buf, const float4 v, int r, int kb) {
    const _Float16 h0 = (_Float16)v.x, h1 = (_Float16)v.y;
    const _Float16 h2 = (_Float16)v.z, h3 = (_Float16)v.w;
    const int kg  = kb >> 3;
    const int hs  = (kb >> 2) & 1;
    const int kge = kg ^ ((r >> 1) & 3);
    const int base = (r >> 4) * 512 + (r & 15) * 32 + kge * 8 + hs * 4;
    *(half4*)(buf + F_XH + base) = (half4){h0, h1, h2, h3};
    *(half4*)(buf + F_XL + base) = (half4){(_Float16)(v.x - (float)h0), (_Float16)(v.y - (float)h1),
                                           (_Float16)(v.z - (float)h2), (_Float16)(v.w - (float)h3)};
}

__global__ __launch_bounds__(512, 2) void kmeans_mfma_kernel(
    const float* __restrict__ x, const _Float16* __restrict__ ChiT,
    const _Float16* __restrict__ CloT, const float* __restrict__ Cnorm,
    int* __restrict__ out)
{
    __shared__ _Float16 lds[2][F_HB];
    __shared__ float red_d[2][64][4];
    __shared__ int   red_i[2][64][4];

    const int tid  = threadIdx.x;
    const int lane = tid & 63;
    const int wid  = tid >> 6;
    const int wm   = wid >> 2;
    const int wn   = wid & 3;
    const int row0 = blockIdx.x * BM;
    const int l15 = lane & 15;
    const int l4  = lane >> 4;
    const int kge = l4 ^ ((l15 >> 1) & 3);
    const int fragoff = l15 * 32 + kge * 8;
    const int sr = tid >> 2, sc = tid & 3;
    const int ccol = lane >> 2;
    const int ckg  = (lane & 3) ^ ((ccol >> 1) & 3);

    float best[4][4];
    int   bidx[4][4];
#pragma unroll
    for (int i = 0; i < 4; ++i)
#pragma unroll
        for (int r = 0; r < 4; ++r) { best[i][r] = 3.4e38f; bidx[i][r] = 0; }

    for (int kc = 0; kc < K_CENT; kc += BN) {
        floatx4 acc[4][4];
#pragma unroll
        for (int i = 0; i < 4; ++i)
#pragma unroll
            for (int j = 0; j < 4; ++j) acc[i][j] = (floatx4)0.0f;
        {
            _Float16* buf = lds[0];
            const float4 xv0 = *(const float4*)&x[(size_t)(row0 + sr) * D_DIM + 0 + sc * 4];
            const float4 xv1 = *(const float4*)&x[(size_t)(row0 + sr) * D_DIM + 16 + sc * 4];
            gload_lds16(&ChiT[(size_t)(kc + wid * 16 + ccol) * D_DIM + 0 + ckg * 8], buf + F_CH + wid * 512);
            gload_lds16(&ChiT[(size_t)(kc + (wid + 8) * 16 + ccol) * D_DIM + 0 + ckg * 8], buf + F_CH + (wid + 8) * 512);
            gload_lds16(&CloT[(size_t)(kc + wid * 16 + ccol) * D_DIM + 0 + ckg * 8], buf + F_CL + wid * 512);
            gload_lds16(&CloT[(size_t)(kc + (wid + 8) * 16 + ccol) * D_DIM + 0 + ckg * 8], buf + F_CL + (wid + 8) * 512);
            write_x2(buf, xv0, sr, sc * 4);
            write_x2(buf, xv1, sr, sc * 4 + 16);
            __syncthreads();
        }
        for (int kdi = 0; kdi < D_DIM / BK; ++kdi) {
            const int cur = kdi & 1;
            _Float16* bufc = lds[cur];
            _Float16* bufn = lds[cur ^ 1];
            const int  kdn = (kdi + 1) * BK;
            const bool pf  = (kdi + 1 < D_DIM / BK);
            float4 xv0, xv1;
            if (pf) {
                xv0 = *(const float4*)&x[(size_t)(row0 + sr) * D_DIM + kdn + sc * 4];
                xv1 = *(const float4*)&x[(size_t)(row0 + sr) * D_DIM + kdn + 16 + sc * 4];
                gload_lds16(&ChiT[(size_t)(kc + wid * 16 + ccol) * D_DIM + kdn + ckg * 8], bufn + F_CH + wid * 512);
                gload_lds16(&ChiT[(size_t)(kc + (wid + 8) * 16 + ccol) * D_DIM + kdn + ckg * 8], bufn + F_CH + (wid + 8) * 512);
                gload_lds16(&CloT[(size_t)(kc + wid * 16 + ccol) * D_DIM + kdn + ckg * 8], bufn + F_CL + wid * 512);
                gload_lds16(&CloT[(size_t)(kc + (wid + 8) * 16 + ccol) * D_DIM + kdn + ckg * 8], bufn + F_CL + (wid + 8) * 512);
            }
            half8 ah[4], al[4], bh[4], bl[4];
#pragma unroll
            for (int i = 0; i < 4; ++i) {
                ah[i] = *(const half8*)(bufc + F_XH + (wm * 4 + i) * 512 + fragoff);
                al[i] = *(const half8*)(bufc + F_XL + (wm * 4 + i) * 512 + fragoff);
            }
#pragma unroll
            for (int j = 0; j < 4; ++j) {
                bh[j] = *(const half8*)(bufc + F_CH + (wn * 4 + j) * 512 + fragoff);
                bl[j] = *(const half8*)(bufc + F_CL + (wn * 4 + j) * 512 + fragoff);
            }
#pragma unroll
            for (int i = 0; i < 4; ++i)
#pragma unroll
                for (int j = 0; j < 4; ++j) {
                    acc[i][j] = __builtin_amdgcn_mfma_f32_16x16x32_f16(ah[i], bh[j], acc[i][j], 0, 0, 0);
                    acc[i][j] = __builtin_amdgcn_mfma_f32_16x16x32_f16(ah[i], bl[j], acc[i][j], 0, 0, 0);
                    acc[i][j] = __builtin_amdgcn_mfma_f32_16x16x32_f16(al[i], bh[j], acc[i][j], 0, 0, 0);
                }
            if (pf) {
                write_x2(bufn, xv0, sr, sc * 4);
                write_x2(bufn, xv1, sr, sc * 4 + 16);
            }
            __syncthreads();
        }
        const int colw = kc + wn * 64;
#pragma unroll
        for (int ns = 0; ns < 4; ++ns) {
            const float cn = Cnorm[colw + ns * 16 + l15];
            const int   ix = colw + ns * 16 + l15;
#pragma unroll
            for (int i = 0; i < 4; ++i)
#pragma unroll
                for (int r = 0; r < 4; ++r) {
                    const float d = fmaf(-2.0f, acc[i][ns][r], cn);
                    if (d < best[i][r]) { best[i][r] = d; bidx[i][r] = ix; }
                }
        }
    }
#pragma unroll
    for (int i = 0; i < 4; ++i)
#pragma unroll
        for (int r = 0; r < 4; ++r) {
            float d  = best[i][r];
            int   ix = bidx[i][r];
#pragma unroll
            for (int off = 1; off < 16; off <<= 1) {
                const float od = __shfl_xor(d, off, 64);
                const int   oi = __shfl_xor(ix, off, 64);
                if (od < d || (od == d && oi < ix)) { d = od; ix = oi; }
            }
            if (l15 == 0) {
                red_d[wm][i * 16 + l4 * 4 + r][wn] = d;
                red_i[wm][i * 16 + l4 * 4 + r][wn] = ix;
            }
        }
    __syncthreads();
    if (tid < BM) {
        const int h = tid >> 6, rr = tid & 63;
        float bd = red_d[h][rr][0];
        int   bi2 = red_i[h][rr][0];
#pragma unroll
        for (int w = 1; w < 4; ++w) {
            const float od = red_d[h][rr][w];
            const int   oi = red_i[h][rr][w];
            if (od < bd || (od == bd && oi < bi2)) { bd = od; bi2 = oi; }
        }
        out[row0 + tid] = bi2;
    }
}

// ============================================================================
// Fallback B: R1 fp32 kernel
// ============================================================================
__global__ __launch_bounds__(256, 2) void kmeans_assign_f32(
    const float* __restrict__ x, const float* __restrict__ Cm,
    const float* __restrict__ Cnorm, int* __restrict__ out)
{
    __shared__ float xs[32][64];
    __shared__ float cs[32][64];
    const int tid = threadIdx.x;
    const int tx = tid & 15, ty = tid >> 4;
    const int row0 = blockIdx.x * 64;
    const int xr = tid >> 3, xc = tid & 7;
    const int cr = tid >> 4, cc = tid & 15;
    float best[4]; int bidx[4];
#pragma unroll
    for (int i = 0; i < 4; ++i) { best[i] = 3.4e38f; bidx[i] = 0; }
    for (int kc = 0; kc < K_CENT; kc += 64) {
        float acc[16];
#pragma unroll
        for (int i = 0; i < 16; ++i) acc[i] = 0.0f;
        for (int kd = 0; kd < D_DIM; kd += 32) {
            const float4 xv0 = *(const float4*)&x[(size_t)(row0 + xr) * D_DIM + kd + xc * 4];
            const float4 xv1 = *(const float4*)&x[(size_t)(row0 + xr + 32) * D_DIM + kd + xc * 4];
            const float4 cv0 = *(const float4*)&Cm[(size_t)(kd + cr) * K_CENT + kc + cc * 4];
            const float4 cv1 = *(const float4*)&Cm[(size_t)(kd + cr + 16) * K_CENT + kc + cc * 4];
            __syncthreads();
            xs[xc*4+0][xr] = xv0.x; xs[xc*4+1][xr] = xv0.y; xs[xc*4+2][xr] = xv0.z; xs[xc*4+3][xr] = xv0.w;
            xs[xc*4+0][xr+32] = xv1.x; xs[xc*4+1][xr+32] = xv1.y; xs[xc*4+2][xr+32] = xv1.z; xs[xc*4+3][xr+32] = xv1.w;
            *(float4*)&cs[cr][cc*4]    = cv0;
            *(float4*)&cs[cr+16][cc*4] = cv1;
            __syncthreads();
#pragma unroll
            for (int kk = 0; kk < 32; ++kk) {
                const float4 a = *(const float4*)&xs[kk][ty*4];
                const float4 b = *(const float4*)&cs[kk][tx*4];
                acc[ 0] += a.x*b.x; acc[ 1] += a.x*b.y; acc[ 2] += a.x*b.z; acc[ 3] += a.x*b.w;
                acc[ 4] += a.y*b.x; acc[ 5] += a.y*b.y; acc[ 6] += a.y*b.z; acc[ 7] += a.y*b.w;
                acc[ 8] += a.z*b.x; acc[ 9] += a.z*b.y; acc[10] += a.z*b.z; acc[11] += a.z*b.w;
                acc[12] += a.w*b.x; acc[13] += a.w*b.y; acc[14] += a.w*b.z; acc[15] += a.w*b.w;
            }
        }
        const float4 cn = *(const float4*)&Cnorm[kc + tx*4];
        const float cnv[4] = {cn.x, cn.y, cn.z, cn.w};
#pragma unroll
        for (int i = 0; i < 4; ++i)
#pragma unroll
            for (int j = 0; j < 4; ++j) {
                const float dist = cnv[j] - 2.0f * acc[i*4+j];
                const int   idx  = kc + tx*4 + j;
                if (dist < best[i]) { best[i] = dist; bidx[i] = idx; }
            }
    }
#pragma unroll
    for (int i = 0; i < 4; ++i) {
        float d = best[i]; int ix = bidx[i];
#pragma unroll
        for (int off = 1; off < 16; off <<= 1) {
            const float od = __shfl_xor(d, off, 64);
            const int   oi = __shfl_xor(ix, off, 64);
            if (od < d || (od == d && oi < ix)) { d = od; ix = oi; }
        }
        if (tx == 0) out[row0 + ty*4 + i] = ix;
    }
}

// ============================================================================
extern "C" void kernel_launch(void* const* d_in, const int* in_sizes, int n_in,
                              void* d_out, int out_size, void* d_ws, size_t ws_size,
                              hipStream_t stream) {
    const float* x     = (const float*)d_in[0];
    const float* C     = (const float*)d_in[1];
    const float* Cnorm = (const float*)d_in[2];
    int* out = (int*)d_out;

    const size_t chalf = (size_t)K_CENT * D_DIM;             // halves per C array
    const size_t capd  = (size_t)CAP * D_DIM;                // halves per xc array
    const size_t need_full = (2 * chalf + 2 * capd) * sizeof(_Float16)
                           + (size_t)(CAP + 16) * sizeof(int);
    const size_t need_r3   = 2 * chalf * sizeof(_Float16);

    if (ws_size >= need_full) {
        _Float16* ChiT = (_Float16*)d_ws;
        _Float16* CloT = ChiT + chalf;
        _Float16* xch  = CloT + chalf;
        _Float16* xcl  = xch + capd;
        int* urows = (int*)(xcl + capd);
        unsigned int* ucount = (unsigned int*)(urows + CAP);

        convert_C_kernel<<<dim3(128, 32), 256, 0, stream>>>(C, ChiT, CloT);
        hipMemsetAsync(ucount, 0, sizeof(unsigned int), stream);
        kmeans_pass1<<<dim3(N_ROWS / BM), 512, 0, stream>>>(x, ChiT, Cnorm, out, urows, ucount);
        kmeans_gather<<<dim3(CAP), 64, 0, stream>>>(x, urows, ucount, xch, xcl);
        kmeans_rescore<<<dim3(CAP / 16), 256, 0, stream>>>(xch, xcl, ChiT, CloT, Cnorm, urows, ucount, out);
    } else if (ws_size >= need_r3) {
        _Float16* ChiT = (_Float16*)d_ws;
        _Float16* CloT = ChiT + chalf;
        convert_C_kernel<<<dim3(128, 32), 256, 0, stream>>>(C, ChiT, CloT);
        kmeans_mfma_kernel<<<dim3(N_ROWS / BM), 512, 0, stream>>>(x, ChiT, CloT, Cnorm, out);
    } else {
        kmeans_assign_f32<<<dim3(N_ROWS / 64), 256, 0, stream>>>(x, C, Cnorm, out);
    }
}

// Round 5
// 984.661 us; speedup vs baseline: 1.0240x; 1.0240x over previous
//
#include <hip/hip_runtime.h>
#include <cstdint>
#include <cstddef>

typedef _Float16 half8 __attribute__((ext_vector_type(8)));
typedef _Float16 half4 __attribute__((ext_vector_type(4)));
typedef float    floatx4 __attribute__((ext_vector_type(4)));

constexpr int N_ROWS = 32768;
constexpr int D_DIM  = 1024;
constexpr int K_CENT = 4096;
constexpr int CAP    = 4096;      // max uncertain rows (E[count]~620, huge margin)
constexpr float EPS_GAP = 0.4f;   // 2 * (14-sigma hh-error bound)

__device__ __forceinline__ void gload_lds16(const void* g, void* l) {
    __builtin_amdgcn_global_load_lds(
        (const __attribute__((address_space(1))) uint32_t*)g,
        (__attribute__((address_space(3))) uint32_t*)l, 16, 0, 0);
}

// ============================================================================
// Pre-pass: C[d][k] f32 -> C_hiT[k][d], C_loT[k][d] fp16 (transposed hi/lo split)
// ============================================================================
__global__ __launch_bounds__(256) void convert_C_kernel(
    const float* __restrict__ C, _Float16* __restrict__ ChiT, _Float16* __restrict__ CloT)
{
    __shared__ float tile[32][33];
    const int bk = blockIdx.x, bd = blockIdx.y, t = threadIdx.x;
    const int r = t >> 3, c4 = (t & 7) * 4;
    const float4 v = *(const float4*)&C[(size_t)(bd * 32 + r) * K_CENT + bk * 32 + c4];
    tile[r][c4 + 0] = v.x; tile[r][c4 + 1] = v.y;
    tile[r][c4 + 2] = v.z; tile[r][c4 + 3] = v.w;
    __syncthreads();
    half4 h, l;
#pragma unroll
    for (int i = 0; i < 4; ++i) {
        const float f = tile[c4 + i][r];
        const _Float16 hi = (_Float16)f;
        h[i] = hi;
        l[i] = (_Float16)(f - (float)hi);
    }
    *(half4*)&ChiT[(size_t)(bk * 32 + r) * D_DIM + bd * 32 + c4] = h;
    *(half4*)&CloT[(size_t)(bk * 32 + r) * D_DIM + bd * 32 + c4] = l;
}

// ============================================================================
// Pass 1 (K-split): hh-only GEMM + (min1, idx1, min2) per half.
// Grid 512 = 256 row-blocks x 2 K-halves -> 2 blocks/CU, 16 waves/CU.
// XCD-aware: h = xcd&1 so each XCD's L2 holds one 4MB C-half.
// ============================================================================
constexpr int BM = 128, BN = 256, BK = 32;
constexpr int P1_XH = 0;        // x_hi [8 msub][16 r][4 kg][8]
constexpr int P1_CH = 4096;     // C_hi [16 nsub][16 c][4 kg][8]
constexpr int P1_HB = 12288;    // halves per buffer (24 KB)

__device__ __forceinline__ void write_x1(_Float16* buf, const float4 v, int r, int kb) {
    const _Float16 h0 = (_Float16)v.x, h1 = (_Float16)v.y;
    const _Float16 h2 = (_Float16)v.z, h3 = (_Float16)v.w;
    const int kg  = kb >> 3;
    const int hs  = (kb >> 2) & 1;
    const int kge = kg ^ ((r >> 1) & 3);
    const int base = (r >> 4) * 512 + (r & 15) * 32 + kge * 8 + hs * 4;
    *(half4*)(buf + P1_XH + base) = (half4){h0, h1, h2, h3};
}

__global__ __launch_bounds__(512) void kmeans_pass1(
    const float* __restrict__ x, const _Float16* __restrict__ ChiT,
    const float* __restrict__ Cnorm,
    float* __restrict__ m1buf, int* __restrict__ i1buf, float* __restrict__ m2buf)
{
    __shared__ _Float16 lds[2][P1_HB];
    __shared__ float red_d[2][64][4];
    __shared__ int   red_i[2][64][4];
    __shared__ float red_2[2][64][4];

    // bijective decode: xcd = bid&7, slot = bid>>3 (0..63)
    // h = xcd&1 (K-half), rb = (xcd>>1)*64 + slot (0..255)
    const int bid  = blockIdx.x;
    const int xcd  = bid & 7;
    const int h    = xcd & 1;
    const int rb   = (xcd >> 1) * 64 + (bid >> 3);
    const int row0 = rb * BM;
    const int kb0  = h * (K_CENT / 2);

    const int tid  = threadIdx.x;
    const int lane = tid & 63;
    const int wid  = tid >> 6;
    const int wm   = wid >> 2;
    const int wn   = wid & 3;

    const int l15 = lane & 15;
    const int l4  = lane >> 4;
    const int kge = l4 ^ ((l15 >> 1) & 3);
    const int fragoff = l15 * 32 + kge * 8;

    const int sr = tid >> 2;                            // x-stage row 0..127
    const int sc = tid & 3;                             // x-stage k-chunk
    const int ccol = lane >> 2;                         // C-stage col-in-subtile
    const int ckg  = (lane & 3) ^ ((ccol >> 1) & 3);    // pre-swizzled source kg

    float b1[4][4], b2[4][4];
    int   bi[4][4];
#pragma unroll
    for (int i = 0; i < 4; ++i)
#pragma unroll
        for (int r = 0; r < 4; ++r) { b1[i][r] = 3.4e38f; b2[i][r] = 3.4e38f; bi[i][r] = 0; }

    for (int kc = kb0; kc < kb0 + K_CENT / 2; kc += BN) {
        floatx4 acc[4][4];
#pragma unroll
        for (int i = 0; i < 4; ++i)
#pragma unroll
            for (int j = 0; j < 4; ++j) acc[i][j] = (floatx4)0.0f;

        {   // prologue: stage kd=0 into buf 0
            _Float16* buf = lds[0];
            const float4 xv0 = *(const float4*)&x[(size_t)(row0 + sr) * D_DIM + 0 + sc * 4];
            const float4 xv1 = *(const float4*)&x[(size_t)(row0 + sr) * D_DIM + 16 + sc * 4];
            gload_lds16(&ChiT[(size_t)(kc + wid * 16       + ccol) * D_DIM + 0 + ckg * 8], buf + P1_CH + wid * 512);
            gload_lds16(&ChiT[(size_t)(kc + (wid + 8) * 16 + ccol) * D_DIM + 0 + ckg * 8], buf + P1_CH + (wid + 8) * 512);
            write_x1(buf, xv0, sr, sc * 4);
            write_x1(buf, xv1, sr, sc * 4 + 16);
            __syncthreads();
        }

        for (int kdi = 0; kdi < D_DIM / BK; ++kdi) {
            const int cur = kdi & 1;
            _Float16* bufc = lds[cur];
            _Float16* bufn = lds[cur ^ 1];
            const int  kdn = (kdi + 1) * BK;
            const bool pf  = (kdi + 1 < D_DIM / BK);

            float4 xv0, xv1;
            if (pf) {
                xv0 = *(const float4*)&x[(size_t)(row0 + sr) * D_DIM + kdn + sc * 4];
                xv1 = *(const float4*)&x[(size_t)(row0 + sr) * D_DIM + kdn + 16 + sc * 4];
                gload_lds16(&ChiT[(size_t)(kc + wid * 16       + ccol) * D_DIM + kdn + ckg * 8], bufn + P1_CH + wid * 512);
                gload_lds16(&ChiT[(size_t)(kc + (wid + 8) * 16 + ccol) * D_DIM + kdn + ckg * 8], bufn + P1_CH + (wid + 8) * 512);
            }

            half8 ah[4], bh[4];
#pragma unroll
            for (int i = 0; i < 4; ++i)
                ah[i] = *(const half8*)(bufc + P1_XH + (wm * 4 + i) * 512 + fragoff);
#pragma unroll
            for (int j = 0; j < 4; ++j)
                bh[j] = *(const half8*)(bufc + P1_CH + (wn * 4 + j) * 512 + fragoff);

#pragma unroll
            for (int i = 0; i < 4; ++i)
#pragma unroll
                for (int j = 0; j < 4; ++j)
                    acc[i][j] = __builtin_amdgcn_mfma_f32_16x16x32_f16(ah[i], bh[j], acc[i][j], 0, 0, 0);

            if (pf) {
                write_x1(bufn, xv0, sr, sc * 4);
                write_x1(bufn, xv1, sr, sc * 4 + 16);
            }
            __syncthreads();
        }

        // argmin epilogue with second-min tracking (cols ascending -> strict <)
        const int colw = kc + wn * 64;
#pragma unroll
        for (int ns = 0; ns < 4; ++ns) {
            const float cn = Cnorm[colw + ns * 16 + l15];
            const int   ix = colw + ns * 16 + l15;
#pragma unroll
            for (int i = 0; i < 4; ++i)
#pragma unroll
                for (int r = 0; r < 4; ++r) {
                    const float d = fmaf(-2.0f, acc[i][ns][r], cn);
                    if (d < b1[i][r]) { b2[i][r] = b1[i][r]; b1[i][r] = d; bi[i][r] = ix; }
                    else if (d < b2[i][r]) { b2[i][r] = d; }
                }
        }
    }

    // per-wave reduce over 16 col-lanes, merging (m1,i1,m2)
#pragma unroll
    for (int i = 0; i < 4; ++i)
#pragma unroll
        for (int r = 0; r < 4; ++r) {
            float m1 = b1[i][r], m2 = b2[i][r];
            int   i1 = bi[i][r];
#pragma unroll
            for (int off = 1; off < 16; off <<= 1) {
                const float om1 = __shfl_xor(m1, off, 64);
                const int   oi  = __shfl_xor(i1, off, 64);
                const float om2 = __shfl_xor(m2, off, 64);
                const float nm2 = fminf(fminf(m2, om2), fmaxf(m1, om1));
                if (om1 < m1 || (om1 == m1 && oi < i1)) { m1 = om1; i1 = oi; }
                m2 = nm2;
            }
            if (l15 == 0) {
                const int rr = i * 16 + l4 * 4 + r;
                red_d[wm][rr][wn] = m1;
                red_i[wm][rr][wn] = i1;
                red_2[wm][rr][wn] = m2;
            }
        }
    __syncthreads();

    if (tid < BM) {
        const int hh = tid >> 6;
        const int rr = tid & 63;
        float m1 = red_d[hh][rr][0], m2 = red_2[hh][rr][0];
        int   i1 = red_i[hh][rr][0];
#pragma unroll
        for (int w = 1; w < 4; ++w) {
            const float om1 = red_d[hh][rr][w];
            const int   oi  = red_i[hh][rr][w];
            const float om2 = red_2[hh][rr][w];
            m2 = fminf(fminf(m2, om2), fmaxf(m1, om1));
            if (om1 < m1 || (om1 == m1 && oi < i1)) { m1 = om1; i1 = oi; }
        }
        const size_t off = (size_t)h * N_ROWS + row0 + tid;
        m1buf[off] = m1;
        i1buf[off] = i1;
        m2buf[off] = m2;
    }
}

// ============================================================================
// Merge halves: final argmin + certainty test + worklist
// ============================================================================
__global__ __launch_bounds__(256) void kmeans_merge(
    const float* __restrict__ m1buf, const int* __restrict__ i1buf,
    const float* __restrict__ m2buf, int* __restrict__ out,
    int* __restrict__ urows, unsigned int* __restrict__ ucount)
{
    const int row = blockIdx.x * 256 + threadIdx.x;
    float m1 = m1buf[row], m2 = m2buf[row];
    int   i1 = i1buf[row];
    const float om1 = m1buf[N_ROWS + row];
    const float om2 = m2buf[N_ROWS + row];
    const int   oi  = i1buf[N_ROWS + row];
    const float nm2 = fminf(fminf(m2, om2), fmaxf(m1, om1));
    if (om1 < m1 || (om1 == m1 && oi < i1)) { m1 = om1; i1 = oi; }
    out[row] = i1;
    if (nm2 - m1 <= EPS_GAP) {
        const unsigned slot = atomicAdd(ucount, 1u);
        if (slot < (unsigned)CAP) urows[slot] = row;
    }
}

// ============================================================================
// Gather: uncertain rows' x -> compact fp16 hi/lo buffers [slot][1024]
// ============================================================================
__global__ __launch_bounds__(64) void kmeans_gather(
    const float* __restrict__ x, const int* __restrict__ urows,
    const unsigned int* __restrict__ ucount,
    _Float16* __restrict__ xch, _Float16* __restrict__ xcl)
{
    const unsigned cnt = min(*ucount, (unsigned)CAP);
    const unsigned slot = blockIdx.x;
    if (slot >= cnt) return;
    const int row = urows[slot];
    const int t = threadIdx.x;
#pragma unroll
    for (int e = 0; e < 16; ++e) {
        const int idx = e * 64 + t;
        const float v = x[(size_t)row * D_DIM + idx];
        const _Float16 h = (_Float16)v;
        xch[(size_t)slot * D_DIM + idx] = h;
        xcl[(size_t)slot * D_DIM + idx] = (_Float16)(v - (float)h);
    }
}

// ============================================================================
// Rescore: exact (3-pass hi/lo) argmin over all K for 16 uncertain rows/block.
// ============================================================================
constexpr int R_XH = 0;      // 512 halves
constexpr int R_XL = 512;    // 512
constexpr int R_CH = 1024;   // 8192
constexpr int R_CL = 9216;   // 8192
constexpr int R_HB = 17408;  // per buffer (34 KB)

__global__ __launch_bounds__(256) void kmeans_rescore(
    const _Float16* __restrict__ xch, const _Float16* __restrict__ xcl,
    const _Float16* __restrict__ ChiT, const _Float16* __restrict__ CloT,
    const float* __restrict__ Cnorm, const int* __restrict__ urows,
    const unsigned int* __restrict__ ucount, int* __restrict__ out)
{
    const unsigned cnt = min(*ucount, (unsigned)CAP);
    const int base = blockIdx.x * 16;
    if ((unsigned)base >= cnt) return;

    __shared__ _Float16 lds[2][R_HB];
    __shared__ float r2d[16][4];
    __shared__ int   r2i[16][4];

    const int tid  = threadIdx.x;
    const int lane = tid & 63;
    const int wid  = tid >> 6;          // 0..3 = col quarter
    const int l15  = lane & 15;
    const int l4   = lane >> 4;
    const int kge  = l4 ^ ((l15 >> 1) & 3);
    const int fragoff = l15 * 32 + kge * 8;

    const int ccol = lane >> 2;
    const int ckg  = (lane & 3) ^ ((ccol >> 1) & 3);
    const int xr   = lane >> 2;
    const int xkg  = (lane & 3) ^ ((xr >> 1) & 3);

    float best1[4];
    int   bidx1[4];
#pragma unroll
    for (int r = 0; r < 4; ++r) { best1[r] = 3.4e38f; bidx1[r] = 0; }

    for (int kc = 0; kc < K_CENT; kc += 256) {
        floatx4 acc[4];
#pragma unroll
        for (int j = 0; j < 4; ++j) acc[j] = (floatx4)0.0f;

        {   // prologue
            _Float16* buf = lds[0];
#pragma unroll
            for (int q = 0; q < 4; ++q) {
                const int nsub = wid + q * 4;
                gload_lds16(&ChiT[(size_t)(kc + nsub * 16 + ccol) * D_DIM + 0 + ckg * 8], buf + R_CH + nsub * 512);
                gload_lds16(&CloT[(size_t)(kc + nsub * 16 + ccol) * D_DIM + 0 + ckg * 8], buf + R_CL + nsub * 512);
            }
            if (wid == 0) gload_lds16(&xch[(size_t)(base + xr) * D_DIM + 0 + xkg * 8], buf + R_XH);
            if (wid == 1) gload_lds16(&xcl[(size_t)(base + xr) * D_DIM + 0 + xkg * 8], buf + R_XL);
            __syncthreads();
        }

        for (int kdi = 0; kdi < D_DIM / 32; ++kdi) {
            const int cur = kdi & 1;
            _Float16* bufc = lds[cur];
            _Float16* bufn = lds[cur ^ 1];
            const int  kdn = (kdi + 1) * 32;
            const bool pf  = (kdi + 1 < D_DIM / 32);

            if (pf) {
#pragma unroll
                for (int q = 0; q < 4; ++q) {
                    const int nsub = wid + q * 4;
                    gload_lds16(&ChiT[(size_t)(kc + nsub * 16 + ccol) * D_DIM + kdn + ckg * 8], bufn + R_CH + nsub * 512);
                    gload_lds16(&CloT[(size_t)(kc + nsub * 16 + ccol) * D_DIM + kdn + ckg * 8], bufn + R_CL + nsub * 512);
                }
                if (wid == 0) gload_lds16(&xch[(size_t)(base + xr) * D_DIM + kdn + xkg * 8], bufn + R_XH);
                if (wid == 1) gload_lds16(&xcl[(size_t)(base + xr) * D_DIM + kdn + xkg * 8], bufn + R_XL);
            }

            const half8 ah = *(const half8*)(bufc + R_XH + fragoff);
            const half8 al = *(const half8*)(bufc + R_XL + fragoff);
            half8 bh[4], bl[4];
#pragma unroll
            for (int j = 0; j < 4; ++j) {
                bh[j] = *(const half8*)(bufc + R_CH + (wid * 4 + j) * 512 + fragoff);
                bl[j] = *(const half8*)(bufc + R_CL + (wid * 4 + j) * 512 + fragoff);
            }
#pragma unroll
            for (int j = 0; j < 4; ++j) {
                acc[j] = __builtin_amdgcn_mfma_f32_16x16x32_f16(ah, bh[j], acc[j], 0, 0, 0);
                acc[j] = __builtin_amdgcn_mfma_f32_16x16x32_f16(ah, bl[j], acc[j], 0, 0, 0);
                acc[j] = __builtin_amdgcn_mfma_f32_16x16x32_f16(al, bh[j], acc[j], 0, 0, 0);
            }
            __syncthreads();
        }

#pragma unroll
        for (int j = 0; j < 4; ++j) {
            const int col = kc + wid * 64 + j * 16 + l15;
            const float cn = Cnorm[col];
#pragma unroll
            for (int r = 0; r < 4; ++r) {
                const float d = fmaf(-2.0f, acc[j][r], cn);
                if (d < best1[r]) { best1[r] = d; bidx1[r] = col; }
            }
        }
    }

#pragma unroll
    for (int r = 0; r < 4; ++r) {
        float m1 = best1[r];
        int   i1 = bidx1[r];
#pragma unroll
        for (int off = 1; off < 16; off <<= 1) {
            const float om1 = __shfl_xor(m1, off, 64);
            const int   oi  = __shfl_xor(i1, off, 64);
            if (om1 < m1 || (om1 == m1 && oi < i1)) { m1 = om1; i1 = oi; }
        }
        if (l15 == 0) { r2d[l4 * 4 + r][wid] = m1; r2i[l4 * 4 + r][wid] = i1; }
    }
    __syncthreads();

    if (tid < 16) {
        const unsigned slot = base + tid;
        if (slot < cnt) {
            float m1 = r2d[tid][0];
            int   i1 = r2i[tid][0];
#pragma unroll
            for (int w = 1; w < 4; ++w) {
                const float om1 = r2d[tid][w];
                const int   oi  = r2i[tid][w];
                if (om1 < m1 || (om1 == m1 && oi < i1)) { m1 = om1; i1 = oi; }
            }
            out[urows[slot]] = i1;
        }
    }
}

// ============================================================================
// Fallback A: proven R3 3-pass MFMA kernel (hi/lo, direct out)
// ============================================================================
constexpr int F_XH = 0, F_XL = 4096, F_CH = 8192, F_CL = 16384, F_HB = 24576;

__device__ __forceinline__ void write_x2(_Float16* buf, const float4 v, int r, int kb) {
    const _Float16 h0 = (_Float16)v.x, h1 = (_Float16)v.y;
    const _Float16 h2 = (_Float16)v.z, h3 = (_Float16)v.w;
    const int kg  = kb >> 3;
    const int hs  = (kb >> 2) & 1;
    const int kge = kg ^ ((r >> 1) & 3);
    const int base = (r >> 4) * 512 + (r & 15) * 32 + kge * 8 + hs * 4;
    *(half4*)(buf + F_XH + base) = (half4){h0, h1, h2, h3};
    *(half4*)(buf + F_XL + base) = (half4){(_Float16)(v.x - (float)h0), (_Float16)(v.y - (float)h1),
                                           (_Float16)(v.z - (float)h2), (_Float16)(v.w - (float)h3)};
}

__global__ __launch_bounds__(512, 2) void kmeans_mfma_kernel(
    const float* __restrict__ x, const _Float16* __restrict__ ChiT,
    const _Float16* __restrict__ CloT, const float* __restrict__ Cnorm,
    int* __restrict__ out)
{
    __shared__ _Float16 lds[2][F_HB];
    __shared__ float red_d[2][64][4];
    __shared__ int   red_i[2][64][4];

    const int tid  = threadIdx.x;
    const int lane = tid & 63;
    const int wid  = tid >> 6;
    const int wm   = wid >> 2;
    const int wn   = wid & 3;
    const int row0 = blockIdx.x * BM;
    const int l15 = lane & 15;
    const int l4  = lane >> 4;
    const int kge = l4 ^ ((l15 >> 1) & 3);
    const int fragoff = l15 * 32 + kge * 8;
    const int sr = tid >> 2, sc = tid & 3;
    const int ccol = lane >> 2;
    const int ckg  = (lane & 3) ^ ((ccol >> 1) & 3);

    float best[4][4];
    int   bidx[4][4];
#pragma unroll
    for (int i = 0; i < 4; ++i)
#pragma unroll
        for (int r = 0; r < 4; ++r) { best[i][r] = 3.4e38f; bidx[i][r] = 0; }

    for (int kc = 0; kc < K_CENT; kc += BN) {
        floatx4 acc[4][4];
#pragma unroll
        for (int i = 0; i < 4; ++i)
#pragma unroll
            for (int j = 0; j < 4; ++j) acc[i][j] = (floatx4)0.0f;
        {
            _Float16* buf = lds[0];
            const float4 xv0 = *(const float4*)&x[(size_t)(row0 + sr) * D_DIM + 0 + sc * 4];
            const float4 xv1 = *(const float4*)&x[(size_t)(row0 + sr) * D_DIM + 16 + sc * 4];
            gload_lds16(&ChiT[(size_t)(kc + wid * 16 + ccol) * D_DIM + 0 + ckg * 8], buf + F_CH + wid * 512);
            gload_lds16(&ChiT[(size_t)(kc + (wid + 8) * 16 + ccol) * D_DIM + 0 + ckg * 8], buf + F_CH + (wid + 8) * 512);
            gload_lds16(&CloT[(size_t)(kc + wid * 16 + ccol) * D_DIM + 0 + ckg * 8], buf + F_CL + wid * 512);
            gload_lds16(&CloT[(size_t)(kc + (wid + 8) * 16 + ccol) * D_DIM + 0 + ckg * 8], buf + F_CL + (wid + 8) * 512);
            write_x2(buf, xv0, sr, sc * 4);
            write_x2(buf, xv1, sr, sc * 4 + 16);
            __syncthreads();
        }
        for (int kdi = 0; kdi < D_DIM / BK; ++kdi) {
            const int cur = kdi & 1;
            _Float16* bufc = lds[cur];
            _Float16* bufn = lds[cur ^ 1];
            const int  kdn = (kdi + 1) * BK;
            const bool pf  = (kdi + 1 < D_DIM / BK);
            float4 xv0, xv1;
            if (pf) {
                xv0 = *(const float4*)&x[(size_t)(row0 + sr) * D_DIM + kdn + sc * 4];
                xv1 = *(const float4*)&x[(size_t)(row0 + sr) * D_DIM + kdn + 16 + sc * 4];
                gload_lds16(&ChiT[(size_t)(kc + wid * 16 + ccol) * D_DIM + kdn + ckg * 8], bufn + F_CH + wid * 512);
                gload_lds16(&ChiT[(size_t)(kc + (wid + 8) * 16 + ccol) * D_DIM + kdn + ckg * 8], bufn + F_CH + (wid + 8) * 512);
                gload_lds16(&CloT[(size_t)(kc + wid * 16 + ccol) * D_DIM + kdn + ckg * 8], bufn + F_CL + wid * 512);
                gload_lds16(&CloT[(size_t)(kc + (wid + 8) * 16 + ccol) * D_DIM + kdn + ckg * 8], bufn + F_CL + (wid + 8) * 512);
            }
            half8 ah[4], al[4], bh[4], bl[4];
#pragma unroll
            for (int i = 0; i < 4; ++i) {
                ah[i] = *(const half8*)(bufc + F_XH + (wm * 4 + i) * 512 + fragoff);
                al[i] = *(const half8*)(bufc + F_XL + (wm * 4 + i) * 512 + fragoff);
            }
#pragma unroll
            for (int j = 0; j < 4; ++j) {
                bh[j] = *(const half8*)(bufc + F_CH + (wn * 4 + j) * 512 + fragoff);
                bl[j] = *(const half8*)(bufc + F_CL + (wn * 4 + j) * 512 + fragoff);
            }
#pragma unroll
            for (int i = 0; i < 4; ++i)
#pragma unroll
                for (int j = 0; j < 4; ++j) {
                    acc[i][j] = __builtin_amdgcn_mfma_f32_16x16x32_f16(ah[i], bh[j], acc[i][j], 0, 0, 0);
                    acc[i][j] = __builtin_amdgcn_mfma_f32_16x16x32_f16(ah[i], bl[j], acc[i][j], 0, 0, 0);
                    acc[i][j] = __builtin_amdgcn_mfma_f32_16x16x32_f16(al[i], bh[j], acc[i][j], 0, 0, 0);
                }
            if (pf) {
                write_x2(bufn, xv0, sr, sc * 4);
                write_x2(bufn, xv1, sr, sc * 4 + 16);
            }
            __syncthreads();
        }
        const int colw = kc + wn * 64;
#pragma unroll
        for (int ns = 0; ns < 4; ++ns) {
            const float cn = Cnorm[colw + ns * 16 + l15];
            const int   ix = colw + ns * 16 + l15;
#pragma unroll
            for (int i = 0; i < 4; ++i)
#pragma unroll
                for (int r = 0; r < 4; ++r) {
                    const float d = fmaf(-2.0f, acc[i][ns][r], cn);
                    if (d < best[i][r]) { best[i][r] = d; bidx[i][r] = ix; }
                }
        }
    }
#pragma unroll
    for (int i = 0; i < 4; ++i)
#pragma unroll
        for (int r = 0; r < 4; ++r) {
            float d  = best[i][r];
            int   ix = bidx[i][r];
#pragma unroll
            for (int off = 1; off < 16; off <<= 1) {
                const float od = __shfl_xor(d, off, 64);
                const int   oi = __shfl_xor(ix, off, 64);
                if (od < d || (od == d && oi < ix)) { d = od; ix = oi; }
            }
            if (l15 == 0) {
                red_d[wm][i * 16 + l4 * 4 + r][wn] = d;
                red_i[wm][i * 16 + l4 * 4 + r][wn] = ix;
            }
        }
    __syncthreads();
    if (tid < BM) {
        const int hh = tid >> 6, rr = tid & 63;
        float bd = red_d[hh][rr][0];
        int   bi2 = red_i[hh][rr][0];
#pragma unroll
        for (int w = 1; w < 4; ++w) {
            const float od = red_d[hh][rr][w];
            const int   oi = red_i[hh][rr][w];
            if (od < bd || (od == bd && oi < bi2)) { bd = od; bi2 = oi; }
        }
        out[row0 + tid] = bi2;
    }
}

// ============================================================================
// Fallback B: R1 fp32 kernel
// ============================================================================
__global__ __launch_bounds__(256, 2) void kmeans_assign_f32(
    const float* __restrict__ x, const float* __restrict__ Cm,
    const float* __restrict__ Cnorm, int* __restrict__ out)
{
    __shared__ float xs[32][64];
    __shared__ float cs[32][64];
    const int tid = threadIdx.x;
    const int tx = tid & 15, ty = tid >> 4;
    const int row0 = blockIdx.x * 64;
    const int xr = tid >> 3, xc = tid & 7;
    const int cr = tid >> 4, cc = tid & 15;
    float best[4]; int bidx[4];
#pragma unroll
    for (int i = 0; i < 4; ++i) { best[i] = 3.4e38f; bidx[i] = 0; }
    for (int kc = 0; kc < K_CENT; kc += 64) {
        float acc[16];
#pragma unroll
        for (int i = 0; i < 16; ++i) acc[i] = 0.0f;
        for (int kd = 0; kd < D_DIM; kd += 32) {
            const float4 xv0 = *(const float4*)&x[(size_t)(row0 + xr) * D_DIM + kd + xc * 4];
            const float4 xv1 = *(const float4*)&x[(size_t)(row0 + xr + 32) * D_DIM + kd + xc * 4];
            const float4 cv0 = *(const float4*)&Cm[(size_t)(kd + cr) * K_CENT + kc + cc * 4];
            const float4 cv1 = *(const float4*)&Cm[(size_t)(kd + cr + 16) * K_CENT + kc + cc * 4];
            __syncthreads();
            xs[xc*4+0][xr] = xv0.x; xs[xc*4+1][xr] = xv0.y; xs[xc*4+2][xr] = xv0.z; xs[xc*4+3][xr] = xv0.w;
            xs[xc*4+0][xr+32] = xv1.x; xs[xc*4+1][xr+32] = xv1.y; xs[xc*4+2][xr+32] = xv1.z; xs[xc*4+3][xr+32] = xv1.w;
            *(float4*)&cs[cr][cc*4]    = cv0;
            *(float4*)&cs[cr+16][cc*4] = cv1;
            __syncthreads();
#pragma unroll
            for (int kk = 0; kk < 32; ++kk) {
                const float4 a = *(const float4*)&xs[kk][ty*4];
                const float4 b = *(const float4*)&cs[kk][tx*4];
                acc[ 0] += a.x*b.x; acc[ 1] += a.x*b.y; acc[ 2] += a.x*b.z; acc[ 3] += a.x*b.w;
                acc[ 4] += a.y*b.x; acc[ 5] += a.y*b.y; acc[ 6] += a.y*b.z; acc[ 7] += a.y*b.w;
                acc[ 8] += a.z*b.x; acc[ 9] += a.z*b.y; acc[10] += a.z*b.z; acc[11] += a.z*b.w;
                acc[12] += a.w*b.x; acc[13] += a.w*b.y; acc[14] += a.w*b.z; acc[15] += a.w*b.w;
            }
        }
        const float4 cn = *(const float4*)&Cnorm[kc + tx*4];
        const float cnv[4] = {cn.x, cn.y, cn.z, cn.w};
#pragma unroll
        for (int i = 0; i < 4; ++i)
#pragma unroll
            for (int j = 0; j < 4; ++j) {
                const float dist = cnv[j] - 2.0f * acc[i*4+j];
                const int   idx  = kc + tx*4 + j;
                if (dist < best[i]) { best[i] = dist; bidx[i] = idx; }
            }
    }
#pragma unroll
    for (int i = 0; i < 4; ++i) {
        float d = best[i]; int ix = bidx[i];
#pragma unroll
        for (int off = 1; off < 16; off <<= 1) {
            const float od = __shfl_xor(d, off, 64);
            const int   oi = __shfl_xor(ix, off, 64);
            if (od < d || (od == d && oi < ix)) { d = od; ix = oi; }
        }
        if (tx == 0) out[row0 + ty*4 + i] = ix;
    }
}

// ============================================================================
extern "C" void kernel_launch(void* const* d_in, const int* in_sizes, int n_in,
                              void* d_out, int out_size, void* d_ws, size_t ws_size,
                              hipStream_t stream) {
    const float* x     = (const float*)d_in[0];
    const float* C     = (const float*)d_in[1];
    const float* Cnorm = (const float*)d_in[2];
    int* out = (int*)d_out;

    const size_t chalf = (size_t)K_CENT * D_DIM;             // halves per C array
    const size_t capd  = (size_t)CAP * D_DIM;                // halves per xc array
    const size_t need_full = (2 * chalf + 2 * capd) * sizeof(_Float16)
                           + (size_t)(2 * N_ROWS) * (4 + 4 + 4)   // m1/i1/m2 per half
                           + (size_t)(CAP + 16) * sizeof(int);
    const size_t need_r3   = 2 * chalf * sizeof(_Float16);

    if (ws_size >= need_full) {
        _Float16* ChiT = (_Float16*)d_ws;
        _Float16* CloT = ChiT + chalf;
        _Float16* xch  = CloT + chalf;
        _Float16* xcl  = xch + capd;
        float* m1buf = (float*)(xcl + capd);
        float* m2buf = m1buf + 2 * N_ROWS;
        int*   i1buf = (int*)(m2buf + 2 * N_ROWS);
        int*   urows = i1buf + 2 * N_ROWS;
        unsigned int* ucount = (unsigned int*)(urows + CAP);

        convert_C_kernel<<<dim3(128, 32), 256, 0, stream>>>(C, ChiT, CloT);
        hipMemsetAsync(ucount, 0, sizeof(unsigned int), stream);
        kmeans_pass1<<<dim3(512), 512, 0, stream>>>(x, ChiT, Cnorm, m1buf, i1buf, m2buf);
        kmeans_merge<<<dim3(N_ROWS / 256), 256, 0, stream>>>(m1buf, i1buf, m2buf, out, urows, ucount);
        kmeans_gather<<<dim3(CAP), 64, 0, stream>>>(x, urows, ucount, xch, xcl);
        kmeans_rescore<<<dim3(CAP / 16), 256, 0, stream>>>(xch, xcl, ChiT, CloT, Cnorm, urows, ucount, out);
    } else if (ws_size >= need_r3) {
        _Float16* ChiT = (_Float16*)d_ws;
        _Float16* CloT = ChiT + chalf;
        convert_C_kernel<<<dim3(128, 32), 256, 0, stream>>>(C, ChiT, CloT);
        kmeans_mfma_kernel<<<dim3(N_ROWS / BM), 512, 0, stream>>>(x, ChiT, CloT, Cnorm, out);
    } else {
        kmeans_assign_f32<<<dim3(N_ROWS / 64), 256, 0, stream>>>(x, C, Cnorm, out);
    }
}

// Round 6
// 605.343 us; speedup vs baseline: 1.6657x; 1.6266x over previous
//
#include <hip/hip_runtime.h>
#include <cstdint>
#include <cstddef>

typedef _Float16 half8 __attribute__((ext_vector_type(8)));
typedef _Float16 half4 __attribute__((ext_vector_type(4)));
typedef float    floatx4 __attribute__((ext_vector_type(4)));

constexpr int N_ROWS = 32768;
constexpr int D_DIM  = 1024;
constexpr int K_CENT = 4096;
constexpr int CAP    = 4096;      // max uncertain rows (E[count]~620)
constexpr int KSL    = 4;         // pass1 K split (1024 cols/slice)
constexpr int RSL    = 8;         // rescore K split (512 cols/slice)
constexpr float EPS_GAP = 0.4f;   // 2 * (14-sigma hh-error bound)

__device__ __forceinline__ void gload_lds16(const void* g, void* l) {
    __builtin_amdgcn_global_load_lds(
        (const __attribute__((address_space(1))) uint32_t*)g,
        (__attribute__((address_space(3))) uint32_t*)l, 16, 0, 0);
}

// ============================================================================
// Pre-pass 1: C[d][k] f32 -> C_hiT[k][d], C_loT[k][d] fp16 (transposed split)
// ============================================================================
__global__ __launch_bounds__(256) void convert_C_kernel(
    const float* __restrict__ C, _Float16* __restrict__ ChiT, _Float16* __restrict__ CloT)
{
    __shared__ float tile[32][33];
    const int bk = blockIdx.x, bd = blockIdx.y, t = threadIdx.x;
    const int r = t >> 3, c4 = (t & 7) * 4;
    const float4 v = *(const float4*)&C[(size_t)(bd * 32 + r) * K_CENT + bk * 32 + c4];
    tile[r][c4 + 0] = v.x; tile[r][c4 + 1] = v.y;
    tile[r][c4 + 2] = v.z; tile[r][c4 + 3] = v.w;
    __syncthreads();
    half4 h, l;
#pragma unroll
    for (int i = 0; i < 4; ++i) {
        const float f = tile[c4 + i][r];
        const _Float16 hi = (_Float16)f;
        h[i] = hi;
        l[i] = (_Float16)(f - (float)hi);
    }
    *(half4*)&ChiT[(size_t)(bk * 32 + r) * D_DIM + bd * 32 + c4] = h;
    *(half4*)&CloT[(size_t)(bk * 32 + r) * D_DIM + bd * 32 + c4] = l;
}

// ============================================================================
// Pre-pass 2: x f32 -> x_hi fp16 (elementwise, same layout)
// ============================================================================
__global__ __launch_bounds__(256) void convert_x_kernel(
    const float* __restrict__ x, _Float16* __restrict__ xh)
{
    const size_t g = (size_t)blockIdx.x * 256 + threadIdx.x;   // 8 elems each
    const float4 v0 = *(const float4*)&x[g * 8];
    const float4 v1 = *(const float4*)&x[g * 8 + 4];
    half8 h;
    h[0] = (_Float16)v0.x; h[1] = (_Float16)v0.y; h[2] = (_Float16)v0.z; h[3] = (_Float16)v0.w;
    h[4] = (_Float16)v1.x; h[5] = (_Float16)v1.y; h[6] = (_Float16)v1.z; h[7] = (_Float16)v1.w;
    *(half8*)&xh[g * 8] = h;
}

// ============================================================================
// Pass 1 (m97 geometry): hh-only GEMM, 128x128 tile, 256 thr / 4 waves,
// wave = 64x64 (4x4 frags), BK=32, dbuf, K-split x4.
// 3 blocks/CU co-resident (reg-capped via __launch_bounds__(256,3)).
// XCD-bijective decode: each XCD owns one K-slice (2MB C_hi in its L2).
// ============================================================================
constexpr int P_XH = 0;        // x_hi [8 sub][16 r][4 kg][8]  = 4096 halves
constexpr int P_CH = 4096;     // C_hi [8 sub][16 c][4 kg][8]  = 4096 halves
constexpr int P_HB = 8192;     // halves per buffer (16 KB)

__device__ __forceinline__ void write_x1(_Float16* buf, const float4 v, int r, int kb) {
    const _Float16 h0 = (_Float16)v.x, h1 = (_Float16)v.y;
    const _Float16 h2 = (_Float16)v.z, h3 = (_Float16)v.w;
    const int kg  = kb >> 3;
    const int hs  = (kb >> 2) & 1;
    const int kge = kg ^ ((r >> 1) & 3);
    const int base = (r >> 4) * 512 + (r & 15) * 32 + kge * 8 + hs * 4;
    *(half4*)(buf + P_XH + base) = (half4){h0, h1, h2, h3};
}

template<bool XPRE>
__global__ __launch_bounds__(256, 3) void kmeans_pass1(
    const float* __restrict__ x, const _Float16* __restrict__ xh,
    const _Float16* __restrict__ ChiT, const float* __restrict__ Cnorm,
    float* __restrict__ m1buf, int* __restrict__ i1buf, float* __restrict__ m2buf)
{
    __shared__ _Float16 lds[2][P_HB];
    __shared__ float red_d[2][64][2];
    __shared__ int   red_i[2][64][2];
    __shared__ float red_2[2][64][2];

    // bijective: xcd = bid&7; ks = xcd&3 (K-slice); rb = (bid>>3)*2 + (xcd>>2)
    const int bid  = blockIdx.x;
    const int xcd  = bid & 7;
    const int ks   = xcd & 3;
    const int rb   = (bid >> 3) * 2 + (xcd >> 2);
    const int row0 = rb * 128;
    const int kb0  = ks * (K_CENT / KSL);

    const int tid  = threadIdx.x;
    const int lane = tid & 63;
    const int wid  = tid >> 6;          // 0..3
    const int wm   = wid >> 1;          // 0..1 row half
    const int wn   = wid & 1;           // 0..1 col half

    const int l15 = lane & 15;
    const int l4  = lane >> 4;
    const int kge = l4 ^ ((l15 >> 1) & 3);
    const int fragoff = l15 * 32 + kge * 8;

    // staging lane mapping (gload): subtile row/col + pre-swizzled k-group
    const int scol = lane >> 2;                       // 0..15
    const int skg  = (lane & 3) ^ ((scol >> 1) & 3);
    // inline-cvt x mapping (XPRE=false): 2 threads/row, 16 k's each
    const int sr = tid >> 1;            // 0..127
    const int sc = tid & 1;             // 0..1

    float b1[4][4], b2[4][4];
    int   bi[4][4];
#pragma unroll
    for (int i = 0; i < 4; ++i)
#pragma unroll
        for (int r = 0; r < 4; ++r) { b1[i][r] = 3.4e38f; b2[i][r] = 3.4e38f; bi[i][r] = 0; }

    for (int kc = kb0; kc < kb0 + K_CENT / KSL; kc += 128) {
        floatx4 acc[4][4];
#pragma unroll
        for (int i = 0; i < 4; ++i)
#pragma unroll
            for (int j = 0; j < 4; ++j) acc[i][j] = (floatx4)0.0f;

        {   // prologue: stage kd=0 into buf 0
            _Float16* buf = lds[0];
#pragma unroll
            for (int q = 0; q < 2; ++q) {
                const int sub = wid * 2 + q;
                gload_lds16(&ChiT[(size_t)(kc + sub * 16 + scol) * D_DIM + 0 + skg * 8], buf + P_CH + sub * 512);
                if (XPRE)
                    gload_lds16(&xh[(size_t)(row0 + sub * 16 + scol) * D_DIM + 0 + skg * 8], buf + P_XH + sub * 512);
            }
            if (!XPRE) {
#pragma unroll
                for (int jj = 0; jj < 4; ++jj) {
                    const float4 v = *(const float4*)&x[(size_t)(row0 + sr) * D_DIM + 0 + sc * 16 + jj * 4];
                    write_x1(buf, v, sr, sc * 16 + jj * 4);
                }
            }
            __syncthreads();
        }

        for (int kdi = 0; kdi < D_DIM / 32; ++kdi) {
            const int cur = kdi & 1;
            _Float16* bufc = lds[cur];
            _Float16* bufn = lds[cur ^ 1];
            const int  kdn = (kdi + 1) * 32;
            const bool pf  = (kdi + 1 < D_DIM / 32);

            float4 xv[4];
            if (pf) {
#pragma unroll
                for (int q = 0; q < 2; ++q) {
                    const int sub = wid * 2 + q;
                    gload_lds16(&ChiT[(size_t)(kc + sub * 16 + scol) * D_DIM + kdn + skg * 8], bufn + P_CH + sub * 512);
                    if (XPRE)
                        gload_lds16(&xh[(size_t)(row0 + sub * 16 + scol) * D_DIM + kdn + skg * 8], bufn + P_XH + sub * 512);
                }
                if (!XPRE) {
#pragma unroll
                    for (int jj = 0; jj < 4; ++jj)
                        xv[jj] = *(const float4*)&x[(size_t)(row0 + sr) * D_DIM + kdn + sc * 16 + jj * 4];
                }
            }

            half8 ah[4], bh[4];
#pragma unroll
            for (int i = 0; i < 4; ++i)
                ah[i] = *(const half8*)(bufc + P_XH + (wm * 4 + i) * 512 + fragoff);
#pragma unroll
            for (int j = 0; j < 4; ++j)
                bh[j] = *(const half8*)(bufc + P_CH + (wn * 4 + j) * 512 + fragoff);

#pragma unroll
            for (int i = 0; i < 4; ++i)
#pragma unroll
                for (int j = 0; j < 4; ++j)
                    acc[i][j] = __builtin_amdgcn_mfma_f32_16x16x32_f16(ah[i], bh[j], acc[i][j], 0, 0, 0);

            if (pf && !XPRE) {
#pragma unroll
                for (int jj = 0; jj < 4; ++jj)
                    write_x1(bufn, xv[jj], sr, sc * 16 + jj * 4);
            }
            __syncthreads();
        }

        // argmin epilogue with second-min tracking (cols ascending -> strict <)
        const int colw = kc + wn * 64;
#pragma unroll
        for (int ns = 0; ns < 4; ++ns) {
            const float cn = Cnorm[colw + ns * 16 + l15];
            const int   ix = colw + ns * 16 + l15;
#pragma unroll
            for (int i = 0; i < 4; ++i)
#pragma unroll
                for (int r = 0; r < 4; ++r) {
                    const float d = fmaf(-2.0f, acc[i][ns][r], cn);
                    if (d < b1[i][r]) { b2[i][r] = b1[i][r]; b1[i][r] = d; bi[i][r] = ix; }
                    else if (d < b2[i][r]) { b2[i][r] = d; }
                }
        }
    }

    // per-wave reduce over 16 col-lanes, merging (m1,i1,m2)
#pragma unroll
    for (int i = 0; i < 4; ++i)
#pragma unroll
        for (int r = 0; r < 4; ++r) {
            float m1 = b1[i][r], m2 = b2[i][r];
            int   i1 = bi[i][r];
#pragma unroll
            for (int off = 1; off < 16; off <<= 1) {
                const float om1 = __shfl_xor(m1, off, 64);
                const int   oi  = __shfl_xor(i1, off, 64);
                const float om2 = __shfl_xor(m2, off, 64);
                const float nm2 = fminf(fminf(m2, om2), fmaxf(m1, om1));
                if (om1 < m1 || (om1 == m1 && oi < i1)) { m1 = om1; i1 = oi; }
                m2 = nm2;
            }
            if (l15 == 0) {
                const int rr = i * 16 + l4 * 4 + r;
                red_d[wm][rr][wn] = m1;
                red_i[wm][rr][wn] = i1;
                red_2[wm][rr][wn] = m2;
            }
        }
    __syncthreads();

    if (tid < 128) {
        const int hh = tid >> 6;
        const int rr = tid & 63;
        float m1 = red_d[hh][rr][0], m2 = red_2[hh][rr][0];
        int   i1 = red_i[hh][rr][0];
        const float om1 = red_d[hh][rr][1];
        const int   oi  = red_i[hh][rr][1];
        const float om2 = red_2[hh][rr][1];
        m2 = fminf(fminf(m2, om2), fmaxf(m1, om1));
        if (om1 < m1 || (om1 == m1 && oi < i1)) { m1 = om1; i1 = oi; }
        const size_t off = (size_t)ks * N_ROWS + row0 + tid;
        m1buf[off] = m1;
        i1buf[off] = i1;
        m2buf[off] = m2;
    }
}

// ============================================================================
// Merge 4 K-slices: final argmin + certainty test + worklist
// ============================================================================
__global__ __launch_bounds__(256) void kmeans_merge4(
    const float* __restrict__ m1buf, const int* __restrict__ i1buf,
    const float* __restrict__ m2buf, int* __restrict__ out,
    int* __restrict__ urows, unsigned int* __restrict__ ucount)
{
    const int row = blockIdx.x * 256 + threadIdx.x;
    float m1 = m1buf[row], m2 = m2buf[row];
    int   i1 = i1buf[row];
#pragma unroll
    for (int s = 1; s < KSL; ++s) {
        const float om1 = m1buf[(size_t)s * N_ROWS + row];
        const float om2 = m2buf[(size_t)s * N_ROWS + row];
        const int   oi  = i1buf[(size_t)s * N_ROWS + row];
        const float nm2 = fminf(fminf(m2, om2), fmaxf(m1, om1));
        if (om1 < m1 || (om1 == m1 && oi < i1)) { m1 = om1; i1 = oi; }
        m2 = nm2;
    }
    out[row] = i1;
    if (m2 - m1 <= EPS_GAP) {
        const unsigned slot = atomicAdd(ucount, 1u);
        if (slot < (unsigned)CAP) urows[slot] = row;
    }
}

// ============================================================================
// Gather: uncertain rows' x -> compact fp16 hi/lo buffers [slot][1024]
// ============================================================================
__global__ __launch_bounds__(64) void kmeans_gather(
    const float* __restrict__ x, const int* __restrict__ urows,
    const unsigned int* __restrict__ ucount,
    _Float16* __restrict__ xch, _Float16* __restrict__ xcl)
{
    const unsigned cntr = *ucount;
    const unsigned cnt = cntr > (unsigned)CAP ? (unsigned)CAP : cntr;
    const unsigned slot = blockIdx.x;
    if (slot >= cnt) return;
    const int row = urows[slot];
    const int t = threadIdx.x;
#pragma unroll
    for (int e = 0; e < 16; ++e) {
        const int idx = e * 64 + t;
        const float v = x[(size_t)row * D_DIM + idx];
        const _Float16 h = (_Float16)v;
        xch[(size_t)slot * D_DIM + idx] = h;
        xcl[(size_t)slot * D_DIM + idx] = (_Float16)(v - (float)h);
    }
}

// ============================================================================
// Rescore (K-split x8): exact 3-pass hi/lo over 512-col slice for 32 rows.
// Writes per-slice (m1,i1) partials; merge2 finalizes.
// ============================================================================
constexpr int R_XH = 0;        // 1024 halves (2 sub)
constexpr int R_XL = 1024;     // 1024
constexpr int R_CH = 2048;     // 8192 (16 sub)
constexpr int R_CL = 10240;    // 8192
constexpr int R_HB = 18432;    // per buffer (36 KB)

__global__ __launch_bounds__(256) void kmeans_rescore2(
    const _Float16* __restrict__ xch, const _Float16* __restrict__ xcl,
    const _Float16* __restrict__ ChiT, const _Float16* __restrict__ CloT,
    const float* __restrict__ Cnorm, const unsigned int* __restrict__ ucount,
    float* __restrict__ rpd, int* __restrict__ rpi)
{
    const unsigned cntr = *ucount;
    const unsigned cnt = cntr > (unsigned)CAP ? (unsigned)CAP : cntr;
    const int bid = blockIdx.x;
    const int ksl = bid & 7;            // K slice (512 cols)
    const int grp = bid >> 3;           // 32-row slot group
    if ((unsigned)(grp * 32) >= cnt) return;

    __shared__ _Float16 lds[2][R_HB];
    __shared__ float rd[32][4];
    __shared__ int   ri[32][4];

    const int tid  = threadIdx.x;
    const int lane = tid & 63;
    const int wid  = tid >> 6;          // 0..3 = col quarter (64 cols)
    const int l15  = lane & 15;
    const int l4   = lane >> 4;
    const int kge  = l4 ^ ((l15 >> 1) & 3);
    const int fragoff = l15 * 32 + kge * 8;
    const int scol = lane >> 2;
    const int skg  = (lane & 3) ^ ((scol >> 1) & 3);

    const int base  = grp * 32;
    const int kbase = ksl * (K_CENT / RSL);

    float best[2][4];
    int   bidx[2][4];
#pragma unroll
    for (int i = 0; i < 2; ++i)
#pragma unroll
        for (int r = 0; r < 4; ++r) { best[i][r] = 3.4e38f; bidx[i][r] = 0; }

    for (int ch = 0; ch < 2; ++ch) {
        const int kc = kbase + ch * 256;
        floatx4 acc[2][4];
#pragma unroll
        for (int i = 0; i < 2; ++i)
#pragma unroll
            for (int j = 0; j < 4; ++j) acc[i][j] = (floatx4)0.0f;

        {   // prologue: stage kd=0
            _Float16* buf = lds[0];
#pragma unroll
            for (int q = 0; q < 4; ++q) {
                const int sub = wid * 4 + q;
                gload_lds16(&ChiT[(size_t)(kc + sub * 16 + scol) * D_DIM + 0 + skg * 8], buf + R_CH + sub * 512);
                gload_lds16(&CloT[(size_t)(kc + sub * 16 + scol) * D_DIM + 0 + skg * 8], buf + R_CL + sub * 512);
            }
            if (wid < 2)
                gload_lds16(&xch[(size_t)(base + wid * 16 + scol) * D_DIM + 0 + skg * 8], buf + R_XH + wid * 512);
            else
                gload_lds16(&xcl[(size_t)(base + (wid - 2) * 16 + scol) * D_DIM + 0 + skg * 8], buf + R_XL + (wid - 2) * 512);
            __syncthreads();
        }

        for (int kdi = 0; kdi < D_DIM / 32; ++kdi) {
            const int cur = kdi & 1;
            _Float16* bufc = lds[cur];
            _Float16* bufn = lds[cur ^ 1];
            const int  kdn = (kdi + 1) * 32;
            const bool pf  = (kdi + 1 < D_DIM / 32);

            if (pf) {
#pragma unroll
                for (int q = 0; q < 4; ++q) {
                    const int sub = wid * 4 + q;
                    gload_lds16(&ChiT[(size_t)(kc + sub * 16 + scol) * D_DIM + kdn + skg * 8], bufn + R_CH + sub * 512);
                    gload_lds16(&CloT[(size_t)(kc + sub * 16 + scol) * D_DIM + kdn + skg * 8], bufn + R_CL + sub * 512);
                }
                if (wid < 2)
                    gload_lds16(&xch[(size_t)(base + wid * 16 + scol) * D_DIM + kdn + skg * 8], bufn + R_XH + wid * 512);
                else
                    gload_lds16(&xcl[(size_t)(base + (wid - 2) * 16 + scol) * D_DIM + kdn + skg * 8], bufn + R_XL + (wid - 2) * 512);
            }

            half8 ah[2], al[2], bh[4], bl[4];
#pragma unroll
            for (int i = 0; i < 2; ++i) {
                ah[i] = *(const half8*)(bufc + R_XH + i * 512 + fragoff);
                al[i] = *(const half8*)(bufc + R_XL + i * 512 + fragoff);
            }
#pragma unroll
            for (int j = 0; j < 4; ++j) {
                bh[j] = *(const half8*)(bufc + R_CH + (wid * 4 + j) * 512 + fragoff);
                bl[j] = *(const half8*)(bufc + R_CL + (wid * 4 + j) * 512 + fragoff);
            }
#pragma unroll
            for (int i = 0; i < 2; ++i)
#pragma unroll
                for (int j = 0; j < 4; ++j) {
                    acc[i][j] = __builtin_amdgcn_mfma_f32_16x16x32_f16(ah[i], bh[j], acc[i][j], 0, 0, 0);
                    acc[i][j] = __builtin_amdgcn_mfma_f32_16x16x32_f16(ah[i], bl[j], acc[i][j], 0, 0, 0);
                    acc[i][j] = __builtin_amdgcn_mfma_f32_16x16x32_f16(al[i], bh[j], acc[i][j], 0, 0, 0);
                }
            __syncthreads();
        }

        // epilogue for this 256-col chunk
#pragma unroll
        for (int j = 0; j < 4; ++j) {
            const int col = kc + wid * 64 + j * 16 + l15;   // NOTE: wave owns cols wid*64..+63
            const float cn = Cnorm[col];
#pragma unroll
            for (int i = 0; i < 2; ++i)
#pragma unroll
                for (int r = 0; r < 4; ++r) {
                    const float d = fmaf(-2.0f, acc[i][j][r], cn);
                    if (d < best[i][r]) { best[i][r] = d; bidx[i][r] = col; }
                }
        }
    }

    // reduce over 16 col-lanes, then cross-wave
#pragma unroll
    for (int i = 0; i < 2; ++i)
#pragma unroll
        for (int r = 0; r < 4; ++r) {
            float m1 = best[i][r];
            int   i1 = bidx[i][r];
#pragma unroll
            for (int off = 1; off < 16; off <<= 1) {
                const float om1 = __shfl_xor(m1, off, 64);
                const int   oi  = __shfl_xor(i1, off, 64);
                if (om1 < m1 || (om1 == m1 && oi < i1)) { m1 = om1; i1 = oi; }
            }
            if (l15 == 0) { rd[i * 16 + l4 * 4 + r][wid] = m1; ri[i * 16 + l4 * 4 + r][wid] = i1; }
        }
    __syncthreads();

    if (tid < 32) {
        float m1 = rd[tid][0];
        int   i1 = ri[tid][0];
#pragma unroll
        for (int w = 1; w < 4; ++w) {
            const float om1 = rd[tid][w];
            const int   oi  = ri[tid][w];
            if (om1 < m1 || (om1 == m1 && oi < i1)) { m1 = om1; i1 = oi; }
        }
        rpd[(size_t)(base + tid) * RSL + ksl] = m1;
        rpi[(size_t)(base + tid) * RSL + ksl] = i1;
    }
}

// ============================================================================
// Merge rescore slices -> final out for uncertain rows
// ============================================================================
__global__ __launch_bounds__(256) void kmeans_merge2(
    const float* __restrict__ rpd, const int* __restrict__ rpi,
    const int* __restrict__ urows, const unsigned int* __restrict__ ucount,
    int* __restrict__ out)
{
    const unsigned cntr = *ucount;
    const unsigned cnt = cntr > (unsigned)CAP ? (unsigned)CAP : cntr;
    const unsigned s = blockIdx.x * 256 + threadIdx.x;
    if (s >= cnt) return;
    float m1 = rpd[(size_t)s * RSL];
    int   i1 = rpi[(size_t)s * RSL];
#pragma unroll
    for (int k = 1; k < RSL; ++k) {
        const float om = rpd[(size_t)s * RSL + k];
        const int   oi = rpi[(size_t)s * RSL + k];
        if (om < m1 || (om == m1 && oi < i1)) { m1 = om; i1 = oi; }
    }
    out[urows[s]] = i1;
}

// ============================================================================
// Fallback A: proven R3 3-pass MFMA kernel (hi/lo, direct out)
// ============================================================================
constexpr int F_XH = 0, F_XL = 4096, F_CH = 8192, F_CL = 16384, F_HB = 24576;

__device__ __forceinline__ void write_x2(_Float16* buf, const float4 v, int r, int kb) {
    const _Float16 h0 = (_Float16)v.x, h1 = (_Float16)v.y;
    const _Float16 h2 = (_Float16)v.z, h3 = (_Float16)v.w;
    const int kg  = kb >> 3;
    const int hs  = (kb >> 2) & 1;
    const int kge = kg ^ ((r >> 1) & 3);
    const int base = (r >> 4) * 512 + (r & 15) * 32 + kge * 8 + hs * 4;
    *(half4*)(buf + F_XH + base) = (half4){h0, h1, h2, h3};
    *(half4*)(buf + F_XL + base) = (half4){(_Float16)(v.x - (float)h0), (_Float16)(v.y - (float)h1),
                                           (_Float16)(v.z - (float)h2), (_Float16)(v.w - (float)h3)};
}

__global__ __launch_bounds__(512, 2) void kmeans_mfma_kernel(
    const float* __restrict__ x, const _Float16* __restrict__ ChiT,
    const _Float16* __restrict__ CloT, const float* __restrict__ Cnorm,
    int* __restrict__ out)
{
    __shared__ _Float16 lds[2][F_HB];
    __shared__ float red_d[2][64][4];
    __shared__ int   red_i[2][64][4];

    const int tid  = threadIdx.x;
    const int lane = tid & 63;
    const int wid  = tid >> 6;
    const int wm   = wid >> 2;
    const int wn   = wid & 3;
    const int row0 = blockIdx.x * 128;
    const int l15 = lane & 15;
    const int l4  = lane >> 4;
    const int kge = l4 ^ ((l15 >> 1) & 3);
    const int fragoff = l15 * 32 + kge * 8;
    const int sr = tid >> 2, sc = tid & 3;
    const int ccol = lane >> 2;
    const int ckg  = (lane & 3) ^ ((ccol >> 1) & 3);

    float best[4][4];
    int   bidx[4][4];
#pragma unroll
    for (int i = 0; i < 4; ++i)
#pragma unroll
        for (int r = 0; r < 4; ++r) { best[i][r] = 3.4e38f; bidx[i][r] = 0; }

    for (int kc = 0; kc < K_CENT; kc += 256) {
        floatx4 acc[4][4];
#pragma unroll
        for (int i = 0; i < 4; ++i)
#pragma unroll
            for (int j = 0; j < 4; ++j) acc[i][j] = (floatx4)0.0f;
        {
            _Float16* buf = lds[0];
            const float4 xv0 = *(const float4*)&x[(size_t)(row0 + sr) * D_DIM + 0 + sc * 4];
            const float4 xv1 = *(const float4*)&x[(size_t)(row0 + sr) * D_DIM + 16 + sc * 4];
            gload_lds16(&ChiT[(size_t)(kc + wid * 16 + ccol) * D_DIM + 0 + ckg * 8], buf + F_CH + wid * 512);
            gload_lds16(&ChiT[(size_t)(kc + (wid + 8) * 16 + ccol) * D_DIM + 0 + ckg * 8], buf + F_CH + (wid + 8) * 512);
            gload_lds16(&CloT[(size_t)(kc + wid * 16 + ccol) * D_DIM + 0 + ckg * 8], buf + F_CL + wid * 512);
            gload_lds16(&CloT[(size_t)(kc + (wid + 8) * 16 + ccol) * D_DIM + 0 + ckg * 8], buf + F_CL + (wid + 8) * 512);
            write_x2(buf, xv0, sr, sc * 4);
            write_x2(buf, xv1, sr, sc * 4 + 16);
            __syncthreads();
        }
        for (int kdi = 0; kdi < D_DIM / 32; ++kdi) {
            const int cur = kdi & 1;
            _Float16* bufc = lds[cur];
            _Float16* bufn = lds[cur ^ 1];
            const int  kdn = (kdi + 1) * 32;
            const bool pf  = (kdi + 1 < D_DIM / 32);
            float4 xv0, xv1;
            if (pf) {
                xv0 = *(const float4*)&x[(size_t)(row0 + sr) * D_DIM + kdn + sc * 4];
                xv1 = *(const float4*)&x[(size_t)(row0 + sr) * D_DIM + kdn + 16 + sc * 4];
                gload_lds16(&ChiT[(size_t)(kc + wid * 16 + ccol) * D_DIM + kdn + ckg * 8], bufn + F_CH + wid * 512);
                gload_lds16(&ChiT[(size_t)(kc + (wid + 8) * 16 + ccol) * D_DIM + kdn + ckg * 8], bufn + F_CH + (wid + 8) * 512);
                gload_lds16(&CloT[(size_t)(kc + wid * 16 + ccol) * D_DIM + kdn + ckg * 8], bufn + F_CL + wid * 512);
                gload_lds16(&CloT[(size_t)(kc + (wid + 8) * 16 + ccol) * D_DIM + kdn + ckg * 8], bufn + F_CL + (wid + 8) * 512);
            }
            half8 ah[4], al[4], bh[4], bl[4];
#pragma unroll
            for (int i = 0; i < 4; ++i) {
                ah[i] = *(const half8*)(bufc + F_XH + (wm * 4 + i) * 512 + fragoff);
                al[i] = *(const half8*)(bufc + F_XL + (wm * 4 + i) * 512 + fragoff);
            }
#pragma unroll
            for (int j = 0; j < 4; ++j) {
                bh[j] = *(const half8*)(bufc + F_CH + (wn * 4 + j) * 512 + fragoff);
                bl[j] = *(const half8*)(bufc + F_CL + (wn * 4 + j) * 512 + fragoff);
            }
#pragma unroll
            for (int i = 0; i < 4; ++i)
#pragma unroll
                for (int j = 0; j < 4; ++j) {
                    acc[i][j] = __builtin_amdgcn_mfma_f32_16x16x32_f16(ah[i], bh[j], acc[i][j], 0, 0, 0);
                    acc[i][j] = __builtin_amdgcn_mfma_f32_16x16x32_f16(ah[i], bl[j], acc[i][j], 0, 0, 0);
                    acc[i][j] = __builtin_amdgcn_mfma_f32_16x16x32_f16(al[i], bh[j], acc[i][j], 0, 0, 0);
                }
            if (pf) {
                write_x2(bufn, xv0, sr, sc * 4);
                write_x2(bufn, xv1, sr, sc * 4 + 16);
            }
            __syncthreads();
        }
        const int colw = kc + wn * 64;
#pragma unroll
        for (int ns = 0; ns < 4; ++ns) {
            const float cn = Cnorm[colw + ns * 16 + l15];
            const int   ix = colw + ns * 16 + l15;
#pragma unroll
            for (int i = 0; i < 4; ++i)
#pragma unroll
                for (int r = 0; r < 4; ++r) {
                    const float d = fmaf(-2.0f, acc[i][ns][r], cn);
                    if (d < best[i][r]) { best[i][r] = d; bidx[i][r] = ix; }
                }
        }
    }
#pragma unroll
    for (int i = 0; i < 4; ++i)
#pragma unroll
        for (int r = 0; r < 4; ++r) {
            float d  = best[i][r];
            int   ix = bidx[i][r];
#pragma unroll
            for (int off = 1; off < 16; off <<= 1) {
                const float od = __shfl_xor(d, off, 64);
                const int   oi = __shfl_xor(ix, off, 64);
                if (od < d || (od == d && oi < ix)) { d = od; ix = oi; }
            }
            if (l15 == 0) {
                red_d[wm][i * 16 + l4 * 4 + r][wn] = d;
                red_i[wm][i * 16 + l4 * 4 + r][wn] = ix;
            }
        }
    __syncthreads();
    if (tid < 128) {
        const int hh = tid >> 6, rr = tid & 63;
        float bd = red_d[hh][rr][0];
        int   bi2 = red_i[hh][rr][0];
#pragma unroll
        for (int w = 1; w < 4; ++w) {
            const float od = red_d[hh][rr][w];
            const int   oi = red_i[hh][rr][w];
            if (od < bd || (od == bd && oi < bi2)) { bd = od; bi2 = oi; }
        }
        out[row0 + tid] = bi2;
    }
}

// ============================================================================
// Fallback B: R1 fp32 kernel
// ============================================================================
__global__ __launch_bounds__(256, 2) void kmeans_assign_f32(
    const float* __restrict__ x, const float* __restrict__ Cm,
    const float* __restrict__ Cnorm, int* __restrict__ out)
{
    __shared__ float xs[32][64];
    __shared__ float cs[32][64];
    const int tid = threadIdx.x;
    const int tx = tid & 15, ty = tid >> 4;
    const int row0 = blockIdx.x * 64;
    const int xr = tid >> 3, xc = tid & 7;
    const int cr = tid >> 4, cc = tid & 15;
    float best[4]; int bidx[4];
#pragma unroll
    for (int i = 0; i < 4; ++i) { best[i] = 3.4e38f; bidx[i] = 0; }
    for (int kc = 0; kc < K_CENT; kc += 64) {
        float acc[16];
#pragma unroll
        for (int i = 0; i < 16; ++i) acc[i] = 0.0f;
        for (int kd = 0; kd < D_DIM; kd += 32) {
            const float4 xv0 = *(const float4*)&x[(size_t)(row0 + xr) * D_DIM + kd + xc * 4];
            const float4 xv1 = *(const float4*)&x[(size_t)(row0 + xr + 32) * D_DIM + kd + xc * 4];
            const float4 cv0 = *(const float4*)&Cm[(size_t)(kd + cr) * K_CENT + kc + cc * 4];
            const float4 cv1 = *(const float4*)&Cm[(size_t)(kd + cr + 16) * K_CENT + kc + cc * 4];
            __syncthreads();
            xs[xc*4+0][xr] = xv0.x; xs[xc*4+1][xr] = xv0.y; xs[xc*4+2][xr] = xv0.z; xs[xc*4+3][xr] = xv0.w;
            xs[xc*4+0][xr+32] = xv1.x; xs[xc*4+1][xr+32] = xv1.y; xs[xc*4+2][xr+32] = xv1.z; xs[xc*4+3][xr+32] = xv1.w;
            *(float4*)&cs[cr][cc*4]    = cv0;
            *(float4*)&cs[cr+16][cc*4] = cv1;
            __syncthreads();
#pragma unroll
            for (int kk = 0; kk < 32; ++kk) {
                const float4 a = *(const float4*)&xs[kk][ty*4];
                const float4 b = *(const float4*)&cs[kk][tx*4];
                acc[ 0] += a.x*b.x; acc[ 1] += a.x*b.y; acc[ 2] += a.x*b.z; acc[ 3] += a.x*b.w;
                acc[ 4] += a.y*b.x; acc[ 5] += a.y*b.y; acc[ 6] += a.y*b.z; acc[ 7] += a.y*b.w;
                acc[ 8] += a.z*b.x; acc[ 9] += a.z*b.y; acc[10] += a.z*b.z; acc[11] += a.z*b.w;
                acc[12] += a.w*b.x; acc[13] += a.w*b.y; acc[14] += a.w*b.z; acc[15] += a.w*b.w;
            }
        }
        const float4 cn = *(const float4*)&Cnorm[kc + tx*4];
        const float cnv[4] = {cn.x, cn.y, cn.z, cn.w};
#pragma unroll
        for (int i = 0; i < 4; ++i)
#pragma unroll
            for (int j = 0; j < 4; ++j) {
                const float dist = cnv[j] - 2.0f * acc[i*4+j];
                const int   idx  = kc + tx*4 + j;
                if (dist < best[i]) { best[i] = dist; bidx[i] = idx; }
            }
    }
#pragma unroll
    for (int i = 0; i < 4; ++i) {
        float d = best[i]; int ix = bidx[i];
#pragma unroll
        for (int off = 1; off < 16; off <<= 1) {
            const float od = __shfl_xor(d, off, 64);
            const int   oi = __shfl_xor(ix, off, 64);
            if (od < d || (od == d && oi < ix)) { d = od; ix = oi; }
        }
        if (tx == 0) out[row0 + ty*4 + i] = ix;
    }
}

// ============================================================================
extern "C" void kernel_launch(void* const* d_in, const int* in_sizes, int n_in,
                              void* d_out, int out_size, void* d_ws, size_t ws_size,
                              hipStream_t stream) {
    const float* x     = (const float*)d_in[0];
    const float* C     = (const float*)d_in[1];
    const float* Cnorm = (const float*)d_in[2];
    int* out = (int*)d_out;

    const size_t chalf = (size_t)K_CENT * D_DIM;   // halves per C array
    const size_t capd  = (size_t)CAP * D_DIM;      // halves per xc array
    const size_t xhN   = (size_t)N_ROWS * D_DIM;   // halves for x_hi

    // ws layout (bytes): ChiT, CloT, xch, xcl, m1, m2, i1, rpd, rpi, urows, ucount, [xh]
    const size_t sz_base = (2 * chalf + 2 * capd) * 2
                         + (size_t)KSL * N_ROWS * 12
                         + (size_t)CAP * RSL * 8
                         + (size_t)CAP * 4 + 64;
    const size_t need_v3   = sz_base;
    const size_t need_xpre = sz_base + xhN * 2;
    const size_t need_r3   = 2 * chalf * 2;

    if (ws_size >= need_v3) {
        _Float16* ChiT = (_Float16*)d_ws;
        _Float16* CloT = ChiT + chalf;
        _Float16* xch  = CloT + chalf;
        _Float16* xcl  = xch + capd;
        float* m1buf = (float*)(xcl + capd);
        float* m2buf = m1buf + (size_t)KSL * N_ROWS;
        int*   i1buf = (int*)(m2buf + (size_t)KSL * N_ROWS);
        float* rpd   = (float*)(i1buf + (size_t)KSL * N_ROWS);
        int*   rpi   = (int*)(rpd + (size_t)CAP * RSL);
        int*   urows = rpi + (size_t)CAP * RSL;
        unsigned int* ucount = (unsigned int*)(urows + CAP);
        _Float16* xh = (_Float16*)(ucount + 16);

        convert_C_kernel<<<dim3(128, 32), 256, 0, stream>>>(C, ChiT, CloT);
        hipMemsetAsync(ucount, 0, sizeof(unsigned int), stream);
        if (ws_size >= need_xpre) {
            convert_x_kernel<<<dim3((int)(xhN / 2048)), 256, 0, stream>>>(x, xh);
            kmeans_pass1<true><<<dim3(256 * KSL), 256, 0, stream>>>(x, xh, ChiT, Cnorm, m1buf, i1buf, m2buf);
        } else {
            kmeans_pass1<false><<<dim3(256 * KSL), 256, 0, stream>>>(x, nullptr, ChiT, Cnorm, m1buf, i1buf, m2buf);
        }
        kmeans_merge4<<<dim3(N_ROWS / 256), 256, 0, stream>>>(m1buf, i1buf, m2buf, out, urows, ucount);
        kmeans_gather<<<dim3(CAP), 64, 0, stream>>>(x, urows, ucount, xch, xcl);
        kmeans_rescore2<<<dim3((CAP / 32) * RSL), 256, 0, stream>>>(xch, xcl, ChiT, CloT, Cnorm, ucount, rpd, rpi);
        kmeans_merge2<<<dim3(CAP / 256), 256, 0, stream>>>(rpd, rpi, urows, ucount, out);
    } else if (ws_size >= need_r3) {
        _Float16* ChiT = (_Float16*)d_ws;
        _Float16* CloT = ChiT + chalf;
        convert_C_kernel<<<dim3(128, 32), 256, 0, stream>>>(C, ChiT, CloT);
        kmeans_mfma_kernel<<<dim3(N_ROWS / 128), 512, 0, stream>>>(x, ChiT, CloT, Cnorm, out);
    } else {
        kmeans_assign_f32<<<dim3(N_ROWS / 64), 256, 0, stream>>>(x, C, Cnorm, out);
    }
}

// Round 7
// 574.653 us; speedup vs baseline: 1.7546x; 1.0534x over previous
//
#include <hip/hip_runtime.h>
#include <cstdint>
#include <cstddef>

typedef _Float16 half8 __attribute__((ext_vector_type(8)));
typedef _Float16 half4 __attribute__((ext_vector_type(4)));
typedef float    floatx4 __attribute__((ext_vector_type(4)));

constexpr int N_ROWS = 32768;
constexpr int D_DIM  = 1024;
constexpr int K_CENT = 4096;
constexpr int CAP    = 4096;      // max uncertain rows (E[count]~620)
constexpr int KSL    = 4;         // pass1 K split (1024 cols/slice)
constexpr int RSL    = 8;         // rescore K split (512 cols/slice)
constexpr float EPS_GAP = 0.4f;   // 2 * (14-sigma hh-error bound)

__device__ __forceinline__ void gload_lds16(const void* g, void* l) {
    __builtin_amdgcn_global_load_lds(
        (const __attribute__((address_space(1))) uint32_t*)g,
        (__attribute__((address_space(3))) uint32_t*)l, 16, 0, 0);
}

// ============================================================================
// Pre-pass 1: C[d][k] f32 -> C_hiT[k][d], C_loT[k][d] fp16 (transposed split)
// ============================================================================
__global__ __launch_bounds__(256) void convert_C_kernel(
    const float* __restrict__ C, _Float16* __restrict__ ChiT, _Float16* __restrict__ CloT)
{
    __shared__ float tile[32][33];
    const int bk = blockIdx.x, bd = blockIdx.y, t = threadIdx.x;
    const int r = t >> 3, c4 = (t & 7) * 4;
    const float4 v = *(const float4*)&C[(size_t)(bd * 32 + r) * K_CENT + bk * 32 + c4];
    tile[r][c4 + 0] = v.x; tile[r][c4 + 1] = v.y;
    tile[r][c4 + 2] = v.z; tile[r][c4 + 3] = v.w;
    __syncthreads();
    half4 h, l;
#pragma unroll
    for (int i = 0; i < 4; ++i) {
        const float f = tile[c4 + i][r];
        const _Float16 hi = (_Float16)f;
        h[i] = hi;
        l[i] = (_Float16)(f - (float)hi);
    }
    *(half4*)&ChiT[(size_t)(bk * 32 + r) * D_DIM + bd * 32 + c4] = h;
    *(half4*)&CloT[(size_t)(bk * 32 + r) * D_DIM + bd * 32 + c4] = l;
}

// ============================================================================
// Pre-pass 2: x f32 -> x_hi fp16 (elementwise)
// ============================================================================
__global__ __launch_bounds__(256) void convert_x_kernel(
    const float* __restrict__ x, _Float16* __restrict__ xh)
{
    const size_t g = (size_t)blockIdx.x * 256 + threadIdx.x;   // 8 elems each
    const float4 v0 = *(const float4*)&x[g * 8];
    const float4 v1 = *(const float4*)&x[g * 8 + 4];
    half8 h;
    h[0] = (_Float16)v0.x; h[1] = (_Float16)v0.y; h[2] = (_Float16)v0.z; h[3] = (_Float16)v0.w;
    h[4] = (_Float16)v1.x; h[5] = (_Float16)v1.y; h[6] = (_Float16)v1.z; h[7] = (_Float16)v1.w;
    *(half8*)&xh[g * 8] = h;
}

// ============================================================================
// Pass 1: hh-only GEMM, block tile 256x128, 4 waves (2x2), per-wave 128x64
// (acc[8][4], 32 MFMA : 12 ds_read_b128 per BK=32 step), dbuf LDS, K-split x4.
// 2 blocks/CU (reg-quantized 2 waves/SIMD). XCD-bijective K-slice mapping.
// ============================================================================
constexpr int P_XH = 0;        // x_hi [16 sub][16 r][4 kg][8] = 8192 halves
constexpr int P_CH = 8192;     // C_hi [ 8 sub][16 c][4 kg][8] = 4096 halves
constexpr int P_HB = 12288;    // halves per buffer (24 KB)

__global__ __launch_bounds__(256, 2) void kmeans_pass1(
    const _Float16* __restrict__ xh, const _Float16* __restrict__ ChiT,
    const float* __restrict__ Cnorm,
    float* __restrict__ m1buf, int* __restrict__ i1buf, float* __restrict__ m2buf)
{
    __shared__ _Float16 lds[2][P_HB];
    __shared__ float red_d[2][128][2];
    __shared__ int   red_i[2][128][2];
    __shared__ float red_2[2][128][2];

    // bijective: xcd = bid&7; ks = xcd&3; rb = (bid>>3)*2 + (xcd>>2)  (512 = 64*8)
    const int bid  = blockIdx.x;
    const int xcd  = bid & 7;
    const int ks   = xcd & 3;
    const int rb   = (bid >> 3) * 2 + (xcd >> 2);   // 0..127
    const int row0 = rb * 256;
    const int kb0  = ks * (K_CENT / KSL);

    const int tid  = threadIdx.x;
    const int lane = tid & 63;
    const int wid  = tid >> 6;          // 0..3
    const int wm   = wid >> 1;          // 0..1 row half (128 rows)
    const int wn   = wid & 1;           // 0..1 col half (64 cols)

    const int l15 = lane & 15;
    const int l4  = lane >> 4;
    const int kge = l4 ^ ((l15 >> 1) & 3);
    const int fragoff = l15 * 32 + kge * 8;

    const int scol = lane >> 2;                       // 0..15
    const int skg  = (lane & 3) ^ ((scol >> 1) & 3);  // pre-swizzled source kg

    // running per-thread (row = row0 + tid) argmin state
    float rm1 = 3.4e38f, rm2 = 3.4e38f;
    int   ri1 = 0;

    for (int kc = kb0; kc < kb0 + K_CENT / KSL; kc += 128) {
        floatx4 acc[8][4];
#pragma unroll
        for (int i = 0; i < 8; ++i)
#pragma unroll
            for (int j = 0; j < 4; ++j) acc[i][j] = (floatx4)0.0f;

        {   // prologue: stage kd=0 into buf 0 (A: 16 subs, B: 8 subs)
            _Float16* buf = lds[0];
#pragma unroll
            for (int q = 0; q < 4; ++q) {
                const int sub = wid * 4 + q;
                gload_lds16(&xh[(size_t)(row0 + sub * 16 + scol) * D_DIM + 0 + skg * 8], buf + P_XH + sub * 512);
            }
#pragma unroll
            for (int q = 0; q < 2; ++q) {
                const int sub = wid * 2 + q;
                gload_lds16(&ChiT[(size_t)(kc + sub * 16 + scol) * D_DIM + 0 + skg * 8], buf + P_CH + sub * 512);
            }
            __syncthreads();
        }

        for (int kdi = 0; kdi < D_DIM / 32; ++kdi) {
            const int cur = kdi & 1;
            _Float16* bufc = lds[cur];
            _Float16* bufn = lds[cur ^ 1];
            const int  kdn = (kdi + 1) * 32;
            const bool pf  = (kdi + 1 < D_DIM / 32);

            if (pf) {
#pragma unroll
                for (int q = 0; q < 4; ++q) {
                    const int sub = wid * 4 + q;
                    gload_lds16(&xh[(size_t)(row0 + sub * 16 + scol) * D_DIM + kdn + skg * 8], bufn + P_XH + sub * 512);
                }
#pragma unroll
                for (int q = 0; q < 2; ++q) {
                    const int sub = wid * 2 + q;
                    gload_lds16(&ChiT[(size_t)(kc + sub * 16 + scol) * D_DIM + kdn + skg * 8], bufn + P_CH + sub * 512);
                }
            }

            half8 ah[8], bh[4];
#pragma unroll
            for (int i = 0; i < 8; ++i)
                ah[i] = *(const half8*)(bufc + P_XH + (wm * 8 + i) * 512 + fragoff);
#pragma unroll
            for (int j = 0; j < 4; ++j)
                bh[j] = *(const half8*)(bufc + P_CH + (wn * 4 + j) * 512 + fragoff);

#pragma unroll
            for (int i = 0; i < 8; ++i)
#pragma unroll
                for (int j = 0; j < 4; ++j)
                    acc[i][j] = __builtin_amdgcn_mfma_f32_16x16x32_f16(ah[i], bh[j], acc[i][j], 0, 0, 0);

            __syncthreads();
        }

        // ---- per-chunk argmin epilogue (transient regs only)
        const int colbase = kc + wn * 64;
        float cnv[4];
#pragma unroll
        for (int j = 0; j < 4; ++j) cnv[j] = Cnorm[colbase + j * 16 + l15];

#pragma unroll
        for (int i = 0; i < 8; ++i)
#pragma unroll
            for (int r = 0; r < 4; ++r) {
                float m1 = 3.4e38f, m2 = 3.4e38f;
                int   i1 = 0;
#pragma unroll
                for (int j = 0; j < 4; ++j) {
                    const float d  = fmaf(-2.0f, acc[i][j][r], cnv[j]);
                    const int   ix = colbase + j * 16 + l15;
                    if (d < m1) { m2 = m1; m1 = d; i1 = ix; }
                    else if (d < m2) { m2 = d; }
                }
#pragma unroll
                for (int off = 1; off < 16; off <<= 1) {
                    const float om1 = __shfl_xor(m1, off, 64);
                    const int   oi  = __shfl_xor(i1, off, 64);
                    const float om2 = __shfl_xor(m2, off, 64);
                    const float nm2 = fminf(fminf(m2, om2), fmaxf(m1, om1));
                    if (om1 < m1 || (om1 == m1 && oi < i1)) { m1 = om1; i1 = oi; }
                    m2 = nm2;
                }
                if (l15 == 0) {
                    const int rr = i * 16 + l4 * 4 + r;
                    red_d[wm][rr][wn] = m1;
                    red_i[wm][rr][wn] = i1;
                    red_2[wm][rr][wn] = m2;
                }
            }
        __syncthreads();

        // merge wn halves for row = tid, fold into running registers
        {
            const int hh = tid >> 7;
            const int rr = tid & 127;
            float m1 = red_d[hh][rr][0], m2 = red_2[hh][rr][0];
            int   i1 = red_i[hh][rr][0];
            const float om1 = red_d[hh][rr][1];
            const int   oi  = red_i[hh][rr][1];
            const float om2 = red_2[hh][rr][1];
            m2 = fminf(fminf(m2, om2), fmaxf(m1, om1));
            if (om1 < m1 || (om1 == m1 && oi < i1)) { m1 = om1; i1 = oi; }
            // fold into running (chunk kc > previous chunks; indices ascending)
            const float nm2 = fminf(fminf(rm2, m2), fmaxf(rm1, m1));
            if (m1 < rm1 || (m1 == rm1 && i1 < ri1)) { rm1 = m1; ri1 = i1; }
            rm2 = nm2;
        }
        // red arrays are re-written only after the next chunk's D-loop barriers
    }

    const size_t off = (size_t)ks * N_ROWS + row0 + tid;
    m1buf[off] = rm1;
    i1buf[off] = ri1;
    m2buf[off] = rm2;
}

// ============================================================================
// Merge 4 K-slices: final argmin + certainty test + worklist
// ============================================================================
__global__ __launch_bounds__(256) void kmeans_merge4(
    const float* __restrict__ m1buf, const int* __restrict__ i1buf,
    const float* __restrict__ m2buf, int* __restrict__ out,
    int* __restrict__ urows, unsigned int* __restrict__ ucount)
{
    const int row = blockIdx.x * 256 + threadIdx.x;
    float m1 = m1buf[row], m2 = m2buf[row];
    int   i1 = i1buf[row];
#pragma unroll
    for (int s = 1; s < KSL; ++s) {
        const float om1 = m1buf[(size_t)s * N_ROWS + row];
        const float om2 = m2buf[(size_t)s * N_ROWS + row];
        const int   oi  = i1buf[(size_t)s * N_ROWS + row];
        const float nm2 = fminf(fminf(m2, om2), fmaxf(m1, om1));
        if (om1 < m1 || (om1 == m1 && oi < i1)) { m1 = om1; i1 = oi; }
        m2 = nm2;
    }
    out[row] = i1;
    if (m2 - m1 <= EPS_GAP) {
        const unsigned slot = atomicAdd(ucount, 1u);
        if (slot < (unsigned)CAP) urows[slot] = row;
    }
}

// ============================================================================
// Gather: uncertain rows' x -> compact fp16 hi/lo buffers [slot][1024]
// ============================================================================
__global__ __launch_bounds__(64) void kmeans_gather(
    const float* __restrict__ x, const int* __restrict__ urows,
    const unsigned int* __restrict__ ucount,
    _Float16* __restrict__ xch, _Float16* __restrict__ xcl)
{
    const unsigned cntr = *ucount;
    const unsigned cnt = cntr > (unsigned)CAP ? (unsigned)CAP : cntr;
    const unsigned slot = blockIdx.x;
    if (slot >= cnt) return;
    const int row = urows[slot];
    const int t = threadIdx.x;
#pragma unroll
    for (int e = 0; e < 16; ++e) {
        const int idx = e * 64 + t;
        const float v = x[(size_t)row * D_DIM + idx];
        const _Float16 h = (_Float16)v;
        xch[(size_t)slot * D_DIM + idx] = h;
        xcl[(size_t)slot * D_DIM + idx] = (_Float16)(v - (float)h);
    }
}

// ============================================================================
// Rescore (K-split x8): exact 3-pass hi/lo over 512-col slice for 32 rows.
// ============================================================================
constexpr int R_XH = 0;        // 1024 halves (2 sub)
constexpr int R_XL = 1024;     // 1024
constexpr int R_CH = 2048;     // 8192 (16 sub)
constexpr int R_CL = 10240;    // 8192
constexpr int R_HB = 18432;    // per buffer (36 KB)

__global__ __launch_bounds__(256) void kmeans_rescore2(
    const _Float16* __restrict__ xch, const _Float16* __restrict__ xcl,
    const _Float16* __restrict__ ChiT, const _Float16* __restrict__ CloT,
    const float* __restrict__ Cnorm, const unsigned int* __restrict__ ucount,
    float* __restrict__ rpd, int* __restrict__ rpi)
{
    const unsigned cntr = *ucount;
    const unsigned cnt = cntr > (unsigned)CAP ? (unsigned)CAP : cntr;
    const int bid = blockIdx.x;
    const int ksl = bid & 7;
    const int grp = bid >> 3;
    if ((unsigned)(grp * 32) >= cnt) return;

    __shared__ _Float16 lds[2][R_HB];
    __shared__ float rd[32][4];
    __shared__ int   ri[32][4];

    const int tid  = threadIdx.x;
    const int lane = tid & 63;
    const int wid  = tid >> 6;
    const int l15  = lane & 15;
    const int l4   = lane >> 4;
    const int kge  = l4 ^ ((l15 >> 1) & 3);
    const int fragoff = l15 * 32 + kge * 8;
    const int scol = lane >> 2;
    const int skg  = (lane & 3) ^ ((scol >> 1) & 3);

    const int base  = grp * 32;
    const int kbase = ksl * (K_CENT / RSL);

    float best[2][4];
    int   bidx[2][4];
#pragma unroll
    for (int i = 0; i < 2; ++i)
#pragma unroll
        for (int r = 0; r < 4; ++r) { best[i][r] = 3.4e38f; bidx[i][r] = 0; }

    for (int ch = 0; ch < 2; ++ch) {
        const int kc = kbase + ch * 256;
        floatx4 acc[2][4];
#pragma unroll
        for (int i = 0; i < 2; ++i)
#pragma unroll
            for (int j = 0; j < 4; ++j) acc[i][j] = (floatx4)0.0f;

        {
            _Float16* buf = lds[0];
#pragma unroll
            for (int q = 0; q < 4; ++q) {
                const int sub = wid * 4 + q;
                gload_lds16(&ChiT[(size_t)(kc + sub * 16 + scol) * D_DIM + 0 + skg * 8], buf + R_CH + sub * 512);
                gload_lds16(&CloT[(size_t)(kc + sub * 16 + scol) * D_DIM + 0 + skg * 8], buf + R_CL + sub * 512);
            }
            if (wid < 2)
                gload_lds16(&xch[(size_t)(base + wid * 16 + scol) * D_DIM + 0 + skg * 8], buf + R_XH + wid * 512);
            else
                gload_lds16(&xcl[(size_t)(base + (wid - 2) * 16 + scol) * D_DIM + 0 + skg * 8], buf + R_XL + (wid - 2) * 512);
            __syncthreads();
        }

        for (int kdi = 0; kdi < D_DIM / 32; ++kdi) {
            const int cur = kdi & 1;
            _Float16* bufc = lds[cur];
            _Float16* bufn = lds[cur ^ 1];
            const int  kdn = (kdi + 1) * 32;
            const bool pf  = (kdi + 1 < D_DIM / 32);

            if (pf) {
#pragma unroll
                for (int q = 0; q < 4; ++q) {
                    const int sub = wid * 4 + q;
                    gload_lds16(&ChiT[(size_t)(kc + sub * 16 + scol) * D_DIM + kdn + skg * 8], bufn + R_CH + sub * 512);
                    gload_lds16(&CloT[(size_t)(kc + sub * 16 + scol) * D_DIM + kdn + skg * 8], bufn + R_CL + sub * 512);
                }
                if (wid < 2)
                    gload_lds16(&xch[(size_t)(base + wid * 16 + scol) * D_DIM + kdn + skg * 8], bufn + R_XH + wid * 512);
                else
                    gload_lds16(&xcl[(size_t)(base + (wid - 2) * 16 + scol) * D_DIM + kdn + skg * 8], bufn + R_XL + (wid - 2) * 512);
            }

            half8 ah[2], al[2], bh[4], bl[4];
#pragma unroll
            for (int i = 0; i < 2; ++i) {
                ah[i] = *(const half8*)(bufc + R_XH + i * 512 + fragoff);
                al[i] = *(const half8*)(bufc + R_XL + i * 512 + fragoff);
            }
#pragma unroll
            for (int j = 0; j < 4; ++j) {
                bh[j] = *(const half8*)(bufc + R_CH + (wid * 4 + j) * 512 + fragoff);
                bl[j] = *(const half8*)(bufc + R_CL + (wid * 4 + j) * 512 + fragoff);
            }
#pragma unroll
            for (int i = 0; i < 2; ++i)
#pragma unroll
                for (int j = 0; j < 4; ++j) {
                    acc[i][j] = __builtin_amdgcn_mfma_f32_16x16x32_f16(ah[i], bh[j], acc[i][j], 0, 0, 0);
                    acc[i][j] = __builtin_amdgcn_mfma_f32_16x16x32_f16(ah[i], bl[j], acc[i][j], 0, 0, 0);
                    acc[i][j] = __builtin_amdgcn_mfma_f32_16x16x32_f16(al[i], bh[j], acc[i][j], 0, 0, 0);
                }
            __syncthreads();
        }

#pragma unroll
        for (int j = 0; j < 4; ++j) {
            const int col = kc + wid * 64 + j * 16 + l15;
            const float cn = Cnorm[col];
#pragma unroll
            for (int i = 0; i < 2; ++i)
#pragma unroll
                for (int r = 0; r < 4; ++r) {
                    const float d = fmaf(-2.0f, acc[i][j][r], cn);
                    if (d < best[i][r]) { best[i][r] = d; bidx[i][r] = col; }
                }
        }
    }

#pragma unroll
    for (int i = 0; i < 2; ++i)
#pragma unroll
        for (int r = 0; r < 4; ++r) {
            float m1 = best[i][r];
            int   i1 = bidx[i][r];
#pragma unroll
            for (int off = 1; off < 16; off <<= 1) {
                const float om1 = __shfl_xor(m1, off, 64);
                const int   oi  = __shfl_xor(i1, off, 64);
                if (om1 < m1 || (om1 == m1 && oi < i1)) { m1 = om1; i1 = oi; }
            }
            if (l15 == 0) { rd[i * 16 + l4 * 4 + r][wid] = m1; ri[i * 16 + l4 * 4 + r][wid] = i1; }
        }
    __syncthreads();

    if (tid < 32) {
        float m1 = rd[tid][0];
        int   i1 = ri[tid][0];
#pragma unroll
        for (int w = 1; w < 4; ++w) {
            const float om1 = rd[tid][w];
            const int   oi  = ri[tid][w];
            if (om1 < m1 || (om1 == m1 && oi < i1)) { m1 = om1; i1 = oi; }
        }
        rpd[(size_t)(base + tid) * RSL + ksl] = m1;
        rpi[(size_t)(base + tid) * RSL + ksl] = i1;
    }
}

// ============================================================================
// Merge rescore slices -> final out for uncertain rows
// ============================================================================
__global__ __launch_bounds__(256) void kmeans_merge2(
    const float* __restrict__ rpd, const int* __restrict__ rpi,
    const int* __restrict__ urows, const unsigned int* __restrict__ ucount,
    int* __restrict__ out)
{
    const unsigned cntr = *ucount;
    const unsigned cnt = cntr > (unsigned)CAP ? (unsigned)CAP : cntr;
    const unsigned s = blockIdx.x * 256 + threadIdx.x;
    if (s >= cnt) return;
    float m1 = rpd[(size_t)s * RSL];
    int   i1 = rpi[(size_t)s * RSL];
#pragma unroll
    for (int k = 1; k < RSL; ++k) {
        const float om = rpd[(size_t)s * RSL + k];
        const int   oi = rpi[(size_t)s * RSL + k];
        if (om < m1 || (om == m1 && oi < i1)) { m1 = om; i1 = oi; }
    }
    out[urows[s]] = i1;
}

// ============================================================================
// Fallback A: proven R3 3-pass MFMA kernel (hi/lo, direct out)
// ============================================================================
constexpr int F_XH = 0, F_XL = 4096, F_CH = 8192, F_CL = 16384, F_HB = 24576;

__device__ __forceinline__ void write_x2(_Float16* buf, const float4 v, int r, int kb) {
    const _Float16 h0 = (_Float16)v.x, h1 = (_Float16)v.y;
    const _Float16 h2 = (_Float16)v.z, h3 = (_Float16)v.w;
    const int kg  = kb >> 3;
    const int hs  = (kb >> 2) & 1;
    const int kge = kg ^ ((r >> 1) & 3);
    const int base = (r >> 4) * 512 + (r & 15) * 32 + kge * 8 + hs * 4;
    *(half4*)(buf + F_XH + base) = (half4){h0, h1, h2, h3};
    *(half4*)(buf + F_XL + base) = (half4){(_Float16)(v.x - (float)h0), (_Float16)(v.y - (float)h1),
                                           (_Float16)(v.z - (float)h2), (_Float16)(v.w - (float)h3)};
}

__global__ __launch_bounds__(512, 2) void kmeans_mfma_kernel(
    const float* __restrict__ x, const _Float16* __restrict__ ChiT,
    const _Float16* __restrict__ CloT, const float* __restrict__ Cnorm,
    int* __restrict__ out)
{
    __shared__ _Float16 lds[2][F_HB];
    __shared__ float red_d[2][64][4];
    __shared__ int   red_i[2][64][4];

    const int tid  = threadIdx.x;
    const int lane = tid & 63;
    const int wid  = tid >> 6;
    const int wm   = wid >> 2;
    const int wn   = wid & 3;
    const int row0 = blockIdx.x * 128;
    const int l15 = lane & 15;
    const int l4  = lane >> 4;
    const int kge = l4 ^ ((l15 >> 1) & 3);
    const int fragoff = l15 * 32 + kge * 8;
    const int sr = tid >> 2, sc = tid & 3;
    const int ccol = lane >> 2;
    const int ckg  = (lane & 3) ^ ((ccol >> 1) & 3);

    float best[4][4];
    int   bidx[4][4];
#pragma unroll
    for (int i = 0; i < 4; ++i)
#pragma unroll
        for (int r = 0; r < 4; ++r) { best[i][r] = 3.4e38f; bidx[i][r] = 0; }

    for (int kc = 0; kc < K_CENT; kc += 256) {
        floatx4 acc[4][4];
#pragma unroll
        for (int i = 0; i < 4; ++i)
#pragma unroll
            for (int j = 0; j < 4; ++j) acc[i][j] = (floatx4)0.0f;
        {
            _Float16* buf = lds[0];
            const float4 xv0 = *(const float4*)&x[(size_t)(row0 + sr) * D_DIM + 0 + sc * 4];
            const float4 xv1 = *(const float4*)&x[(size_t)(row0 + sr) * D_DIM + 16 + sc * 4];
            gload_lds16(&ChiT[(size_t)(kc + wid * 16 + ccol) * D_DIM + 0 + ckg * 8], buf + F_CH + wid * 512);
            gload_lds16(&ChiT[(size_t)(kc + (wid + 8) * 16 + ccol) * D_DIM + 0 + ckg * 8], buf + F_CH + (wid + 8) * 512);
            gload_lds16(&CloT[(size_t)(kc + wid * 16 + ccol) * D_DIM + 0 + ckg * 8], buf + F_CL + wid * 512);
            gload_lds16(&CloT[(size_t)(kc + (wid + 8) * 16 + ccol) * D_DIM + 0 + ckg * 8], buf + F_CL + (wid + 8) * 512);
            write_x2(buf, xv0, sr, sc * 4);
            write_x2(buf, xv1, sr, sc * 4 + 16);
            __syncthreads();
        }
        for (int kdi = 0; kdi < D_DIM / 32; ++kdi) {
            const int cur = kdi & 1;
            _Float16* bufc = lds[cur];
            _Float16* bufn = lds[cur ^ 1];
            const int  kdn = (kdi + 1) * 32;
            const bool pf  = (kdi + 1 < D_DIM / 32);
            float4 xv0, xv1;
            if (pf) {
                xv0 = *(const float4*)&x[(size_t)(row0 + sr) * D_DIM + kdn + sc * 4];
                xv1 = *(const float4*)&x[(size_t)(row0 + sr) * D_DIM + kdn + 16 + sc * 4];
                gload_lds16(&ChiT[(size_t)(kc + wid * 16 + ccol) * D_DIM + kdn + ckg * 8], bufn + F_CH + wid * 512);
                gload_lds16(&ChiT[(size_t)(kc + (wid + 8) * 16 + ccol) * D_DIM + kdn + ckg * 8], bufn + F_CH + (wid + 8) * 512);
                gload_lds16(&CloT[(size_t)(kc + wid * 16 + ccol) * D_DIM + kdn + ckg * 8], bufn + F_CL + wid * 512);
                gload_lds16(&CloT[(size_t)(kc + (wid + 8) * 16 + ccol) * D_DIM + kdn + ckg * 8], bufn + F_CL + (wid + 8) * 512);
            }
            half8 ah[4], al[4], bh[4], bl[4];
#pragma unroll
            for (int i = 0; i < 4; ++i) {
                ah[i] = *(const half8*)(bufc + F_XH + (wm * 4 + i) * 512 + fragoff);
                al[i] = *(const half8*)(bufc + F_XL + (wm * 4 + i) * 512 + fragoff);
            }
#pragma unroll
            for (int j = 0; j < 4; ++j) {
                bh[j] = *(const half8*)(bufc + F_CH + (wn * 4 + j) * 512 + fragoff);
                bl[j] = *(const half8*)(bufc + F_CL + (wn * 4 + j) * 512 + fragoff);
            }
#pragma unroll
            for (int i = 0; i < 4; ++i)
#pragma unroll
                for (int j = 0; j < 4; ++j) {
                    acc[i][j] = __builtin_amdgcn_mfma_f32_16x16x32_f16(ah[i], bh[j], acc[i][j], 0, 0, 0);
                    acc[i][j] = __builtin_amdgcn_mfma_f32_16x16x32_f16(ah[i], bl[j], acc[i][j], 0, 0, 0);
                    acc[i][j] = __builtin_amdgcn_mfma_f32_16x16x32_f16(al[i], bh[j], acc[i][j], 0, 0, 0);
                }
            if (pf) {
                write_x2(bufn, xv0, sr, sc * 4);
                write_x2(bufn, xv1, sr, sc * 4 + 16);
            }
            __syncthreads();
        }
        const int colw = kc + wn * 64;
#pragma unroll
        for (int ns = 0; ns < 4; ++ns) {
            const float cn = Cnorm[colw + ns * 16 + l15];
            const int   ix = colw + ns * 16 + l15;
#pragma unroll
            for (int i = 0; i < 4; ++i)
#pragma unroll
                for (int r = 0; r < 4; ++r) {
                    const float d = fmaf(-2.0f, acc[i][ns][r], cn);
                    if (d < best[i][r]) { best[i][r] = d; bidx[i][r] = ix; }
                }
        }
    }
#pragma unroll
    for (int i = 0; i < 4; ++i)
#pragma unroll
        for (int r = 0; r < 4; ++r) {
            float d  = best[i][r];
            int   ix = bidx[i][r];
#pragma unroll
            for (int off = 1; off < 16; off <<= 1) {
                const float od = __shfl_xor(d, off, 64);
                const int   oi = __shfl_xor(ix, off, 64);
                if (od < d || (od == d && oi < ix)) { d = od; ix = oi; }
            }
            if (l15 == 0) {
                red_d[wm][i * 16 + l4 * 4 + r][wn] = d;
                red_i[wm][i * 16 + l4 * 4 + r][wn] = ix;
            }
        }
    __syncthreads();
    if (tid < 128) {
        const int hh = tid >> 6, rr = tid & 63;
        float bd = red_d[hh][rr][0];
        int   bi2 = red_i[hh][rr][0];
#pragma unroll
        for (int w = 1; w < 4; ++w) {
            const float od = red_d[hh][rr][w];
            const int   oi = red_i[hh][rr][w];
            if (od < bd || (od == bd && oi < bi2)) { bd = od; bi2 = oi; }
        }
        out[row0 + tid] = bi2;
    }
}

// ============================================================================
// Fallback B: R1 fp32 kernel
// ============================================================================
__global__ __launch_bounds__(256, 2) void kmeans_assign_f32(
    const float* __restrict__ x, const float* __restrict__ Cm,
    const float* __restrict__ Cnorm, int* __restrict__ out)
{
    __shared__ float xs[32][64];
    __shared__ float cs[32][64];
    const int tid = threadIdx.x;
    const int tx = tid & 15, ty = tid >> 4;
    const int row0 = blockIdx.x * 64;
    const int xr = tid >> 3, xc = tid & 7;
    const int cr = tid >> 4, cc = tid & 15;
    float best[4]; int bidx[4];
#pragma unroll
    for (int i = 0; i < 4; ++i) { best[i] = 3.4e38f; bidx[i] = 0; }
    for (int kc = 0; kc < K_CENT; kc += 64) {
        float acc[16];
#pragma unroll
        for (int i = 0; i < 16; ++i) acc[i] = 0.0f;
        for (int kd = 0; kd < D_DIM; kd += 32) {
            const float4 xv0 = *(const float4*)&x[(size_t)(row0 + xr) * D_DIM + kd + xc * 4];
            const float4 xv1 = *(const float4*)&x[(size_t)(row0 + xr + 32) * D_DIM + kd + xc * 4];
            const float4 cv0 = *(const float4*)&Cm[(size_t)(kd + cr) * K_CENT + kc + cc * 4];
            const float4 cv1 = *(const float4*)&Cm[(size_t)(kd + cr + 16) * K_CENT + kc + cc * 4];
            __syncthreads();
            xs[xc*4+0][xr] = xv0.x; xs[xc*4+1][xr] = xv0.y; xs[xc*4+2][xr] = xv0.z; xs[xc*4+3][xr] = xv0.w;
            xs[xc*4+0][xr+32] = xv1.x; xs[xc*4+1][xr+32] = xv1.y; xs[xc*4+2][xr+32] = xv1.z; xs[xc*4+3][xr+32] = xv1.w;
            *(float4*)&cs[cr][cc*4]    = cv0;
            *(float4*)&cs[cr+16][cc*4] = cv1;
            __syncthreads();
#pragma unroll
            for (int kk = 0; kk < 32; ++kk) {
                const float4 a = *(const float4*)&xs[kk][ty*4];
                const float4 b = *(const float4*)&cs[kk][tx*4];
                acc[ 0] += a.x*b.x; acc[ 1] += a.x*b.y; acc[ 2] += a.x*b.z; acc[ 3] += a.x*b.w;
                acc[ 4] += a.y*b.x; acc[ 5] += a.y*b.y; acc[ 6] += a.y*b.z; acc[ 7] += a.y*b.w;
                acc[ 8] += a.z*b.x; acc[ 9] += a.z*b.y; acc[10] += a.z*b.z; acc[11] += a.z*b.w;
                acc[12] += a.w*b.x; acc[13] += a.w*b.y; acc[14] += a.w*b.z; acc[15] += a.w*b.w;
            }
        }
        const float4 cn = *(const float4*)&Cnorm[kc + tx*4];
        const float cnv[4] = {cn.x, cn.y, cn.z, cn.w};
#pragma unroll
        for (int i = 0; i < 4; ++i)
#pragma unroll
            for (int j = 0; j < 4; ++j) {
                const float dist = cnv[j] - 2.0f * acc[i*4+j];
                const int   idx  = kc + tx*4 + j;
                if (dist < best[i]) { best[i] = dist; bidx[i] = idx; }
            }
    }
#pragma unroll
    for (int i = 0; i < 4; ++i) {
        float d = best[i]; int ix = bidx[i];
#pragma unroll
        for (int off = 1; off < 16; off <<= 1) {
            const float od = __shfl_xor(d, off, 64);
            const int   oi = __shfl_xor(ix, off, 64);
            if (od < d || (od == d && oi < ix)) { d = od; ix = oi; }
        }
        if (tx == 0) out[row0 + ty*4 + i] = ix;
    }
}

// ============================================================================
extern "C" void kernel_launch(void* const* d_in, const int* in_sizes, int n_in,
                              void* d_out, int out_size, void* d_ws, size_t ws_size,
                              hipStream_t stream) {
    const float* x     = (const float*)d_in[0];
    const float* C     = (const float*)d_in[1];
    const float* Cnorm = (const float*)d_in[2];
    int* out = (int*)d_out;

    const size_t chalf = (size_t)K_CENT * D_DIM;   // halves per C array
    const size_t capd  = (size_t)CAP * D_DIM;      // halves per xc array
    const size_t xhN   = (size_t)N_ROWS * D_DIM;   // halves for x_hi

    const size_t sz_base = (2 * chalf + 2 * capd) * 2
                         + (size_t)KSL * N_ROWS * 12
                         + (size_t)CAP * RSL * 8
                         + (size_t)CAP * 4 + 64;
    const size_t need_full = sz_base + xhN * 2;
    const size_t need_r3   = 2 * chalf * 2;

    if (ws_size >= need_full) {
        _Float16* ChiT = (_Float16*)d_ws;
        _Float16* CloT = ChiT + chalf;
        _Float16* xch  = CloT + chalf;
        _Float16* xcl  = xch + capd;
        float* m1buf = (float*)(xcl + capd);
        float* m2buf = m1buf + (size_t)KSL * N_ROWS;
        int*   i1buf = (int*)(m2buf + (size_t)KSL * N_ROWS);
        float* rpd   = (float*)(i1buf + (size_t)KSL * N_ROWS);
        int*   rpi   = (int*)(rpd + (size_t)CAP * RSL);
        int*   urows = rpi + (size_t)CAP * RSL;
        unsigned int* ucount = (unsigned int*)(urows + CAP);
        _Float16* xh = (_Float16*)(ucount + 16);

        convert_C_kernel<<<dim3(128, 32), 256, 0, stream>>>(C, ChiT, CloT);
        convert_x_kernel<<<dim3((int)(xhN / 2048)), 256, 0, stream>>>(x, xh);
        hipMemsetAsync(ucount, 0, sizeof(unsigned int), stream);
        kmeans_pass1<<<dim3(128 * KSL), 256, 0, stream>>>(xh, ChiT, Cnorm, m1buf, i1buf, m2buf);
        kmeans_merge4<<<dim3(N_ROWS / 256), 256, 0, stream>>>(m1buf, i1buf, m2buf, out, urows, ucount);
        kmeans_gather<<<dim3(CAP), 64, 0, stream>>>(x, urows, ucount, xch, xcl);
        kmeans_rescore2<<<dim3((CAP / 32) * RSL), 256, 0, stream>>>(xch, xcl, ChiT, CloT, Cnorm, ucount, rpd, rpi);
        kmeans_merge2<<<dim3(CAP / 256), 256, 0, stream>>>(rpd, rpi, urows, ucount, out);
    } else if (ws_size >= need_r3) {
        _Float16* ChiT = (_Float16*)d_ws;
        _Float16* CloT = ChiT + chalf;
        convert_C_kernel<<<dim3(128, 32), 256, 0, stream>>>(C, ChiT, CloT);
        kmeans_mfma_kernel<<<dim3(N_ROWS / 128), 512, 0, stream>>>(x, ChiT, CloT, Cnorm, out);
    } else {
        kmeans_assign_f32<<<dim3(N_ROWS / 64), 256, 0, stream>>>(x, C, Cnorm, out);
    }
}

// Round 8
// 480.361 us; speedup vs baseline: 2.0991x; 1.1963x over previous
//
#include <hip/hip_runtime.h>
#include <cstdint>
#include <cstddef>

typedef _Float16 half8 __attribute__((ext_vector_type(8)));
typedef _Float16 half4 __attribute__((ext_vector_type(4)));
typedef float    floatx4 __attribute__((ext_vector_type(4)));

constexpr int N_ROWS = 32768;
constexpr int D_DIM  = 1024;
constexpr int K_CENT = 4096;
constexpr int CAP    = 4096;      // max uncertain rows (E[count]~620)
constexpr int KSL    = 2;         // pass1 K split (2048 cols/slice)
constexpr int RSL    = 8;         // rescore K split (512 cols/slice)
constexpr float EPS_GAP = 0.4f;   // 2 * (14-sigma hh-error bound)

__device__ __forceinline__ void gload_lds16(const void* g, void* l) {
    __builtin_amdgcn_global_load_lds(
        (const __attribute__((address_space(1))) uint32_t*)g,
        (__attribute__((address_space(3))) uint32_t*)l, 16, 0, 0);
}

// ============================================================================
// Pre-pass 1: C[d][k] f32 -> C_hiT[k][d], C_loT[k][d] fp16 (transposed split)
// ============================================================================
__global__ __launch_bounds__(256) void convert_C_kernel(
    const float* __restrict__ C, _Float16* __restrict__ ChiT, _Float16* __restrict__ CloT)
{
    __shared__ float tile[32][33];
    const int bk = blockIdx.x, bd = blockIdx.y, t = threadIdx.x;
    const int r = t >> 3, c4 = (t & 7) * 4;
    const float4 v = *(const float4*)&C[(size_t)(bd * 32 + r) * K_CENT + bk * 32 + c4];
    tile[r][c4 + 0] = v.x; tile[r][c4 + 1] = v.y;
    tile[r][c4 + 2] = v.z; tile[r][c4 + 3] = v.w;
    __syncthreads();
    half4 h, l;
#pragma unroll
    for (int i = 0; i < 4; ++i) {
        const float f = tile[c4 + i][r];
        const _Float16 hi = (_Float16)f;
        h[i] = hi;
        l[i] = (_Float16)(f - (float)hi);
    }
    *(half4*)&ChiT[(size_t)(bk * 32 + r) * D_DIM + bd * 32 + c4] = h;
    *(half4*)&CloT[(size_t)(bk * 32 + r) * D_DIM + bd * 32 + c4] = l;
}

// ============================================================================
// Pre-pass 2: x f32 -> x_hi fp16 (elementwise)
// ============================================================================
__global__ __launch_bounds__(256) void convert_x_kernel(
    const float* __restrict__ x, _Float16* __restrict__ xh)
{
    const size_t g = (size_t)blockIdx.x * 256 + threadIdx.x;   // 8 elems each
    const float4 v0 = *(const float4*)&x[g * 8];
    const float4 v1 = *(const float4*)&x[g * 8 + 4];
    half8 h;
    h[0] = (_Float16)v0.x; h[1] = (_Float16)v0.y; h[2] = (_Float16)v0.z; h[3] = (_Float16)v0.w;
    h[4] = (_Float16)v1.x; h[5] = (_Float16)v1.y; h[6] = (_Float16)v1.z; h[7] = (_Float16)v1.w;
    *(half8*)&xh[g * 8] = h;
}

// ============================================================================
// Pass 1: hh-only GEMM, block 128 rows x 256-col chunks, 4 waves (2x2),
// per-wave 64x128 (acc[4][8]).  Counted-vmcnt pipeline (T4): per K-step
//   stage6(next) -> vmcnt(6) -> s_barrier -> ds_read -> MFMA -> s_barrier
// Last step drains vmcnt(0); chunk epilogue overlaps next chunk's prologue.
// KSL=2, grid 512 (2 blocks/CU), XCD-bijective (each XCD owns one C-half).
// ============================================================================
constexpr int P_XH = 0;        // x_hi [ 8 sub][16 r][4 kg][8] = 4096 halves
constexpr int P_CH = 4096;     // C_hi [16 sub][16 c][4 kg][8] = 8192 halves
constexpr int P_HB = 12288;    // 24 KB per buffer

__device__ __forceinline__ void stage6(
    _Float16* buf, const _Float16* __restrict__ xh, const _Float16* __restrict__ ChiT,
    int row0, int kc, int kd, int wid, int scol, int skg)
{
#pragma unroll
    for (int q = 0; q < 2; ++q) {
        const int sub = wid * 2 + q;
        gload_lds16(&xh[(size_t)(row0 + sub * 16 + scol) * D_DIM + kd + skg * 8],
                    buf + P_XH + sub * 512);
    }
#pragma unroll
    for (int q = 0; q < 4; ++q) {
        const int sub = wid * 4 + q;
        gload_lds16(&ChiT[(size_t)(kc + sub * 16 + scol) * D_DIM + kd + skg * 8],
                    buf + P_CH + sub * 512);
    }
}

__global__ __launch_bounds__(256, 2) void kmeans_pass1(
    const _Float16* __restrict__ xh, const _Float16* __restrict__ ChiT,
    const float* __restrict__ Cnorm,
    float* __restrict__ m1buf, int* __restrict__ i1buf, float* __restrict__ m2buf)
{
    __shared__ _Float16 lds[2][P_HB];
    __shared__ float red_d[2][64][2];
    __shared__ int   red_i[2][64][2];
    __shared__ float red_2[2][64][2];
    __shared__ float cns[K_CENT / KSL];   // 2048 floats = 8 KB

    // bijective: xcd = bid&7; ks = xcd&1; rb = (bid>>3)*4 + (xcd>>1)
    const int bid  = blockIdx.x;
    const int xcd  = bid & 7;
    const int ks   = xcd & 1;
    const int rb   = (bid >> 3) * 4 + (xcd >> 1);   // 0..255
    const int row0 = rb * 128;
    const int kb0  = ks * (K_CENT / KSL);

    const int tid  = threadIdx.x;
    const int lane = tid & 63;
    const int wid  = tid >> 6;          // 0..3
    const int wm   = wid >> 1;          // 0..1 (64-row half)
    const int wn   = wid & 1;           // 0..1 (128-col half)

    const int l15 = lane & 15;
    const int l4  = lane >> 4;
    const int kge = l4 ^ ((l15 >> 1) & 3);
    const int fragoff = l15 * 32 + kge * 8;

    const int scol = lane >> 2;                       // 0..15
    const int skg  = (lane & 3) ^ ((scol >> 1) & 3);  // pre-swizzled source kg

    // stage Cnorm slice into LDS (read in epilogue via LDS -> no VMEM there)
#pragma unroll
    for (int q = 0; q < (K_CENT / KSL) / 256; ++q)
        cns[q * 256 + tid] = Cnorm[kb0 + q * 256 + tid];

    float rm1 = 3.4e38f, rm2 = 3.4e38f;
    int   ri1 = 0;

    // prologue: stage chunk0 / kd0 into buf0 (6 loads in flight)
    stage6(lds[0], xh, ChiT, row0, kb0, 0, wid, scol, skg);

    const int nch = (K_CENT / KSL) / 256;   // 8 chunks
    for (int ci = 0; ci < nch; ++ci) {
        const int kc = kb0 + ci * 256;
        floatx4 acc[4][8];
#pragma unroll
        for (int i = 0; i < 4; ++i)
#pragma unroll
            for (int j = 0; j < 8; ++j) acc[i][j] = (floatx4)0.0f;

        for (int kdi = 0; kdi < 32; ++kdi) {
            _Float16* bufc = lds[kdi & 1];
            _Float16* bufn = lds[(kdi + 1) & 1];
            const bool hn = (kdi < 31) || (ci < nch - 1);
            if (hn) {
                const int nkc = (kdi < 31) ? kc : kc + 256;
                const int nkd = (kdi < 31) ? (kdi + 1) * 32 : 0;
                stage6(bufn, xh, ChiT, row0, nkc, nkd, wid, scol, skg);
                asm volatile("s_waitcnt vmcnt(6)" ::: "memory");   // current buf ready; 6 fly
            } else {
                asm volatile("s_waitcnt vmcnt(0)" ::: "memory");   // final drain
            }
            __builtin_amdgcn_s_barrier();
            __builtin_amdgcn_sched_barrier(0);

            half8 ah[4], bh[8];
#pragma unroll
            for (int i = 0; i < 4; ++i)
                ah[i] = *(const half8*)(bufc + P_XH + (wm * 4 + i) * 512 + fragoff);
#pragma unroll
            for (int j = 0; j < 8; ++j)
                bh[j] = *(const half8*)(bufc + P_CH + (wn * 8 + j) * 512 + fragoff);

            __builtin_amdgcn_s_setprio(1);
#pragma unroll
            for (int i = 0; i < 4; ++i)
#pragma unroll
                for (int j = 0; j < 8; ++j)
                    acc[i][j] = __builtin_amdgcn_mfma_f32_16x16x32_f16(ah[i], bh[j], acc[i][j], 0, 0, 0);
            __builtin_amdgcn_s_setprio(0);

            __builtin_amdgcn_sched_barrier(0);
            asm volatile("" ::: "memory");
            __builtin_amdgcn_s_barrier();      // readers done -> next stage may overwrite
        }

        // ---- per-chunk argmin epilogue (LDS cns only; prologue loads may fly)
        const int colw = ci * 256 + wn * 128;   // offset into cns
#pragma unroll
        for (int i = 0; i < 4; ++i)
#pragma unroll
            for (int r = 0; r < 4; ++r) {
                float m1 = 3.4e38f, m2 = 3.4e38f;
                int   i1 = 0;
#pragma unroll
                for (int j = 0; j < 8; ++j) {
                    const float cn = cns[colw + j * 16 + l15];
                    const float d  = fmaf(-2.0f, acc[i][j][r], cn);
                    const int   ix = kb0 + colw + j * 16 + l15;
                    if (d < m1) { m2 = m1; m1 = d; i1 = ix; }
                    else if (d < m2) { m2 = d; }
                }
#pragma unroll
                for (int off = 1; off < 16; off <<= 1) {
                    const float om1 = __shfl_xor(m1, off, 64);
                    const int   oi  = __shfl_xor(i1, off, 64);
                    const float om2 = __shfl_xor(m2, off, 64);
                    const float nm2 = fminf(fminf(m2, om2), fmaxf(m1, om1));
                    if (om1 < m1 || (om1 == m1 && oi < i1)) { m1 = om1; i1 = oi; }
                    m2 = nm2;
                }
                if (l15 == 0) {
                    const int rr = i * 16 + l4 * 4 + r;
                    red_d[wm][rr][wn] = m1;
                    red_i[wm][rr][wn] = i1;
                    red_2[wm][rr][wn] = m2;
                }
            }
        asm volatile("s_waitcnt lgkmcnt(0)" ::: "memory");
        __builtin_amdgcn_s_barrier();
        __builtin_amdgcn_sched_barrier(0);

        if (tid < 128) {
            const int hh = tid >> 6;
            const int rr = tid & 63;
            float m1 = red_d[hh][rr][0], m2 = red_2[hh][rr][0];
            int   i1 = red_i[hh][rr][0];
            const float om1 = red_d[hh][rr][1];
            const int   oi  = red_i[hh][rr][1];
            const float om2 = red_2[hh][rr][1];
            m2 = fminf(fminf(m2, om2), fmaxf(m1, om1));
            if (om1 < m1 || (om1 == m1 && oi < i1)) { m1 = om1; i1 = oi; }
            const float nm2 = fminf(fminf(rm2, m2), fmaxf(rm1, m1));
            if (m1 < rm1 || (m1 == rm1 && i1 < ri1)) { rm1 = m1; ri1 = i1; }
            rm2 = nm2;
        }
        // red re-written only after next chunk's 64 barriers -> safe
    }

    if (tid < 128) {
        const size_t off = (size_t)ks * N_ROWS + row0 + tid;
        m1buf[off] = rm1;
        i1buf[off] = ri1;
        m2buf[off] = rm2;
    }
}

// ============================================================================
// Merge K-slices: final argmin + certainty test + worklist
// ============================================================================
__global__ __launch_bounds__(256) void kmeans_merge4(
    const float* __restrict__ m1buf, const int* __restrict__ i1buf,
    const float* __restrict__ m2buf, int* __restrict__ out,
    int* __restrict__ urows, unsigned int* __restrict__ ucount)
{
    const int row = blockIdx.x * 256 + threadIdx.x;
    float m1 = m1buf[row], m2 = m2buf[row];
    int   i1 = i1buf[row];
#pragma unroll
    for (int s = 1; s < KSL; ++s) {
        const float om1 = m1buf[(size_t)s * N_ROWS + row];
        const float om2 = m2buf[(size_t)s * N_ROWS + row];
        const int   oi  = i1buf[(size_t)s * N_ROWS + row];
        const float nm2 = fminf(fminf(m2, om2), fmaxf(m1, om1));
        if (om1 < m1 || (om1 == m1 && oi < i1)) { m1 = om1; i1 = oi; }
        m2 = nm2;
    }
    out[row] = i1;
    if (m2 - m1 <= EPS_GAP) {
        const unsigned slot = atomicAdd(ucount, 1u);
        if (slot < (unsigned)CAP) urows[slot] = row;
    }
}

// ============================================================================
// Gather: uncertain rows' x -> compact fp16 hi/lo buffers [slot][1024]
// ============================================================================
__global__ __launch_bounds__(64) void kmeans_gather(
    const float* __restrict__ x, const int* __restrict__ urows,
    const unsigned int* __restrict__ ucount,
    _Float16* __restrict__ xch, _Float16* __restrict__ xcl)
{
    const unsigned cntr = *ucount;
    const unsigned cnt = cntr > (unsigned)CAP ? (unsigned)CAP : cntr;
    const unsigned slot = blockIdx.x;
    if (slot >= cnt) return;
    const int row = urows[slot];
    const int t = threadIdx.x;
#pragma unroll
    for (int e = 0; e < 16; ++e) {
        const int idx = e * 64 + t;
        const float v = x[(size_t)row * D_DIM + idx];
        const _Float16 h = (_Float16)v;
        xch[(size_t)slot * D_DIM + idx] = h;
        xcl[(size_t)slot * D_DIM + idx] = (_Float16)(v - (float)h);
    }
}

// ============================================================================
// Rescore (K-split x8): exact 3-pass hi/lo over 512-col slice for 32 rows.
// ============================================================================
constexpr int R_XH = 0;        // 1024 halves (2 sub)
constexpr int R_XL = 1024;     // 1024
constexpr int R_CH = 2048;     // 8192 (16 sub)
constexpr int R_CL = 10240;    // 8192
constexpr int R_HB = 18432;    // per buffer (36 KB)

__global__ __launch_bounds__(256) void kmeans_rescore2(
    const _Float16* __restrict__ xch, const _Float16* __restrict__ xcl,
    const _Float16* __restrict__ ChiT, const _Float16* __restrict__ CloT,
    const float* __restrict__ Cnorm, const unsigned int* __restrict__ ucount,
    float* __restrict__ rpd, int* __restrict__ rpi)
{
    const unsigned cntr = *ucount;
    const unsigned cnt = cntr > (unsigned)CAP ? (unsigned)CAP : cntr;
    const int bid = blockIdx.x;
    const int ksl = bid & 7;
    const int grp = bid >> 3;
    if ((unsigned)(grp * 32) >= cnt) return;

    __shared__ _Float16 lds[2][R_HB];
    __shared__ float rd[32][4];
    __shared__ int   ri[32][4];

    const int tid  = threadIdx.x;
    const int lane = tid & 63;
    const int wid  = tid >> 6;
    const int l15  = lane & 15;
    const int l4   = lane >> 4;
    const int kge  = l4 ^ ((l15 >> 1) & 3);
    const int fragoff = l15 * 32 + kge * 8;
    const int scol = lane >> 2;
    const int skg  = (lane & 3) ^ ((scol >> 1) & 3);

    const int base  = grp * 32;
    const int kbase = ksl * (K_CENT / RSL);

    float best[2][4];
    int   bidx[2][4];
#pragma unroll
    for (int i = 0; i < 2; ++i)
#pragma unroll
        for (int r = 0; r < 4; ++r) { best[i][r] = 3.4e38f; bidx[i][r] = 0; }

    for (int ch = 0; ch < 2; ++ch) {
        const int kc = kbase + ch * 256;
        floatx4 acc[2][4];
#pragma unroll
        for (int i = 0; i < 2; ++i)
#pragma unroll
            for (int j = 0; j < 4; ++j) acc[i][j] = (floatx4)0.0f;

        {
            _Float16* buf = lds[0];
#pragma unroll
            for (int q = 0; q < 4; ++q) {
                const int sub = wid * 4 + q;
                gload_lds16(&ChiT[(size_t)(kc + sub * 16 + scol) * D_DIM + 0 + skg * 8], buf + R_CH + sub * 512);
                gload_lds16(&CloT[(size_t)(kc + sub * 16 + scol) * D_DIM + 0 + skg * 8], buf + R_CL + sub * 512);
            }
            if (wid < 2)
                gload_lds16(&xch[(size_t)(base + wid * 16 + scol) * D_DIM + 0 + skg * 8], buf + R_XH + wid * 512);
            else
                gload_lds16(&xcl[(size_t)(base + (wid - 2) * 16 + scol) * D_DIM + 0 + skg * 8], buf + R_XL + (wid - 2) * 512);
            __syncthreads();
        }

        for (int kdi = 0; kdi < D_DIM / 32; ++kdi) {
            const int cur = kdi & 1;
            _Float16* bufc = lds[cur];
            _Float16* bufn = lds[cur ^ 1];
            const int  kdn = (kdi + 1) * 32;
            const bool pf  = (kdi + 1 < D_DIM / 32);

            if (pf) {
#pragma unroll
                for (int q = 0; q < 4; ++q) {
                    const int sub = wid * 4 + q;
                    gload_lds16(&ChiT[(size_t)(kc + sub * 16 + scol) * D_DIM + kdn + skg * 8], bufn + R_CH + sub * 512);
                    gload_lds16(&CloT[(size_t)(kc + sub * 16 + scol) * D_DIM + kdn + skg * 8], bufn + R_CL + sub * 512);
                }
                if (wid < 2)
                    gload_lds16(&xch[(size_t)(base + wid * 16 + scol) * D_DIM + kdn + skg * 8], bufn + R_XH + wid * 512);
                else
                    gload_lds16(&xcl[(size_t)(base + (wid - 2) * 16 + scol) * D_DIM + kdn + skg * 8], bufn + R_XL + (wid - 2) * 512);
            }

            half8 ah[2], al[2], bh[4], bl[4];
#pragma unroll
            for (int i = 0; i < 2; ++i) {
                ah[i] = *(const half8*)(bufc + R_XH + i * 512 + fragoff);
                al[i] = *(const half8*)(bufc + R_XL + i * 512 + fragoff);
            }
#pragma unroll
            for (int j = 0; j < 4; ++j) {
                bh[j] = *(const half8*)(bufc + R_CH + (wid * 4 + j) * 512 + fragoff);
                bl[j] = *(const half8*)(bufc + R_CL + (wid * 4 + j) * 512 + fragoff);
            }
#pragma unroll
            for (int i = 0; i < 2; ++i)
#pragma unroll
                for (int j = 0; j < 4; ++j) {
                    acc[i][j] = __builtin_amdgcn_mfma_f32_16x16x32_f16(ah[i], bh[j], acc[i][j], 0, 0, 0);
                    acc[i][j] = __builtin_amdgcn_mfma_f32_16x16x32_f16(ah[i], bl[j], acc[i][j], 0, 0, 0);
                    acc[i][j] = __builtin_amdgcn_mfma_f32_16x16x32_f16(al[i], bh[j], acc[i][j], 0, 0, 0);
                }
            __syncthreads();
        }

#pragma unroll
        for (int j = 0; j < 4; ++j) {
            const int col = kc + wid * 64 + j * 16 + l15;
            const float cn = Cnorm[col];
#pragma unroll
            for (int i = 0; i < 2; ++i)
#pragma unroll
                for (int r = 0; r < 4; ++r) {
                    const float d = fmaf(-2.0f, acc[i][j][r], cn);
                    if (d < best[i][r]) { best[i][r] = d; bidx[i][r] = col; }
                }
        }
    }

#pragma unroll
    for (int i = 0; i < 2; ++i)
#pragma unroll
        for (int r = 0; r < 4; ++r) {
            float m1 = best[i][r];
            int   i1 = bidx[i][r];
#pragma unroll
            for (int off = 1; off < 16; off <<= 1) {
                const float om1 = __shfl_xor(m1, off, 64);
                const int   oi  = __shfl_xor(i1, off, 64);
                if (om1 < m1 || (om1 == m1 && oi < i1)) { m1 = om1; i1 = oi; }
            }
            if (l15 == 0) { rd[i * 16 + l4 * 4 + r][wid] = m1; ri[i * 16 + l4 * 4 + r][wid] = i1; }
        }
    __syncthreads();

    if (tid < 32) {
        float m1 = rd[tid][0];
        int   i1 = ri[tid][0];
#pragma unroll
        for (int w = 1; w < 4; ++w) {
            const float om1 = rd[tid][w];
            const int   oi  = ri[tid][w];
            if (om1 < m1 || (om1 == m1 && oi < i1)) { m1 = om1; i1 = oi; }
        }
        rpd[(size_t)(base + tid) * RSL + ksl] = m1;
        rpi[(size_t)(base + tid) * RSL + ksl] = i1;
    }
}

// ============================================================================
// Merge rescore slices -> final out for uncertain rows
// ============================================================================
__global__ __launch_bounds__(256) void kmeans_merge2(
    const float* __restrict__ rpd, const int* __restrict__ rpi,
    const int* __restrict__ urows, const unsigned int* __restrict__ ucount,
    int* __restrict__ out)
{
    const unsigned cntr = *ucount;
    const unsigned cnt = cntr > (unsigned)CAP ? (unsigned)CAP : cntr;
    const unsigned s = blockIdx.x * 256 + threadIdx.x;
    if (s >= cnt) return;
    float m1 = rpd[(size_t)s * RSL];
    int   i1 = rpi[(size_t)s * RSL];
#pragma unroll
    for (int k = 1; k < RSL; ++k) {
        const float om = rpd[(size_t)s * RSL + k];
        const int   oi = rpi[(size_t)s * RSL + k];
        if (om < m1 || (om == m1 && oi < i1)) { m1 = om; i1 = oi; }
    }
    out[urows[s]] = i1;
}

// ============================================================================
// Fallback A: proven R3 3-pass MFMA kernel (hi/lo, direct out)
// ============================================================================
constexpr int F_XH = 0, F_XL = 4096, F_CH = 8192, F_CL = 16384, F_HB = 24576;

__device__ __forceinline__ void write_x2(_Float16* buf, const float4 v, int r, int kb) {
    const _Float16 h0 = (_Float16)v.x, h1 = (_Float16)v.y;
    const _Float16 h2 = (_Float16)v.z, h3 = (_Float16)v.w;
    const int kg  = kb >> 3;
    const int hs  = (kb >> 2) & 1;
    const int kge = kg ^ ((r >> 1) & 3);
    const int base = (r >> 4) * 512 + (r & 15) * 32 + kge * 8 + hs * 4;
    *(half4*)(buf + F_XH + base) = (half4){h0, h1, h2, h3};
    *(half4*)(buf + F_XL + base) = (half4){(_Float16)(v.x - (float)h0), (_Float16)(v.y - (float)h1),
                                           (_Float16)(v.z - (float)h2), (_Float16)(v.w - (float)h3)};
}

__global__ __launch_bounds__(512, 2) void kmeans_mfma_kernel(
    const float* __restrict__ x, const _Float16* __restrict__ ChiT,
    const _Float16* __restrict__ CloT, const float* __restrict__ Cnorm,
    int* __restrict__ out)
{
    __shared__ _Float16 lds[2][F_HB];
    __shared__ float red_d[2][64][4];
    __shared__ int   red_i[2][64][4];

    const int tid  = threadIdx.x;
    const int lane = tid & 63;
    const int wid  = tid >> 6;
    const int wm   = wid >> 2;
    const int wn   = wid & 3;
    const int row0 = blockIdx.x * 128;
    const int l15 = lane & 15;
    const int l4  = lane >> 4;
    const int kge = l4 ^ ((l15 >> 1) & 3);
    const int fragoff = l15 * 32 + kge * 8;
    const int sr = tid >> 2, sc = tid & 3;
    const int ccol = lane >> 2;
    const int ckg  = (lane & 3) ^ ((ccol >> 1) & 3);

    float best[4][4];
    int   bidx[4][4];
#pragma unroll
    for (int i = 0; i < 4; ++i)
#pragma unroll
        for (int r = 0; r < 4; ++r) { best[i][r] = 3.4e38f; bidx[i][r] = 0; }

    for (int kc = 0; kc < K_CENT; kc += 256) {
        floatx4 acc[4][4];
#pragma unroll
        for (int i = 0; i < 4; ++i)
#pragma unroll
            for (int j = 0; j < 4; ++j) acc[i][j] = (floatx4)0.0f;
        {
            _Float16* buf = lds[0];
            const float4 xv0 = *(const float4*)&x[(size_t)(row0 + sr) * D_DIM + 0 + sc * 4];
            const float4 xv1 = *(const float4*)&x[(size_t)(row0 + sr) * D_DIM + 16 + sc * 4];
            gload_lds16(&ChiT[(size_t)(kc + wid * 16 + ccol) * D_DIM + 0 + ckg * 8], buf + F_CH + wid * 512);
            gload_lds16(&ChiT[(size_t)(kc + (wid + 8) * 16 + ccol) * D_DIM + 0 + ckg * 8], buf + F_CH + (wid + 8) * 512);
            gload_lds16(&CloT[(size_t)(kc + wid * 16 + ccol) * D_DIM + 0 + ckg * 8], buf + F_CL + wid * 512);
            gload_lds16(&CloT[(size_t)(kc + (wid + 8) * 16 + ccol) * D_DIM + 0 + ckg * 8], buf + F_CL + (wid + 8) * 512);
            write_x2(buf, xv0, sr, sc * 4);
            write_x2(buf, xv1, sr, sc * 4 + 16);
            __syncthreads();
        }
        for (int kdi = 0; kdi < D_DIM / 32; ++kdi) {
            const int cur = kdi & 1;
            _Float16* bufc = lds[cur];
            _Float16* bufn = lds[cur ^ 1];
            const int  kdn = (kdi + 1) * 32;
            const bool pf  = (kdi + 1 < D_DIM / 32);
            float4 xv0, xv1;
            if (pf) {
                xv0 = *(const float4*)&x[(size_t)(row0 + sr) * D_DIM + kdn + sc * 4];
                xv1 = *(const float4*)&x[(size_t)(row0 + sr) * D_DIM + kdn + 16 + sc * 4];
                gload_lds16(&ChiT[(size_t)(kc + wid * 16 + ccol) * D_DIM + kdn + ckg * 8], bufn + F_CH + wid * 512);
                gload_lds16(&ChiT[(size_t)(kc + (wid + 8) * 16 + ccol) * D_DIM + kdn + ckg * 8], bufn + F_CH + (wid + 8) * 512);
                gload_lds16(&CloT[(size_t)(kc + wid * 16 + ccol) * D_DIM + kdn + ckg * 8], bufn + F_CL + wid * 512);
                gload_lds16(&CloT[(size_t)(kc + (wid + 8) * 16 + ccol) * D_DIM + kdn + ckg * 8], bufn + F_CL + (wid + 8) * 512);
            }
            half8 ah[4], al[4], bh[4], bl[4];
#pragma unroll
            for (int i = 0; i < 4; ++i) {
                ah[i] = *(const half8*)(bufc + F_XH + (wm * 4 + i) * 512 + fragoff);
                al[i] = *(const half8*)(bufc + F_XL + (wm * 4 + i) * 512 + fragoff);
            }
#pragma unroll
            for (int j = 0; j < 4; ++j) {
                bh[j] = *(const half8*)(bufc + F_CH + (wn * 4 + j) * 512 + fragoff);
                bl[j] = *(const half8*)(bufc + F_CL + (wn * 4 + j) * 512 + fragoff);
            }
#pragma unroll
            for (int i = 0; i < 4; ++i)
#pragma unroll
                for (int j = 0; j < 4; ++j) {
                    acc[i][j] = __builtin_amdgcn_mfma_f32_16x16x32_f16(ah[i], bh[j], acc[i][j], 0, 0, 0);
                    acc[i][j] = __builtin_amdgcn_mfma_f32_16x16x32_f16(ah[i], bl[j], acc[i][j], 0, 0, 0);
                    acc[i][j] = __builtin_amdgcn_mfma_f32_16x16x32_f16(al[i], bh[j], acc[i][j], 0, 0, 0);
                }
            if (pf) {
                write_x2(bufn, xv0, sr, sc * 4);
                write_x2(bufn, xv1, sr, sc * 4 + 16);
            }
            __syncthreads();
        }
        const int colw = kc + wn * 64;
#pragma unroll
        for (int ns = 0; ns < 4; ++ns) {
            const float cn = Cnorm[colw + ns * 16 + l15];
            const int   ix = colw + ns * 16 + l15;
#pragma unroll
            for (int i = 0; i < 4; ++i)
#pragma unroll
                for (int r = 0; r < 4; ++r) {
                    const float d = fmaf(-2.0f, acc[i][ns][r], cn);
                    if (d < best[i][r]) { best[i][r] = d; bidx[i][r] = ix; }
                }
        }
    }
#pragma unroll
    for (int i = 0; i < 4; ++i)
#pragma unroll
        for (int r = 0; r < 4; ++r) {
            float d  = best[i][r];
            int   ix = bidx[i][r];
#pragma unroll
            for (int off = 1; off < 16; off <<= 1) {
                const float od = __shfl_xor(d, off, 64);
                const int   oi = __shfl_xor(ix, off, 64);
                if (od < d || (od == d && oi < ix)) { d = od; ix = oi; }
            }
            if (l15 == 0) {
                red_d[wm][i * 16 + l4 * 4 + r][wn] = d;
                red_i[wm][i * 16 + l4 * 4 + r][wn] = ix;
            }
        }
    __syncthreads();
    if (tid < 128) {
        const int hh = tid >> 6, rr = tid & 63;
        float bd = red_d[hh][rr][0];
        int   bi2 = red_i[hh][rr][0];
#pragma unroll
        for (int w = 1; w < 4; ++w) {
            const float od = red_d[hh][rr][w];
            const int   oi = red_i[hh][rr][w];
            if (od < bd || (od == bd && oi < bi2)) { bd = od; bi2 = oi; }
        }
        out[row0 + tid] = bi2;
    }
}

// ============================================================================
// Fallback B: R1 fp32 kernel
// ============================================================================
__global__ __launch_bounds__(256, 2) void kmeans_assign_f32(
    const float* __restrict__ x, const float* __restrict__ Cm,
    const float* __restrict__ Cnorm, int* __restrict__ out)
{
    __shared__ float xs[32][64];
    __shared__ float cs[32][64];
    const int tid = threadIdx.x;
    const int tx = tid & 15, ty = tid >> 4;
    const int row0 = blockIdx.x * 64;
    const int xr = tid >> 3, xc = tid & 7;
    const int cr = tid >> 4, cc = tid & 15;
    float best[4]; int bidx[4];
#pragma unroll
    for (int i = 0; i < 4; ++i) { best[i] = 3.4e38f; bidx[i] = 0; }
    for (int kc = 0; kc < K_CENT; kc += 64) {
        float acc[16];
#pragma unroll
        for (int i = 0; i < 16; ++i) acc[i] = 0.0f;
        for (int kd = 0; kd < D_DIM; kd += 32) {
            const float4 xv0 = *(const float4*)&x[(size_t)(row0 + xr) * D_DIM + kd + xc * 4];
            const float4 xv1 = *(const float4*)&x[(size_t)(row0 + xr + 32) * D_DIM + kd + xc * 4];
            const float4 cv0 = *(const float4*)&Cm[(size_t)(kd + cr) * K_CENT + kc + cc * 4];
            const float4 cv1 = *(const float4*)&Cm[(size_t)(kd + cr + 16) * K_CENT + kc + cc * 4];
            __syncthreads();
            xs[xc*4+0][xr] = xv0.x; xs[xc*4+1][xr] = xv0.y; xs[xc*4+2][xr] = xv0.z; xs[xc*4+3][xr] = xv0.w;
            xs[xc*4+0][xr+32] = xv1.x; xs[xc*4+1][xr+32] = xv1.y; xs[xc*4+2][xr+32] = xv1.z; xs[xc*4+3][xr+32] = xv1.w;
            *(float4*)&cs[cr][cc*4]    = cv0;
            *(float4*)&cs[cr+16][cc*4] = cv1;
            __syncthreads();
#pragma unroll
            for (int kk = 0; kk < 32; ++kk) {
                const float4 a = *(const float4*)&xs[kk][ty*4];
                const float4 b = *(const float4*)&cs[kk][tx*4];
                acc[ 0] += a.x*b.x; acc[ 1] += a.x*b.y; acc[ 2] += a.x*b.z; acc[ 3] += a.x*b.w;
                acc[ 4] += a.y*b.x; acc[ 5] += a.y*b.y; acc[ 6] += a.y*b.z; acc[ 7] += a.y*b.w;
                acc[ 8] += a.z*b.x; acc[ 9] += a.z*b.y; acc[10] += a.z*b.z; acc[11] += a.z*b.w;
                acc[12] += a.w*b.x; acc[13] += a.w*b.y; acc[14] += a.w*b.z; acc[15] += a.w*b.w;
            }
        }
        const float4 cn = *(const float4*)&Cnorm[kc + tx*4];
        const float cnv[4] = {cn.x, cn.y, cn.z, cn.w};
#pragma unroll
        for (int i = 0; i < 4; ++i)
#pragma unroll
            for (int j = 0; j < 4; ++j) {
                const float dist = cnv[j] - 2.0f * acc[i*4+j];
                const int   idx  = kc + tx*4 + j;
                if (dist < best[i]) { best[i] = dist; bidx[i] = idx; }
            }
    }
#pragma unroll
    for (int i = 0; i < 4; ++i) {
        float d = best[i]; int ix = bidx[i];
#pragma unroll
        for (int off = 1; off < 16; off <<= 1) {
            const float od = __shfl_xor(d, off, 64);
            const int   oi = __shfl_xor(ix, off, 64);
            if (od < d || (od == d && oi < ix)) { d = od; ix = oi; }
        }
        if (tx == 0) out[row0 + ty*4 + i] = ix;
    }
}

// ============================================================================
extern "C" void kernel_launch(void* const* d_in, const int* in_sizes, int n_in,
                              void* d_out, int out_size, void* d_ws, size_t ws_size,
                              hipStream_t stream) {
    const float* x     = (const float*)d_in[0];
    const float* C     = (const float*)d_in[1];
    const float* Cnorm = (const float*)d_in[2];
    int* out = (int*)d_out;

    const size_t chalf = (size_t)K_CENT * D_DIM;   // halves per C array
    const size_t capd  = (size_t)CAP * D_DIM;      // halves per xc array
    const size_t xhN   = (size_t)N_ROWS * D_DIM;   // halves for x_hi

    const size_t sz_base = (2 * chalf + 2 * capd) * 2
                         + (size_t)KSL * N_ROWS * 12
                         + (size_t)CAP * RSL * 8
                         + (size_t)CAP * 4 + 64;
    const size_t need_full = sz_base + xhN * 2;
    const size_t need_r3   = 2 * chalf * 2;

    if (ws_size >= need_full) {
        _Float16* ChiT = (_Float16*)d_ws;
        _Float16* CloT = ChiT + chalf;
        _Float16* xch  = CloT + chalf;
        _Float16* xcl  = xch + capd;
        float* m1buf = (float*)(xcl + capd);
        float* m2buf = m1buf + (size_t)KSL * N_ROWS;
        int*   i1buf = (int*)(m2buf + (size_t)KSL * N_ROWS);
        float* rpd   = (float*)(i1buf + (size_t)KSL * N_ROWS);
        int*   rpi   = (int*)(rpd + (size_t)CAP * RSL);
        int*   urows = rpi + (size_t)CAP * RSL;
        unsigned int* ucount = (unsigned int*)(urows + CAP);
        _Float16* xh = (_Float16*)(ucount + 16);

        convert_C_kernel<<<dim3(128, 32), 256, 0, stream>>>(C, ChiT, CloT);
        convert_x_kernel<<<dim3((int)(xhN / 2048)), 256, 0, stream>>>(x, xh);
        hipMemsetAsync(ucount, 0, sizeof(unsigned int), stream);
        kmeans_pass1<<<dim3(256 * KSL), 256, 0, stream>>>(xh, ChiT, Cnorm, m1buf, i1buf, m2buf);
        kmeans_merge4<<<dim3(N_ROWS / 256), 256, 0, stream>>>(m1buf, i1buf, m2buf, out, urows, ucount);
        kmeans_gather<<<dim3(CAP), 64, 0, stream>>>(x, urows, ucount, xch, xcl);
        kmeans_rescore2<<<dim3((CAP / 32) * RSL), 256, 0, stream>>>(xch, xcl, ChiT, CloT, Cnorm, ucount, rpd, rpi);
        kmeans_merge2<<<dim3(CAP / 256), 256, 0, stream>>>(rpd, rpi, urows, ucount, out);
    } else if (ws_size >= need_r3) {
        _Float16* ChiT = (_Float16*)d_ws;
        _Float16* CloT = ChiT + chalf;
        convert_C_kernel<<<dim3(128, 32), 256, 0, stream>>>(C, ChiT, CloT);
        kmeans_mfma_kernel<<<dim3(N_ROWS / 128), 512, 0, stream>>>(x, ChiT, CloT, Cnorm, out);
    } else {
        kmeans_assign_f32<<<dim3(N_ROWS / 64), 256, 0, stream>>>(x, C, Cnorm, out);
    }
}

// Round 9
// 476.206 us; speedup vs baseline: 2.1174x; 1.0087x over previous
//
#include <hip/hip_runtime.h>
#include <cstdint>
#include <cstddef>

typedef _Float16 half8 __attribute__((ext_vector_type(8)));
typedef _Float16 half4 __attribute__((ext_vector_type(4)));
typedef float    floatx4 __attribute__((ext_vector_type(4)));

constexpr int N_ROWS = 32768;
constexpr int D_DIM  = 1024;
constexpr int K_CENT = 4096;
constexpr int CAP    = 4096;      // max uncertain rows (E[count]~620)
constexpr int KSL    = 2;         // pass1 K split (2048 cols/slice)
constexpr int RSL    = 8;         // rescore K split (512 cols/slice)
constexpr float EPS_GAP = 0.4f;   // 2 * (14-sigma hh-error bound)

__device__ __forceinline__ void gload_lds16(const void* g, void* l) {
    __builtin_amdgcn_global_load_lds(
        (const __attribute__((address_space(1))) uint32_t*)g,
        (__attribute__((address_space(3))) uint32_t*)l, 16, 0, 0);
}

// ============================================================================
// Pre-pass 1: C[d][k] f32 -> C_hiT[k][d], C_loT[k][d] fp16 (transposed split)
// ============================================================================
__global__ __launch_bounds__(256) void convert_C_kernel(
    const float* __restrict__ C, _Float16* __restrict__ ChiT, _Float16* __restrict__ CloT)
{
    __shared__ float tile[32][33];
    const int bk = blockIdx.x, bd = blockIdx.y, t = threadIdx.x;
    const int r = t >> 3, c4 = (t & 7) * 4;
    const float4 v = *(const float4*)&C[(size_t)(bd * 32 + r) * K_CENT + bk * 32 + c4];
    tile[r][c4 + 0] = v.x; tile[r][c4 + 1] = v.y;
    tile[r][c4 + 2] = v.z; tile[r][c4 + 3] = v.w;
    __syncthreads();
    half4 h, l;
#pragma unroll
    for (int i = 0; i < 4; ++i) {
        const float f = tile[c4 + i][r];
        const _Float16 hi = (_Float16)f;
        h[i] = hi;
        l[i] = (_Float16)(f - (float)hi);
    }
    *(half4*)&ChiT[(size_t)(bk * 32 + r) * D_DIM + bd * 32 + c4] = h;
    *(half4*)&CloT[(size_t)(bk * 32 + r) * D_DIM + bd * 32 + c4] = l;
}

// ============================================================================
// Pre-pass 2: x f32 -> x_hi fp16 (elementwise)
// ============================================================================
__global__ __launch_bounds__(256) void convert_x_kernel(
    const float* __restrict__ x, _Float16* __restrict__ xh)
{
    const size_t g = (size_t)blockIdx.x * 256 + threadIdx.x;   // 8 elems each
    const float4 v0 = *(const float4*)&x[g * 8];
    const float4 v1 = *(const float4*)&x[g * 8 + 4];
    half8 h;
    h[0] = (_Float16)v0.x; h[1] = (_Float16)v0.y; h[2] = (_Float16)v0.z; h[3] = (_Float16)v0.w;
    h[4] = (_Float16)v1.x; h[5] = (_Float16)v1.y; h[6] = (_Float16)v1.z; h[7] = (_Float16)v1.w;
    *(half8*)&xh[g * 8] = h;
}

// ============================================================================
// Pass 1: hh-only GEMM, block 128 rows x 256-col chunks, 4 waves (2x2),
// per-wave 64x128 (acc[4][8]).  2-deep counted-vmcnt pipeline (T4):
//   step s: stage6(buf[(s+2)%3]) -> vmcnt(12) -> barrier -> ds_read -> MFMA -> barrier
// Loads get TWO MFMA phases to land (covers LLC/HBM latency).
// KSL=2, grid 512 (2 blocks/CU), XCD-bijective (each XCD owns one 4MB C-half).
// ============================================================================
constexpr int P_XH = 0;        // x_hi [ 8 sub][16 r][4 kg][8] = 4096 halves
constexpr int P_CH = 4096;     // C_hi [16 sub][16 c][4 kg][8] = 8192 halves
constexpr int P_HB = 12288;    // 24 KB per buffer

__device__ __forceinline__ void stage6(
    _Float16* buf, const _Float16* __restrict__ xh, const _Float16* __restrict__ ChiT,
    int row0, int kc, int kd, int wid, int scol, int skg)
{
#pragma unroll
    for (int q = 0; q < 2; ++q) {
        const int sub = wid * 2 + q;
        gload_lds16(&xh[(size_t)(row0 + sub * 16 + scol) * D_DIM + kd + skg * 8],
                    buf + P_XH + sub * 512);
    }
#pragma unroll
    for (int q = 0; q < 4; ++q) {
        const int sub = wid * 4 + q;
        gload_lds16(&ChiT[(size_t)(kc + sub * 16 + scol) * D_DIM + kd + skg * 8],
                    buf + P_CH + sub * 512);
    }
}

__global__ __launch_bounds__(256, 2) void kmeans_pass1(
    const _Float16* __restrict__ xh, const _Float16* __restrict__ ChiT,
    const float* __restrict__ Cnorm,
    float* __restrict__ m1buf, int* __restrict__ i1buf, float* __restrict__ m2buf)
{
    __shared__ _Float16 lds[3][P_HB];        // 72 KB (3-deep rotation)
    __shared__ float red_d[2][64][2];
    __shared__ int   red_i[2][64][2];
    __shared__ float red_2[2][64][2];

    // bijective: xcd = bid&7; ks = xcd&1; rb = (bid>>3)*4 + (xcd>>1)
    const int bid  = blockIdx.x;
    const int xcd  = bid & 7;
    const int ks   = xcd & 1;
    const int rb   = (bid >> 3) * 4 + (xcd >> 1);   // 0..255
    const int row0 = rb * 128;
    const int kb0  = ks * (K_CENT / KSL);

    const int tid  = threadIdx.x;
    const int lane = tid & 63;
    const int wid  = tid >> 6;          // 0..3
    const int wm   = wid >> 1;          // 0..1 (64-row half)
    const int wn   = wid & 1;           // 0..1 (128-col half)

    const int l15 = lane & 15;
    const int l4  = lane >> 4;
    const int kge = l4 ^ ((l15 >> 1) & 3);
    const int fragoff = l15 * 32 + kge * 8;

    const int scol = lane >> 2;                       // 0..15
    const int skg  = (lane & 3) ^ ((scol >> 1) & 3);  // pre-swizzled source kg

    float rm1 = 3.4e38f, rm2 = 3.4e38f;
    int   ri1 = 0;

    constexpr int NSTEP = ((K_CENT / KSL) / 256) * 32;   // 256 flat steps

    // prologue: stage steps 0,1 into buf 0,1 (12 loads in flight)
    stage6(lds[0], xh, ChiT, row0, kb0, 0,  wid, scol, skg);
    stage6(lds[1], xh, ChiT, row0, kb0, 32, wid, scol, skg);

    floatx4 acc[4][8];
#pragma unroll
    for (int i = 0; i < 4; ++i)
#pragma unroll
        for (int j = 0; j < 8; ++j) acc[i][j] = (floatx4)0.0f;

    int cur = 0;
    for (int s = 0; s < NSTEP; ++s) {
        _Float16* bufc = lds[cur];
        const int s2 = s + 2;
        if (s2 < NSTEP) {
            const int nkc = kb0 + (s2 >> 5) * 256;
            const int nkd = (s2 & 31) * 32;
            const int b2  = (cur >= 1) ? cur - 1 : 2;    // (cur+2)%3
            stage6(lds[b2], xh, ChiT, row0, nkc, nkd, wid, scol, skg);
            asm volatile("s_waitcnt vmcnt(12)" ::: "memory");   // step s ready; 12 fly
        } else if (s + 1 < NSTEP) {
            asm volatile("s_waitcnt vmcnt(6)" ::: "memory");
        } else {
            asm volatile("s_waitcnt vmcnt(0)" ::: "memory");
        }
        __builtin_amdgcn_s_barrier();
        __builtin_amdgcn_sched_barrier(0);

        half8 ah[4], bh[8];
#pragma unroll
        for (int i = 0; i < 4; ++i)
            ah[i] = *(const half8*)(bufc + P_XH + (wm * 4 + i) * 512 + fragoff);
#pragma unroll
        for (int j = 0; j < 8; ++j)
            bh[j] = *(const half8*)(bufc + P_CH + (wn * 8 + j) * 512 + fragoff);

        __builtin_amdgcn_s_setprio(1);
#pragma unroll
        for (int i = 0; i < 4; ++i)
#pragma unroll
            for (int j = 0; j < 8; ++j)
                acc[i][j] = __builtin_amdgcn_mfma_f32_16x16x32_f16(ah[i], bh[j], acc[i][j], 0, 0, 0);
        __builtin_amdgcn_s_setprio(0);

        __builtin_amdgcn_sched_barrier(0);
        asm volatile("" ::: "memory");
        __builtin_amdgcn_s_barrier();      // readers done -> buf[cur] may be re-staged

        cur = (cur == 2) ? 0 : cur + 1;

        if ((s & 31) == 31) {
            // ---- per-chunk argmin epilogue (hoisted Cnorm regs; next stages fly)
            const int ci   = s >> 5;
            const int colw = ci * 256 + wn * 128;
            float cn8[8];
#pragma unroll
            for (int j = 0; j < 8; ++j) cn8[j] = Cnorm[kb0 + colw + j * 16 + l15];

#pragma unroll
            for (int i = 0; i < 4; ++i)
#pragma unroll
                for (int r = 0; r < 4; ++r) {
                    float m1 = 3.4e38f, m2 = 3.4e38f;
                    int   i1 = 0;
#pragma unroll
                    for (int j = 0; j < 8; ++j) {
                        const float d  = fmaf(-2.0f, acc[i][j][r], cn8[j]);
                        const int   ix = kb0 + colw + j * 16 + l15;
                        if (d < m1) { m2 = m1; m1 = d; i1 = ix; }
                        else if (d < m2) { m2 = d; }
                    }
#pragma unroll
                    for (int off = 1; off < 16; off <<= 1) {
                        const float om1 = __shfl_xor(m1, off, 64);
                        const int   oi  = __shfl_xor(i1, off, 64);
                        const float om2 = __shfl_xor(m2, off, 64);
                        const float nm2 = fminf(fminf(m2, om2), fmaxf(m1, om1));
                        if (om1 < m1 || (om1 == m1 && oi < i1)) { m1 = om1; i1 = oi; }
                        m2 = nm2;
                    }
                    if (l15 == 0) {
                        const int rr = i * 16 + l4 * 4 + r;
                        red_d[wm][rr][wn] = m1;
                        red_i[wm][rr][wn] = i1;
                        red_2[wm][rr][wn] = m2;
                    }
                }
            asm volatile("s_waitcnt lgkmcnt(0)" ::: "memory");
            __builtin_amdgcn_s_barrier();
            __builtin_amdgcn_sched_barrier(0);

            if (tid < 128) {
                const int hh = tid >> 7;
                const int rr = tid & 127;
                // (hh always 0 for tid<128; kept for clarity with [2][64] layout)
                const int h2 = rr >> 6;
                const int r2 = rr & 63;
                float m1 = red_d[h2][r2][0], m2 = red_2[h2][r2][0];
                int   i1 = red_i[h2][r2][0];
                const float om1 = red_d[h2][r2][1];
                const int   oi  = red_i[h2][r2][1];
                const float om2 = red_2[h2][r2][1];
                m2 = fminf(fminf(m2, om2), fmaxf(m1, om1));
                if (om1 < m1 || (om1 == m1 && oi < i1)) { m1 = om1; i1 = oi; }
                const float nm2 = fminf(fminf(rm2, m2), fmaxf(rm1, m1));
                if (m1 < rm1 || (m1 == rm1 && i1 < ri1)) { rm1 = m1; ri1 = i1; }
                rm2 = nm2;
                (void)hh;
            }

#pragma unroll
            for (int i = 0; i < 4; ++i)
#pragma unroll
                for (int j = 0; j < 8; ++j) acc[i][j] = (floatx4)0.0f;
        }
    }

    if (tid < 128) {
        const size_t off = (size_t)ks * N_ROWS + row0 + tid;
        m1buf[off] = rm1;
        i1buf[off] = ri1;
        m2buf[off] = rm2;
    }
}

// ============================================================================
// Merge K-slices: final argmin + certainty test + worklist
// ============================================================================
__global__ __launch_bounds__(256) void kmeans_merge4(
    const float* __restrict__ m1buf, const int* __restrict__ i1buf,
    const float* __restrict__ m2buf, int* __restrict__ out,
    int* __restrict__ urows, unsigned int* __restrict__ ucount)
{
    const int row = blockIdx.x * 256 + threadIdx.x;
    float m1 = m1buf[row], m2 = m2buf[row];
    int   i1 = i1buf[row];
#pragma unroll
    for (int s = 1; s < KSL; ++s) {
        const float om1 = m1buf[(size_t)s * N_ROWS + row];
        const float om2 = m2buf[(size_t)s * N_ROWS + row];
        const int   oi  = i1buf[(size_t)s * N_ROWS + row];
        const float nm2 = fminf(fminf(m2, om2), fmaxf(m1, om1));
        if (om1 < m1 || (om1 == m1 && oi < i1)) { m1 = om1; i1 = oi; }
        m2 = nm2;
    }
    out[row] = i1;
    if (m2 - m1 <= EPS_GAP) {
        const unsigned slot = atomicAdd(ucount, 1u);
        if (slot < (unsigned)CAP) urows[slot] = row;
    }
}

// ============================================================================
// Gather: uncertain rows' x -> compact fp16 hi/lo buffers [slot][1024]
// ============================================================================
__global__ __launch_bounds__(64) void kmeans_gather(
    const float* __restrict__ x, const int* __restrict__ urows,
    const unsigned int* __restrict__ ucount,
    _Float16* __restrict__ xch, _Float16* __restrict__ xcl)
{
    const unsigned cntr = *ucount;
    const unsigned cnt = cntr > (unsigned)CAP ? (unsigned)CAP : cntr;
    const unsigned slot = blockIdx.x;
    if (slot >= cnt) return;
    const int row = urows[slot];
    const int t = threadIdx.x;
#pragma unroll
    for (int e = 0; e < 16; ++e) {
        const int idx = e * 64 + t;
        const float v = x[(size_t)row * D_DIM + idx];
        const _Float16 h = (_Float16)v;
        xch[(size_t)slot * D_DIM + idx] = h;
        xcl[(size_t)slot * D_DIM + idx] = (_Float16)(v - (float)h);
    }
}

// ============================================================================
// Rescore (K-split x8): exact 3-pass hi/lo over 512-col slice for 32 rows.
// ============================================================================
constexpr int R_XH = 0;        // 1024 halves (2 sub)
constexpr int R_XL = 1024;     // 1024
constexpr int R_CH = 2048;     // 8192 (16 sub)
constexpr int R_CL = 10240;    // 8192
constexpr int R_HB = 18432;    // per buffer (36 KB)

__global__ __launch_bounds__(256) void kmeans_rescore2(
    const _Float16* __restrict__ xch, const _Float16* __restrict__ xcl,
    const _Float16* __restrict__ ChiT, const _Float16* __restrict__ CloT,
    const float* __restrict__ Cnorm, const unsigned int* __restrict__ ucount,
    float* __restrict__ rpd, int* __restrict__ rpi)
{
    const unsigned cntr = *ucount;
    const unsigned cnt = cntr > (unsigned)CAP ? (unsigned)CAP : cntr;
    const int bid = blockIdx.x;
    const int ksl = bid & 7;
    const int grp = bid >> 3;
    if ((unsigned)(grp * 32) >= cnt) return;

    __shared__ _Float16 lds[2][R_HB];
    __shared__ float rd[32][4];
    __shared__ int   ri[32][4];

    const int tid  = threadIdx.x;
    const int lane = tid & 63;
    const int wid  = tid >> 6;
    const int l15  = lane & 15;
    const int l4   = lane >> 4;
    const int kge  = l4 ^ ((l15 >> 1) & 3);
    const int fragoff = l15 * 32 + kge * 8;
    const int scol = lane >> 2;
    const int skg  = (lane & 3) ^ ((scol >> 1) & 3);

    const int base  = grp * 32;
    const int kbase = ksl * (K_CENT / RSL);

    float best[2][4];
    int   bidx[2][4];
#pragma unroll
    for (int i = 0; i < 2; ++i)
#pragma unroll
        for (int r = 0; r < 4; ++r) { best[i][r] = 3.4e38f; bidx[i][r] = 0; }

    for (int ch = 0; ch < 2; ++ch) {
        const int kc = kbase + ch * 256;
        floatx4 acc[2][4];
#pragma unroll
        for (int i = 0; i < 2; ++i)
#pragma unroll
            for (int j = 0; j < 4; ++j) acc[i][j] = (floatx4)0.0f;

        {
            _Float16* buf = lds[0];
#pragma unroll
            for (int q = 0; q < 4; ++q) {
                const int sub = wid * 4 + q;
                gload_lds16(&ChiT[(size_t)(kc + sub * 16 + scol) * D_DIM + 0 + skg * 8], buf + R_CH + sub * 512);
                gload_lds16(&CloT[(size_t)(kc + sub * 16 + scol) * D_DIM + 0 + skg * 8], buf + R_CL + sub * 512);
            }
            if (wid < 2)
                gload_lds16(&xch[(size_t)(base + wid * 16 + scol) * D_DIM + 0 + skg * 8], buf + R_XH + wid * 512);
            else
                gload_lds16(&xcl[(size_t)(base + (wid - 2) * 16 + scol) * D_DIM + 0 + skg * 8], buf + R_XL + (wid - 2) * 512);
            __syncthreads();
        }

        for (int kdi = 0; kdi < D_DIM / 32; ++kdi) {
            const int cur = kdi & 1;
            _Float16* bufc = lds[cur];
            _Float16* bufn = lds[cur ^ 1];
            const int  kdn = (kdi + 1) * 32;
            const bool pf  = (kdi + 1 < D_DIM / 32);

            if (pf) {
#pragma unroll
                for (int q = 0; q < 4; ++q) {
                    const int sub = wid * 4 + q;
                    gload_lds16(&ChiT[(size_t)(kc + sub * 16 + scol) * D_DIM + kdn + skg * 8], bufn + R_CH + sub * 512);
                    gload_lds16(&CloT[(size_t)(kc + sub * 16 + scol) * D_DIM + kdn + skg * 8], bufn + R_CL + sub * 512);
                }
                if (wid < 2)
                    gload_lds16(&xch[(size_t)(base + wid * 16 + scol) * D_DIM + kdn + skg * 8], bufn + R_XH + wid * 512);
                else
                    gload_lds16(&xcl[(size_t)(base + (wid - 2) * 16 + scol) * D_DIM + kdn + skg * 8], bufn + R_XL + (wid - 2) * 512);
            }

            half8 ah[2], al[2], bh[4], bl[4];
#pragma unroll
            for (int i = 0; i < 2; ++i) {
                ah[i] = *(const half8*)(bufc + R_XH + i * 512 + fragoff);
                al[i] = *(const half8*)(bufc + R_XL + i * 512 + fragoff);
            }
#pragma unroll
            for (int j = 0; j < 4; ++j) {
                bh[j] = *(const half8*)(bufc + R_CH + (wid * 4 + j) * 512 + fragoff);
                bl[j] = *(const half8*)(bufc + R_CL + (wid * 4 + j) * 512 + fragoff);
            }
#pragma unroll
            for (int i = 0; i < 2; ++i)
#pragma unroll
                for (int j = 0; j < 4; ++j) {
                    acc[i][j] = __builtin_amdgcn_mfma_f32_16x16x32_f16(ah[i], bh[j], acc[i][j], 0, 0, 0);
                    acc[i][j] = __builtin_amdgcn_mfma_f32_16x16x32_f16(ah[i], bl[j], acc[i][j], 0, 0, 0);
                    acc[i][j] = __builtin_amdgcn_mfma_f32_16x16x32_f16(al[i], bh[j], acc[i][j], 0, 0, 0);
                }
            __syncthreads();
        }

#pragma unroll
        for (int j = 0; j < 4; ++j) {
            const int col = kc + wid * 64 + j * 16 + l15;
            const float cn = Cnorm[col];
#pragma unroll
            for (int i = 0; i < 2; ++i)
#pragma unroll
                for (int r = 0; r < 4; ++r) {
                    const float d = fmaf(-2.0f, acc[i][j][r], cn);
                    if (d < best[i][r]) { best[i][r] = d; bidx[i][r] = col; }
                }
        }
    }

#pragma unroll
    for (int i = 0; i < 2; ++i)
#pragma unroll
        for (int r = 0; r < 4; ++r) {
            float m1 = best[i][r];
            int   i1 = bidx[i][r];
#pragma unroll
            for (int off = 1; off < 16; off <<= 1) {
                const float om1 = __shfl_xor(m1, off, 64);
                const int   oi  = __shfl_xor(i1, off, 64);
                if (om1 < m1 || (om1 == m1 && oi < i1)) { m1 = om1; i1 = oi; }
            }
            if (l15 == 0) { rd[i * 16 + l4 * 4 + r][wid] = m1; ri[i * 16 + l4 * 4 + r][wid] = i1; }
        }
    __syncthreads();

    if (tid < 32) {
        float m1 = rd[tid][0];
        int   i1 = ri[tid][0];
#pragma unroll
        for (int w = 1; w < 4; ++w) {
            const float om1 = rd[tid][w];
            const int   oi  = ri[tid][w];
            if (om1 < m1 || (om1 == m1 && oi < i1)) { m1 = om1; i1 = oi; }
        }
        rpd[(size_t)(base + tid) * RSL + ksl] = m1;
        rpi[(size_t)(base + tid) * RSL + ksl] = i1;
    }
}

// ============================================================================
// Merge rescore slices -> final out for uncertain rows
// ============================================================================
__global__ __launch_bounds__(256) void kmeans_merge2(
    const float* __restrict__ rpd, const int* __restrict__ rpi,
    const int* __restrict__ urows, const unsigned int* __restrict__ ucount,
    int* __restrict__ out)
{
    const unsigned cntr = *ucount;
    const unsigned cnt = cntr > (unsigned)CAP ? (unsigned)CAP : cntr;
    const unsigned s = blockIdx.x * 256 + threadIdx.x;
    if (s >= cnt) return;
    float m1 = rpd[(size_t)s * RSL];
    int   i1 = rpi[(size_t)s * RSL];
#pragma unroll
    for (int k = 1; k < RSL; ++k) {
        const float om = rpd[(size_t)s * RSL + k];
        const int   oi = rpi[(size_t)s * RSL + k];
        if (om < m1 || (om == m1 && oi < i1)) { m1 = om; i1 = oi; }
    }
    out[urows[s]] = i1;
}

// ============================================================================
// Fallback A: proven R3 3-pass MFMA kernel (hi/lo, direct out)
// ============================================================================
constexpr int F_XH = 0, F_XL = 4096, F_CH = 8192, F_CL = 16384, F_HB = 24576;

__device__ __forceinline__ void write_x2(_Float16* buf, const float4 v, int r, int kb) {
    const _Float16 h0 = (_Float16)v.x, h1 = (_Float16)v.y;
    const _Float16 h2 = (_Float16)v.z, h3 = (_Float16)v.w;
    const int kg  = kb >> 3;
    const int hs  = (kb >> 2) & 1;
    const int kge = kg ^ ((r >> 1) & 3);
    const int base = (r >> 4) * 512 + (r & 15) * 32 + kge * 8 + hs * 4;
    *(half4*)(buf + F_XH + base) = (half4){h0, h1, h2, h3};
    *(half4*)(buf + F_XL + base) = (half4){(_Float16)(v.x - (float)h0), (_Float16)(v.y - (float)h1),
                                           (_Float16)(v.z - (float)h2), (_Float16)(v.w - (float)h3)};
}

__global__ __launch_bounds__(512, 2) void kmeans_mfma_kernel(
    const float* __restrict__ x, const _Float16* __restrict__ ChiT,
    const _Float16* __restrict__ CloT, const float* __restrict__ Cnorm,
    int* __restrict__ out)
{
    __shared__ _Float16 lds[2][F_HB];
    __shared__ float red_d[2][64][4];
    __shared__ int   red_i[2][64][4];

    const int tid  = threadIdx.x;
    const int lane = tid & 63;
    const int wid  = tid >> 6;
    const int wm   = wid >> 2;
    const int wn   = wid & 3;
    const int row0 = blockIdx.x * 128;
    const int l15 = lane & 15;
    const int l4  = lane >> 4;
    const int kge = l4 ^ ((l15 >> 1) & 3);
    const int fragoff = l15 * 32 + kge * 8;
    const int sr = tid >> 2, sc = tid & 3;
    const int ccol = lane >> 2;
    const int ckg  = (lane & 3) ^ ((ccol >> 1) & 3);

    float best[4][4];
    int   bidx[4][4];
#pragma unroll
    for (int i = 0; i < 4; ++i)
#pragma unroll
        for (int r = 0; r < 4; ++r) { best[i][r] = 3.4e38f; bidx[i][r] = 0; }

    for (int kc = 0; kc < K_CENT; kc += 256) {
        floatx4 acc[4][4];
#pragma unroll
        for (int i = 0; i < 4; ++i)
#pragma unroll
            for (int j = 0; j < 4; ++j) acc[i][j] = (floatx4)0.0f;
        {
            _Float16* buf = lds[0];
            const float4 xv0 = *(const float4*)&x[(size_t)(row0 + sr) * D_DIM + 0 + sc * 4];
            const float4 xv1 = *(const float4*)&x[(size_t)(row0 + sr) * D_DIM + 16 + sc * 4];
            gload_lds16(&ChiT[(size_t)(kc + wid * 16 + ccol) * D_DIM + 0 + ckg * 8], buf + F_CH + wid * 512);
            gload_lds16(&ChiT[(size_t)(kc + (wid + 8) * 16 + ccol) * D_DIM + 0 + ckg * 8], buf + F_CH + (wid + 8) * 512);
            gload_lds16(&CloT[(size_t)(kc + wid * 16 + ccol) * D_DIM + 0 + ckg * 8], buf + F_CL + wid * 512);
            gload_lds16(&CloT[(size_t)(kc + (wid + 8) * 16 + ccol) * D_DIM + 0 + ckg * 8], buf + F_CL + (wid + 8) * 512);
            write_x2(buf, xv0, sr, sc * 4);
            write_x2(buf, xv1, sr, sc * 4 + 16);
            __syncthreads();
        }
        for (int kdi = 0; kdi < D_DIM / 32; ++kdi) {
            const int cur = kdi & 1;
            _Float16* bufc = lds[cur];
            _Float16* bufn = lds[cur ^ 1];
            const int  kdn = (kdi + 1) * 32;
            const bool pf  = (kdi + 1 < D_DIM / 32);
            float4 xv0, xv1;
            if (pf) {
                xv0 = *(const float4*)&x[(size_t)(row0 + sr) * D_DIM + kdn + sc * 4];
                xv1 = *(const float4*)&x[(size_t)(row0 + sr) * D_DIM + kdn + 16 + sc * 4];
                gload_lds16(&ChiT[(size_t)(kc + wid * 16 + ccol) * D_DIM + kdn + ckg * 8], bufn + F_CH + wid * 512);
                gload_lds16(&ChiT[(size_t)(kc + (wid + 8) * 16 + ccol) * D_DIM + kdn + ckg * 8], bufn + F_CH + (wid + 8) * 512);
                gload_lds16(&CloT[(size_t)(kc + wid * 16 + ccol) * D_DIM + kdn + ckg * 8], bufn + F_CL + wid * 512);
                gload_lds16(&CloT[(size_t)(kc + (wid + 8) * 16 + ccol) * D_DIM + kdn + ckg * 8], bufn + F_CL + (wid + 8) * 512);
            }
            half8 ah[4], al[4], bh[4], bl[4];
#pragma unroll
            for (int i = 0; i < 4; ++i) {
                ah[i] = *(const half8*)(bufc + F_XH + (wm * 4 + i) * 512 + fragoff);
                al[i] = *(const half8*)(bufc + F_XL + (wm * 4 + i) * 512 + fragoff);
            }
#pragma unroll
            for (int j = 0; j < 4; ++j) {
                bh[j] = *(const half8*)(bufc + F_CH + (wn * 4 + j) * 512 + fragoff);
                bl[j] = *(const half8*)(bufc + F_CL + (wn * 4 + j) * 512 + fragoff);
            }
#pragma unroll
            for (int i = 0; i < 4; ++i)
#pragma unroll
                for (int j = 0; j < 4; ++j) {
                    acc[i][j] = __builtin_amdgcn_mfma_f32_16x16x32_f16(ah[i], bh[j], acc[i][j], 0, 0, 0);
                    acc[i][j] = __builtin_amdgcn_mfma_f32_16x16x32_f16(ah[i], bl[j], acc[i][j], 0, 0, 0);
                    acc[i][j] = __builtin_amdgcn_mfma_f32_16x16x32_f16(al[i], bh[j], acc[i][j], 0, 0, 0);
                }
            if (pf) {
                write_x2(bufn, xv0, sr, sc * 4);
                write_x2(bufn, xv1, sr, sc * 4 + 16);
            }
            __syncthreads();
        }
        const int colw = kc + wn * 64;
#pragma unroll
        for (int ns = 0; ns < 4; ++ns) {
            const float cn = Cnorm[colw + ns * 16 + l15];
            const int   ix = colw + ns * 16 + l15;
#pragma unroll
            for (int i = 0; i < 4; ++i)
#pragma unroll
                for (int r = 0; r < 4; ++r) {
                    const float d = fmaf(-2.0f, acc[i][ns][r], cn);
                    if (d < best[i][r]) { best[i][r] = d; bidx[i][r] = ix; }
                }
        }
    }
#pragma unroll
    for (int i = 0; i < 4; ++i)
#pragma unroll
        for (int r = 0; r < 4; ++r) {
            float d  = best[i][r];
            int   ix = bidx[i][r];
#pragma unroll
            for (int off = 1; off < 16; off <<= 1) {
                const float od = __shfl_xor(d, off, 64);
                const int   oi = __shfl_xor(ix, off, 64);
                if (od < d || (od == d && oi < ix)) { d = od; ix = oi; }
            }
            if (l15 == 0) {
                red_d[wm][i * 16 + l4 * 4 + r][wn] = d;
                red_i[wm][i * 16 + l4 * 4 + r][wn] = ix;
            }
        }
    __syncthreads();
    if (tid < 128) {
        const int hh = tid >> 6, rr = tid & 63;
        float bd = red_d[hh][rr][0];
        int   bi2 = red_i[hh][rr][0];
#pragma unroll
        for (int w = 1; w < 4; ++w) {
            const float od = red_d[hh][rr][w];
            const int   oi = red_i[hh][rr][w];
            if (od < bd || (od == bd && oi < bi2)) { bd = od; bi2 = oi; }
        }
        out[row0 + tid] = bi2;
    }
}

// ============================================================================
// Fallback B: R1 fp32 kernel
// ============================================================================
__global__ __launch_bounds__(256, 2) void kmeans_assign_f32(
    const float* __restrict__ x, const float* __restrict__ Cm,
    const float* __restrict__ Cnorm, int* __restrict__ out)
{
    __shared__ float xs[32][64];
    __shared__ float cs[32][64];
    const int tid = threadIdx.x;
    const int tx = tid & 15, ty = tid >> 4;
    const int row0 = blockIdx.x * 64;
    const int xr = tid >> 3, xc = tid & 7;
    const int cr = tid >> 4, cc = tid & 15;
    float best[4]; int bidx[4];
#pragma unroll
    for (int i = 0; i < 4; ++i) { best[i] = 3.4e38f; bidx[i] = 0; }
    for (int kc = 0; kc < K_CENT; kc += 64) {
        float acc[16];
#pragma unroll
        for (int i = 0; i < 16; ++i) acc[i] = 0.0f;
        for (int kd = 0; kd < D_DIM; kd += 32) {
            const float4 xv0 = *(const float4*)&x[(size_t)(row0 + xr) * D_DIM + kd + xc * 4];
            const float4 xv1 = *(const float4*)&x[(size_t)(row0 + xr + 32) * D_DIM + kd + xc * 4];
            const float4 cv0 = *(const float4*)&Cm[(size_t)(kd + cr) * K_CENT + kc + cc * 4];
            const float4 cv1 = *(const float4*)&Cm[(size_t)(kd + cr + 16) * K_CENT + kc + cc * 4];
            __syncthreads();
            xs[xc*4+0][xr] = xv0.x; xs[xc*4+1][xr] = xv0.y; xs[xc*4+2][xr] = xv0.z; xs[xc*4+3][xr] = xv0.w;
            xs[xc*4+0][xr+32] = xv1.x; xs[xc*4+1][xr+32] = xv1.y; xs[xc*4+2][xr+32] = xv1.z; xs[xc*4+3][xr+32] = xv1.w;
            *(float4*)&cs[cr][cc*4]    = cv0;
            *(float4*)&cs[cr+16][cc*4] = cv1;
            __syncthreads();
#pragma unroll
            for (int kk = 0; kk < 32; ++kk) {
                const float4 a = *(const float4*)&xs[kk][ty*4];
                const float4 b = *(const float4*)&cs[kk][tx*4];
                acc[ 0] += a.x*b.x; acc[ 1] += a.x*b.y; acc[ 2] += a.x*b.z; acc[ 3] += a.x*b.w;
                acc[ 4] += a.y*b.x; acc[ 5] += a.y*b.y; acc[ 6] += a.y*b.z; acc[ 7] += a.y*b.w;
                acc[ 8] += a.z*b.x; acc[ 9] += a.z*b.y; acc[10] += a.z*b.z; acc[11] += a.z*b.w;
                acc[12] += a.w*b.x; acc[13] += a.w*b.y; acc[14] += a.w*b.z; acc[15] += a.w*b.w;
            }
        }
        const float4 cn = *(const float4*)&Cnorm[kc + tx*4];
        const float cnv[4] = {cn.x, cn.y, cn.z, cn.w};
#pragma unroll
        for (int i = 0; i < 4; ++i)
#pragma unroll
            for (int j = 0; j < 4; ++j) {
                const float dist = cnv[j] - 2.0f * acc[i*4+j];
                const int   idx  = kc + tx*4 + j;
                if (dist < best[i]) { best[i] = dist; bidx[i] = idx; }
            }
    }
#pragma unroll
    for (int i = 0; i < 4; ++i) {
        float d = best[i]; int ix = bidx[i];
#pragma unroll
        for (int off = 1; off < 16; off <<= 1) {
            const float od = __shfl_xor(d, off, 64);
            const int   oi = __shfl_xor(ix, off, 64);
            if (od < d || (od == d && oi < ix)) { d = od; ix = oi; }
        }
        if (tx == 0) out[row0 + ty*4 + i] = ix;
    }
}

// ============================================================================
extern "C" void kernel_launch(void* const* d_in, const int* in_sizes, int n_in,
                              void* d_out, int out_size, void* d_ws, size_t ws_size,
                              hipStream_t stream) {
    const float* x     = (const float*)d_in[0];
    const float* C     = (const float*)d_in[1];
    const float* Cnorm = (const float*)d_in[2];
    int* out = (int*)d_out;

    const size_t chalf = (size_t)K_CENT * D_DIM;   // halves per C array
    const size_t capd  = (size_t)CAP * D_DIM;      // halves per xc array
    const size_t xhN   = (size_t)N_ROWS * D_DIM;   // halves for x_hi

    const size_t sz_base = (2 * chalf + 2 * capd) * 2
                         + (size_t)KSL * N_ROWS * 12
                         + (size_t)CAP * RSL * 8
                         + (size_t)CAP * 4 + 64;
    const size_t need_full = sz_base + xhN * 2;
    const size_t need_r3   = 2 * chalf * 2;

    if (ws_size >= need_full) {
        _Float16* ChiT = (_Float16*)d_ws;
        _Float16* CloT = ChiT + chalf;
        _Float16* xch  = CloT + chalf;
        _Float16* xcl  = xch + capd;
        float* m1buf = (float*)(xcl + capd);
        float* m2buf = m1buf + (size_t)KSL * N_ROWS;
        int*   i1buf = (int*)(m2buf + (size_t)KSL * N_ROWS);
        float* rpd   = (float*)(i1buf + (size_t)KSL * N_ROWS);
        int*   rpi   = (int*)(rpd + (size_t)CAP * RSL);
        int*   urows = rpi + (size_t)CAP * RSL;
        unsigned int* ucount = (unsigned int*)(urows + CAP);
        _Float16* xh = (_Float16*)(ucount + 16);

        convert_C_kernel<<<dim3(128, 32), 256, 0, stream>>>(C, ChiT, CloT);
        convert_x_kernel<<<dim3((int)(xhN / 2048)), 256, 0, stream>>>(x, xh);
        hipMemsetAsync(ucount, 0, sizeof(unsigned int), stream);
        kmeans_pass1<<<dim3(256 * KSL), 256, 0, stream>>>(xh, ChiT, Cnorm, m1buf, i1buf, m2buf);
        kmeans_merge4<<<dim3(N_ROWS / 256), 256, 0, stream>>>(m1buf, i1buf, m2buf, out, urows, ucount);
        kmeans_gather<<<dim3(CAP), 64, 0, stream>>>(x, urows, ucount, xch, xcl);
        kmeans_rescore2<<<dim3((CAP / 32) * RSL), 256, 0, stream>>>(xch, xcl, ChiT, CloT, Cnorm, ucount, rpd, rpi);
        kmeans_merge2<<<dim3(CAP / 256), 256, 0, stream>>>(rpd, rpi, urows, ucount, out);
    } else if (ws_size >= need_r3) {
        _Float16* ChiT = (_Float16*)d_ws;
        _Float16* CloT = ChiT + chalf;
        convert_C_kernel<<<dim3(128, 32), 256, 0, stream>>>(C, ChiT, CloT);
        kmeans_mfma_kernel<<<dim3(N_ROWS / 128), 512, 0, stream>>>(x, ChiT, CloT, Cnorm, out);
    } else {
        kmeans_assign_f32<<<dim3(N_ROWS / 64), 256, 0, stream>>>(x, C, Cnorm, out);
    }
}